// Round 10
// baseline (268.891 us; speedup 1.0000x reference)
//
#include <hip/hip_runtime.h>

typedef unsigned short u16;
typedef unsigned long long u64;
typedef __attribute__((ext_vector_type(8))) short s8v;   // 8 x bf16 bits (4 VGPR)
typedef __attribute__((ext_vector_type(4))) short s4v;
typedef __attribute__((ext_vector_type(4))) float f4v;

#define LOG2E 1.4426950408889634f

__device__ __forceinline__ float b2f(u16 u) {
  union { unsigned u; float f; } x; x.u = ((unsigned)u) << 16; return x.f;
}
__device__ __forceinline__ u16 f2b(float f) {
  union { float f; unsigned u; } x; x.f = f;
  unsigned r = x.u + 0x7fffu + ((x.u >> 16) & 1u);
  return (u16)(r >> 16);
}
// packed f32x2 -> bf16x2 (single VALU op; RTE)
__device__ __forceinline__ unsigned cvtpk(float lo, float hi) {
  unsigned r;
  asm("v_cvt_pk_bf16_f32 %0, %1, %2" : "=v"(r) : "v"(lo), "v"(hi));
  return r;
}

#define MFMA16(a, b, c) __builtin_amdgcn_mfma_f32_16x16x32_bf16((a), (b), (c), 0, 0, 0)

__device__ __forceinline__ void gload16(const void* g, void* l) {
  __builtin_amdgcn_global_load_lds(
      (const __attribute__((address_space(1))) unsigned*)g,
      (__attribute__((address_space(3))) unsigned*)l, 16, 0, 0);
}

// ---------------------------------------------------------------------------
// weight cast: 14 f32 segments -> one contiguous bf16 region (with per-seg scale)
// ---------------------------------------------------------------------------
struct Segs {
  const float* src[14];
  int cum[15];
  float scl[14];
};

__global__ __launch_bounds__(256) void castk(Segs sg, u16* __restrict__ dst) {
  int gid = (blockIdx.x * 256 + threadIdx.x) * 4;
  if (gid >= sg.cum[14]) return;
  int s = 0;
  while (gid >= sg.cum[s + 1]) ++s;
  const float* sp = sg.src[s] + (gid - sg.cum[s]);
  float sc = sg.scl[s];
  f4v v = *(const f4v*)sp;
  s4v o;
  o[0] = (short)f2b(v[0] * sc); o[1] = (short)f2b(v[1] * sc);
  o[2] = (short)f2b(v[2] * sc); o[3] = (short)f2b(v[3] * sc);
  *(s4v*)(dst + gid) = o;
}

// ---------------------------------------------------------------------------
// transpose a 512x512 bf16 matrix: out[n][k] = in[k][n]
// ---------------------------------------------------------------------------
__global__ __launch_bounds__(256) void tr512(const u16* __restrict__ in, u16* __restrict__ out) {
  __shared__ u16 t[64][72];
  const int bi = blockIdx.x & 7, bj = blockIdx.x >> 3;
  const int tid = threadIdx.x;
  for (int f = tid; f < 512; f += 256) {
    int row = f >> 3, c8 = (f & 7) * 8;
    *(s8v*)&t[row][c8] = *(const s8v*)(in + (size_t)(bj * 64 + row) * 512 + bi * 64 + c8);
  }
  __syncthreads();
  for (int f = tid; f < 512; f += 256) {
    int row = f >> 3, c8 = (f & 7) * 8;
    s8v v;
#pragma unroll
    for (int j = 0; j < 8; ++j) v[j] = (short)t[c8 + j][row];
    *(s8v*)(out + (size_t)(bi * 64 + row) * 512 + bj * 64 + c8) = v;
  }
}

// ---------------------------------------------------------------------------
// bcomb[i] = sum_j Wout_f32[i][j] * ff_b2[j] + out_b[i]   (512 outputs)
// ---------------------------------------------------------------------------
__global__ __launch_bounds__(256) void bcomb_k(
    const float* __restrict__ Wout, const float* __restrict__ b2,
    const float* __restrict__ ob, float* __restrict__ bc)
{
  int i = blockIdx.x * 256 + threadIdx.x;
  if (i >= 512) return;
  float s = ob[i];
  const float* wr = Wout + (size_t)i * 512;
  for (int j = 0; j < 512; j += 4) {
    f4v w = *(const f4v*)(wr + j);
    f4v b = *(const f4v*)(b2 + j);
    s += w[0] * b[0] + w[1] * b[1] + w[2] * b[2] + w[3] * b[3];
  }
  bc[i] = s;
}

// ---------------------------------------------------------------------------
// GN1: group_norm(hidden, pre) + pos_emb -> xb (NCHW bf16); stats of x for GN2.
// ---------------------------------------------------------------------------
__global__ __launch_bounds__(256) void gn1_k(
    const float* __restrict__ hs, const float* __restrict__ pg, const float* __restrict__ pb,
    const float* __restrict__ pos, u16* __restrict__ xb,
    float* __restrict__ mu2, float* __restrict__ rs2)
{
  int bid = blockIdx.x;
  int b = bid >> 5, g = bid & 31;
  int tid = threadIdx.x, l = tid & 63, w = tid >> 6;
  const float* src = hs + ((size_t)b * 512 + g * 16) * 1024;
  const float* pp = pos + (size_t)(g * 16) * 1024;
  u16* dst = xb + ((size_t)b * 512 + g * 16) * 1024;
  f4v vals[16];
  float sum = 0.f, sq = 0.f;
#pragma unroll
  for (int i = 0; i < 16; ++i) {
    int idx = tid + i * 256;
    vals[i] = *(const f4v*)(src + (size_t)idx * 4);
    f4v v = vals[i];
    sum += v[0] + v[1] + v[2] + v[3];
    sq += v[0] * v[0] + v[1] * v[1] + v[2] * v[2] + v[3] * v[3];
  }
  __shared__ float red[8];
#pragma unroll
  for (int off = 1; off < 64; off <<= 1) { sum += __shfl_xor(sum, off); sq += __shfl_xor(sq, off); }
  if (l == 0) { red[w * 2] = sum; red[w * 2 + 1] = sq; }
  __syncthreads();
  float S = red[0] + red[2] + red[4] + red[6];
  float Q = red[1] + red[3] + red[5] + red[7];
  float mean = S * (1.f / 16384.f);
  float var = Q * (1.f / 16384.f) - mean * mean;
  float rstd = rsqrtf(var + 1e-6f);
  __syncthreads();
  float sum2 = 0.f, sq2 = 0.f;
#pragma unroll
  for (int i = 0; i < 16; ++i) {
    int idx = tid + i * 256;
    int c = idx >> 8;
    float gam = pg[g * 16 + c], bet = pb[g * 16 + c];
    f4v v = vals[i];
    f4v pe = *(const f4v*)(pp + (size_t)idx * 4);
    f4v o;
    s4v ob;
#pragma unroll
    for (int j = 0; j < 4; ++j) {
      o[j] = (v[j] - mean) * rstd * gam + bet + pe[j];
      ob[j] = (short)f2b(o[j]);
    }
    *(s4v*)(dst + (size_t)idx * 4) = ob;
    sum2 += o[0] + o[1] + o[2] + o[3];
    sq2 += o[0] * o[0] + o[1] * o[1] + o[2] * o[2] + o[3] * o[3];
  }
#pragma unroll
  for (int off = 1; off < 64; off <<= 1) { sum2 += __shfl_xor(sum2, off); sq2 += __shfl_xor(sq2, off); }
  if (l == 0) { red[w * 2] = sum2; red[w * 2 + 1] = sq2; }
  __syncthreads();
  if (tid == 0) {
    float S2 = red[0] + red[2] + red[4] + red[6];
    float Q2 = red[1] + red[3] + red[5] + red[7];
    float m2 = S2 * (1.f / 16384.f);
    float v2 = Q2 * (1.f / 16384.f) - m2 * m2;
    mu2[b * 32 + g] = m2;
    rs2[b * 32 + g] = rsqrtf(v2 + 1e-6f);
  }
}

// ---------------------------------------------------------------------------
// transpose xb (NCHW bf16) -> xt (token-major bf16) and sh = GN2(x) (token-major)
// ---------------------------------------------------------------------------
__global__ __launch_bounds__(256) void trans_gn2(
    const u16* __restrict__ xb, const float* __restrict__ mu2, const float* __restrict__ rs2,
    const float* __restrict__ ng, const float* __restrict__ nb,
    u16* __restrict__ xt, u16* __restrict__ sh)
{
  __shared__ float lds[512 * 17];
  int st = blockIdx.x, b = blockIdx.y;
  int tid = threadIdx.x;
  const u16* xp = xb + (size_t)b * 512 * 1024 + st * 16;
#pragma unroll
  for (int i = 0; i < 4; ++i) {
    int idx = tid + i * 256;       // 1024 chunks of 8 u16 = 512c x 2
    int c = idx >> 1, sq = (idx & 1) * 8;
    s8v v = *(const s8v*)(xp + (size_t)c * 1024 + sq);
#pragma unroll
    for (int j = 0; j < 8; ++j) lds[c * 17 + sq + j] = b2f((u16)v[j]);
  }
  __syncthreads();
  int s = tid & 15, cb0 = (tid >> 4) * 32;
  size_t token = (size_t)b * 1024 + st * 16 + s;
  float m0 = mu2[b * 32 + (cb0 >> 4)], m1 = mu2[b * 32 + (cb0 >> 4) + 1];
  float r0 = rs2[b * 32 + (cb0 >> 4)], r1 = rs2[b * 32 + (cb0 >> 4) + 1];
#pragma unroll
  for (int q = 0; q < 4; ++q) {
    s8v ox, os;
#pragma unroll
    for (int j = 0; j < 8; ++j) {
      int cj = q * 8 + j;
      int c = cb0 + cj;
      float v = lds[c * 17 + s];
      ox[j] = (short)f2b(v);
      float mm = (cj < 16) ? m0 : m1;
      float rr = (cj < 16) ? r0 : r1;
      os[j] = (short)f2b((v - mm) * rr * ng[c] + nb[c]);
    }
    *(s8v*)(xt + token * 512 + cb0 + q * 8) = ox;
    *(s8v*)(sh + token * 512 + cb0 + q * 8) = os;
  }
}

// ---------------------------------------------------------------------------
// generic bf16 MFMA GEMM: C[M][ldc] = A[M][lda] * Bw[N][ldb]^T  (+bias, +silu,
// +per-row scale). 1-D grid, XCD-swizzled, mt-group-4 L2 panel ordering.
// Single-buffered LDS; implicit wave-level overlap at ~5 blocks/CU.
// ---------------------------------------------------------------------------
template <int BM, int BN, bool SILU, bool OUT32, bool BIAS, bool RSCALE>
__global__ __launch_bounds__(256, 2) void gemm_k(
    const u16* __restrict__ A, int lda,
    const u16* __restrict__ Bw, int ldb,
    void* __restrict__ Cp, int ldc,
    const float* __restrict__ bias, int K, int ntx,
    const float* __restrict__ rscale)
{
  constexpr int WMT = BM / 2, WNT = BN / 2, MF = WMT / 16, NF = WNT / 16;
  __shared__ u16 Al[BM * 64];
  __shared__ u16 Bl[BN * 64];
  const int tid = threadIdx.x, l = tid & 63, w = tid >> 6;
  const int lg = l >> 4, lr = l & 15;
  const int wm = w >> 1, wn = w & 1;
  const int flat = blockIdx.x;
  const int cpx = gridDim.x >> 3;
  const int id = (flat & 7) * cpx + (flat >> 3);
  const int grp = id / (ntx * 4), rem = id % (ntx * 4);
  const int nt = rem >> 2, mt = grp * 4 + (rem & 3);
  const u16* Ag = A + (size_t)mt * BM * lda;
  const u16* Bg = Bw + (size_t)nt * BN * ldb;
  const f4v z = {0.f, 0.f, 0.f, 0.f};
  f4v acc[MF][NF];
#pragma unroll
  for (int i = 0; i < MF; ++i)
#pragma unroll
    for (int j = 0; j < NF; ++j) acc[i][j] = z;

  for (int kt = 0; kt < K; kt += 64) {
    __syncthreads();
    for (int f = tid; f < BM * 8; f += 256) {
      int row = f >> 3, g = (f & 7) ^ (row & 7);
      gload16(Ag + (size_t)row * lda + kt + g * 8, (char*)Al + f * 16);
    }
    for (int f = tid; f < BN * 8; f += 256) {
      int row = f >> 3, g = (f & 7) ^ (row & 7);
      gload16(Bg + (size_t)row * ldb + kt + g * 8, (char*)Bl + f * 16);
    }
    __syncthreads();
#pragma unroll
    for (int ks = 0; ks < 2; ++ks) {
      s8v af[MF], bf[NF];
#pragma unroll
      for (int mf = 0; mf < MF; ++mf) {
        int row = wm * WMT + mf * 16 + lr;
        af[mf] = *(const s8v*)((const char*)Al + row * 128 + (((ks * 4 + lg) ^ (row & 7)) << 4));
      }
#pragma unroll
      for (int nf = 0; nf < NF; ++nf) {
        int row = wn * WNT + nf * 16 + lr;
        bf[nf] = *(const s8v*)((const char*)Bl + row * 128 + (((ks * 4 + lg) ^ (row & 7)) << 4));
      }
#pragma unroll
      for (int mf = 0; mf < MF; ++mf)
#pragma unroll
        for (int nf = 0; nf < NF; ++nf)
          acc[mf][nf] = MFMA16(af[mf], bf[nf], acc[mf][nf]);
    }
  }
#pragma unroll
  for (int mf = 0; mf < MF; ++mf) {
    int row0 = mt * BM + wm * WMT + mf * 16 + lg * 4;
#pragma unroll
    for (int nf = 0; nf < NF; ++nf) {
      int col = nt * BN + wn * WNT + nf * 16 + lr;
      float bv = BIAS ? bias[col] : 0.f;
#pragma unroll
      for (int r = 0; r < 4; ++r) {
        float v = acc[mf][nf][r] + bv;
        if (RSCALE) v *= rscale[row0 + r];
        if (SILU) v = v / (1.f + exp2f(-v * LOG2E));
        size_t off = (size_t)(row0 + r) * ldc + col;
        if (OUT32) ((float*)Cp)[off] = v;
        else ((u16*)Cp)[off] = f2b(v);
      }
    }
  }
}

// ---------------------------------------------------------------------------
// im2col for 3x3 conv
// ---------------------------------------------------------------------------
__global__ __launch_bounds__(256) void im2col_k(const u16* __restrict__ s1t, u16* __restrict__ col) {
  int gid = blockIdx.x * 256 + threadIdx.x;
  if (gid >= 8192 * 64) return;
  int token = gid >> 6, c = gid & 63;
  int s = token & 1023, y = s >> 5, xx = s & 31;
  u16* dst = col + (size_t)token * 576 + c * 9;
#pragma unroll
  for (int dy = 0; dy < 3; ++dy)
#pragma unroll
    for (int dx = 0; dx < 3; ++dx) {
      int yy = y + dy - 1, x2 = xx + dx - 1;
      u16 v = 0;
      if (yy >= 0 && yy < 32 && x2 >= 0 && x2 < 32)
        v = s1t[(size_t)(token + (dy - 1) * 32 + (dx - 1)) * 64 + c];
      dst[dy * 3 + dx] = v;
    }
}

// ---------------------------------------------------------------------------
// conv3 (1x1, 64->1) + sigmoid -> gate [8192] f32
// ---------------------------------------------------------------------------
__global__ __launch_bounds__(256) void conv3_k(
    const u16* __restrict__ s2t, const float* __restrict__ w3,
    const float* __restrict__ b3, float* __restrict__ gate)
{
  int token = blockIdx.x * 256 + threadIdx.x;
  if (token >= 8192) return;
  float acc = b3[0];
#pragma unroll
  for (int q = 0; q < 8; ++q) {
    s8v v = *(const s8v*)(s2t + (size_t)token * 64 + q * 8);
#pragma unroll
    for (int e = 0; e < 8; ++e) acc += b2f((u16)v[e]) * w3[q * 8 + e];
  }
  gate[token] = 1.f / (1.f + exp2f(-acc * LOG2E));
}

// ---------------------------------------------------------------------------
// V transpose: proj[token][col0 + hh*HD + d] -> out[(y)*HD + d][1024 keys]
// with per-64-key-block pi-permutation: position a*4+bb holds key bb*16+a.
// ---------------------------------------------------------------------------
template <int HD>
__global__ __launch_bounds__(256) void tv_k(const u16* __restrict__ proj, int col0,
                                            u16* __restrict__ out)
{
  __shared__ u16 tile[64][HD + 2];
  const int tid = threadIdx.x;
  const int kb = blockIdx.x, y = blockIdx.y;
  const int nh = 512 / HD;
  const int b = y / nh, hh = y % nh;
  const u16* src = proj + ((size_t)b * 1024 + kb * 64) * 2560 + col0 + hh * HD;
  for (int f = tid; f < 64 * HD / 8; f += 256) {
    int key = f / (HD / 8), c = f % (HD / 8);
    *(s8v*)&tile[key][c * 8] = *(const s8v*)(src + (size_t)key * 2560 + c * 8);
  }
  __syncthreads();
  u16* dst = out + (size_t)y * HD * 1024 + kb * 64;
  for (int idx = tid; idx < HD * 16; idx += 256) {
    int d = idx >> 4, a = idx & 15;
    u16 e0 = tile[a][d], e1 = tile[16 + a][d], e2 = tile[32 + a][d], e3 = tile[48 + a][d];
    u64 v = (u64)e0 | ((u64)e1 << 16) | ((u64)e2 << 32) | ((u64)e3 << 48);
    *(u64*)(dst + (size_t)d * 1024 + a * 4) = v;
  }
}

// ---------------------------------------------------------------------------
// standard MHA flash attention v8: hd=64, unnormalized flash.
// K/V dbuf LDS; staging pointers hoisted out of the K-loop (constant strides).
// ---------------------------------------------------------------------------
__global__ __launch_bounds__(256, 4) void attn_std(
    const u16* __restrict__ proj, const u16* __restrict__ vts, u16* __restrict__ comb)
{
  const int tid = threadIdx.x, l = tid & 63, w = tid >> 6;
  const int lg = l >> 4, lr = l & 15;
  const int flat = blockIdx.x;
  const int xcd = flat & 7, idx = flat >> 3;      // idx 0..127
  const int bh = xcd + 8 * (idx >> 4);            // 8 heads per XCD
  const int qt = idx & 15;
  const int b = bh >> 3, h = bh & 7;
  const size_t tokb = (size_t)b * 1024;
  __shared__ u16 Kl[2][64 * 64];
  __shared__ u16 Vl[2][64 * 64];
  __shared__ u16 Pl[4][16 * 64];
  const int qr0 = qt * 64 + w * 16;
  s8v qf[2];
#pragma unroll
  for (int ks = 0; ks < 2; ++ks)
    qf[ks] = *(const s8v*)(proj + (tokb + qr0 + lr) * 2560 + h * 64 + ks * 32 + lg * 8);
  const f4v z = {0.f, 0.f, 0.f, 0.f};
  f4v acc[4];
  float lsl[4] = {0.f, 0.f, 0.f, 0.f};
#pragma unroll
  for (int r = 0; r < 4; ++r) acc[r] = z;

  // hoisted per-lane staging pointers (at kt = 0); advanced by constant stride
  const u16* gk[2];
  const u16* gv[2];
  char* lk[2];
  char* lv[2];
#pragma unroll
  for (int j = 0; j < 2; ++j) {
    int f = tid + j * 256;
    int key = f >> 3, g = (f & 7) ^ (key & 7);
    gk[j] = proj + (tokb + key) * 2560 + 512 + h * 64 + g * 8;
    int c = (f & 7) ^ (key & 7);
    gv[j] = vts + (size_t)bh * 64 * 1024 + (size_t)key * 1024 + c * 8;
    lk[j] = (char*)&Kl[0][0] + f * 16;
    lv[j] = (char*)&Vl[0][0] + f * 16;
  }

  auto stage = [&](int buf) {
#pragma unroll
    for (int j = 0; j < 2; ++j) {
      gload16(gk[j], lk[j] + buf * 8192);
      gload16(gv[j], lv[j] + buf * 8192);
    }
#pragma unroll
    for (int j = 0; j < 2; ++j) { gk[j] += 64 * 2560; gv[j] += 64; }
  };

  stage(0);
  __syncthreads();
  int cur = 0;
  for (int kt = 0; kt < 16; ++kt) {
    if (kt < 15) stage(cur ^ 1);
    f4v sf[4];
#pragma unroll
    for (int nf = 0; nf < 4; ++nf) sf[nf] = z;
#pragma unroll
    for (int ks = 0; ks < 2; ++ks) {
      s8v kfr[4];
#pragma unroll
      for (int nf = 0; nf < 4; ++nf) {
        int row = nf * 16 + lr;
        kfr[nf] = *(const s8v*)((const char*)&Kl[cur][0] + row * 128 + (((ks * 4 + lg) ^ (row & 7)) << 4));
      }
#pragma unroll
      for (int nf = 0; nf < 4; ++nf) sf[nf] = MFMA16(qf[ks], kfr[nf], sf[nf]);
    }
#pragma unroll
    for (int r = 0; r < 4; ++r) {
      float pv[4];
#pragma unroll
      for (int nf = 0; nf < 4; ++nf) pv[nf] = exp2f(sf[nf][r]);
      lsl[r] += (pv[0] + pv[1]) + (pv[2] + pv[3]);
      int q = lg * 4 + r;
      u64 pk = (u64)cvtpk(pv[0], pv[1]) | ((u64)cvtpk(pv[2], pv[3]) << 32);
      *(u64*)((char*)&Pl[w][0] + q * 128 + ((((lr >> 1) ^ (q & 7)) << 4)) + (lr & 1) * 8) = pk;
    }
#pragma unroll
    for (int ks2 = 0; ks2 < 2; ++ks2) {
      int g = ks2 * 4 + lg;
      s8v pfr = *(const s8v*)((const char*)&Pl[w][0] + lr * 128 + ((g ^ (lr & 7)) << 4));
#pragma unroll
      for (int nf = 0; nf < 4; ++nf) {
        int d = nf * 16 + lr;
        s8v vfr = *(const s8v*)((const char*)&Vl[cur][0] + d * 128 + ((g ^ (d & 7)) << 4));
        acc[nf] = MFMA16(pfr, vfr, acc[nf]);
      }
    }
    __syncthreads();
    cur ^= 1;
  }
#pragma unroll
  for (int r = 0; r < 4; ++r) {
    float t = lsl[r];
#pragma unroll
    for (int off = 1; off < 16; off <<= 1) t += __shfl_xor(t, off);
    float inv = 1.f / t;
    size_t row = tokb + qr0 + lg * 4 + r;
#pragma unroll
    for (int nf = 0; nf < 4; ++nf)
      comb[row * 1024 + h * 64 + nf * 16 + lr] = f2b(acc[nf][r] * inv);
  }
}

// ---------------------------------------------------------------------------
// multi-scale attention v8: hd=256, K-split=2, unnormalized flash.
// K/V single-buffered LDS; staging pointers hoisted with constant strides.
// ---------------------------------------------------------------------------
__global__ __launch_bounds__(256, 2) void attn_ms(
    const u16* __restrict__ proj, const u16* __restrict__ qm, const u16* __restrict__ vtm,
    u16* __restrict__ pacc, float* __restrict__ pl)
{
  const int tid = threadIdx.x, l = tid & 63, w = tid >> 6;
  const int lg = l >> 4, lr = l & 15;
  const int flat = blockIdx.x;
  const int xcd = flat & 7, idx = flat >> 3;      // idx 0..63
  const int bp = xcd + 8 * (idx >> 5);            // 2 (b,p) pairs per XCD
  const int rest = idx & 31;
  const int qt = rest >> 1, ks = rest & 1;
  const int b = bp >> 1, p = bp & 1;
  const size_t tokb = (size_t)b * 1024;
  __shared__ u16 Kl[64 * 256];
  __shared__ u16 Vl[256 * 64];
  __shared__ u16 Pl[4][16 * 64];
  const int qr0 = qt * 64 + w * 16;
  s8v qf[8];
#pragma unroll
  for (int kf = 0; kf < 8; ++kf)
    qf[kf] = *(const s8v*)(qm + (tokb + qr0 + lr) * 512 + p * 256 + kf * 32 + lg * 8);
  const f4v z = {0.f, 0.f, 0.f, 0.f};
  f4v acc[16];
#pragma unroll
  for (int i = 0; i < 16; ++i) acc[i] = z;
  float lsl[4] = {0.f, 0.f, 0.f, 0.f};
  const u16* vbase = vtm + (size_t)bp * 256 * 1024;

  // hoisted per-lane staging pointers (at kk = 0)
  const u16* gk[8];
  const u16* gv[8];
#pragma unroll
  for (int j = 0; j < 8; ++j) {
    int f = tid + j * 256;
    int key = f >> 5, pgc = f & 31;
    int g = (pgc & 24) | ((pgc & 7) ^ (key & 7));
    gk[j] = proj + (tokb + ks * 512 + key) * 2560 + 1536 + p * 256 + g * 8;
    int d = f >> 3, c = (f & 7) ^ (d & 7);
    gv[j] = vbase + (size_t)d * 1024 + ks * 512 + c * 8;
  }

  for (int kk = 0; kk < 8; ++kk) {
    __syncthreads();
#pragma unroll
    for (int j = 0; j < 8; ++j) gload16(gk[j], (char*)Kl + (tid + j * 256) * 16);
#pragma unroll
    for (int j = 0; j < 8; ++j) gload16(gv[j], (char*)Vl + (tid + j * 256) * 16);
#pragma unroll
    for (int j = 0; j < 8; ++j) { gk[j] += 64 * 2560; gv[j] += 64; }
    __syncthreads();
    f4v sf[4];
#pragma unroll
    for (int nf = 0; nf < 4; ++nf) sf[nf] = z;
#pragma unroll
    for (int ksi = 0; ksi < 8; ++ksi) {
      s8v kfr[4];
#pragma unroll
      for (int nf = 0; nf < 4; ++nf) {
        int row = nf * 16 + lr;
        int g = ksi * 4 + lg;
        int pg2 = (g & 24) | ((g & 7) ^ (row & 7));
        kfr[nf] = *(const s8v*)((const char*)Kl + row * 512 + (pg2 << 4));
      }
#pragma unroll
      for (int nf = 0; nf < 4; ++nf) sf[nf] = MFMA16(qf[ksi], kfr[nf], sf[nf]);
    }
#pragma unroll
    for (int r = 0; r < 4; ++r) {
      float pv[4];
#pragma unroll
      for (int nf = 0; nf < 4; ++nf) pv[nf] = exp2f(sf[nf][r]);
      lsl[r] += (pv[0] + pv[1]) + (pv[2] + pv[3]);
      int q = lg * 4 + r;
      u64 pk = (u64)cvtpk(pv[0], pv[1]) | ((u64)cvtpk(pv[2], pv[3]) << 32);
      *(u64*)((char*)&Pl[w][0] + q * 128 + ((((lr >> 1) ^ (q & 7)) << 4)) + (lr & 1) * 8) = pk;
    }
#pragma unroll
    for (int ks2 = 0; ks2 < 2; ++ks2) {
      int g = ks2 * 4 + lg;
      s8v pfr = *(const s8v*)((const char*)&Pl[w][0] + lr * 128 + ((g ^ (lr & 7)) << 4));
#pragma unroll
      for (int nfd = 0; nfd < 16; ++nfd) {
        int d = nfd * 16 + lr;
        s8v vfr = *(const s8v*)((const char*)Vl + d * 128 + ((g ^ (d & 7)) << 4));
        acc[nfd] = MFMA16(pfr, vfr, acc[nfd]);
      }
    }
  }
  // write partials (unnormalized acc in bf16, per-row l in f32)
#pragma unroll
  for (int r = 0; r < 4; ++r) {
    float t = lsl[r];
#pragma unroll
    for (int off = 1; off < 16; off <<= 1) t += __shfl_xor(t, off);
    size_t prow = ((size_t)(bp * 2 + ks) * 16 + qt) * 64 + w * 16 + lg * 4 + r;
#pragma unroll
    for (int nfd = 0; nfd < 16; ++nfd)
      pacc[prow * 256 + nfd * 16 + lr] = f2b(acc[nfd][r]);
    if (lr == 0) pl[prow] = t;
  }
}

// ---------------------------------------------------------------------------
// combine the 2 K-slices of attn_ms -> comb[:, 512:1024]  (shared exponent frame)
// ---------------------------------------------------------------------------
__global__ __launch_bounds__(256) void ms_comb(
    const u16* __restrict__ pacc, const float* __restrict__ pl,
    u16* __restrict__ comb)
{
  const int qt = blockIdx.x, bp = blockIdx.y;
  const int tid = threadIdx.x;
  const int row = tid >> 2, seg = tid & 3;
  size_t prow0 = ((size_t)(bp * 2 + 0) * 16 + qt) * 64 + row;
  size_t prow1 = ((size_t)(bp * 2 + 1) * 16 + qt) * 64 + row;
  float inv = 1.f / (pl[prow0] + pl[prow1]);
  const int b = bp >> 1, p = bp & 1;
  size_t orow = ((size_t)b * 1024 + qt * 64 + row) * 1024 + 512 + p * 256 + seg * 64;
#pragma unroll
  for (int j = 0; j < 8; ++j) {
    s8v v0 = *(const s8v*)(pacc + prow0 * 256 + seg * 64 + j * 8);
    s8v v1 = *(const s8v*)(pacc + prow1 * 256 + seg * 64 + j * 8);
    s8v ov;
#pragma unroll
    for (int e = 0; e < 8; ++e)
      ov[e] = (short)f2b((b2f((u16)v0[e]) + b2f((u16)v1[e])) * inv);
    *(s8v*)(comb + orow + j * 8) = ov;
  }
}

// ---------------------------------------------------------------------------
// GN3 stats over fin [8192][512] per (b, group)
// ---------------------------------------------------------------------------
__global__ __launch_bounds__(256) void gn3_stats(
    const float* __restrict__ fin, float* __restrict__ mu3, float* __restrict__ rs3)
{
  int bid = blockIdx.x;
  int b = bid >> 5, g = bid & 31;
  int tid = threadIdx.x, l = tid & 63, w = tid >> 6;
  const float* fp = fin + (size_t)b * 1024 * 512 + g * 16;
  float sum = 0.f, sq = 0.f;
#pragma unroll
  for (int i = 0; i < 16; ++i) {
    int idx = tid + i * 256;
    int s = idx >> 2, cq = idx & 3;
    f4v v = *(const f4v*)(fp + (size_t)s * 512 + cq * 4);
    sum += v[0] + v[1] + v[2] + v[3];
    sq += v[0] * v[0] + v[1] * v[1] + v[2] * v[2] + v[3] * v[3];
  }
  __shared__ float red[8];
#pragma unroll
  for (int off = 1; off < 64; off <<= 1) { sum += __shfl_xor(sum, off); sq += __shfl_xor(sq, off); }
  if (l == 0) { red[w * 2] = sum; red[w * 2 + 1] = sq; }
  __syncthreads();
  if (tid == 0) {
    float S = red[0] + red[2] + red[4] + red[6];
    float Q = red[1] + red[3] + red[5] + red[7];
    float mean = S * (1.f / 16384.f);
    float var = Q * (1.f / 16384.f) - mean * mean;
    mu3[b * 32 + g] = mean;
    rs3[b * 32 + g] = rsqrtf(var + 1e-6f);
  }
}

// ---------------------------------------------------------------------------
// final: transpose fin back to NCHW, apply GN3 + residual -> out (f32)
// ---------------------------------------------------------------------------
__global__ __launch_bounds__(256) void final_k(
    const float* __restrict__ fin, const float* __restrict__ mu3, const float* __restrict__ rs3,
    const float* __restrict__ postg, const float* __restrict__ postb,
    const float* __restrict__ res, float* __restrict__ out)
{
  __shared__ float lds[16 * 513];
  int st = blockIdx.x, b = blockIdx.y;
  int tid = threadIdx.x;
  const float* fp = fin + ((size_t)b * 1024 + st * 16) * 512;
#pragma unroll
  for (int i = 0; i < 8; ++i) {
    int idx = tid + i * 256;   // 2048 float4 = 16s x 128
    int s = idx >> 7, cq = idx & 127;
    f4v v = *(const f4v*)(fp + (size_t)s * 512 + cq * 4);
#pragma unroll
    for (int j = 0; j < 4; ++j) lds[s * 513 + cq * 4 + j] = v[j];
  }
  __syncthreads();
#pragma unroll
  for (int cc = 0; cc < 2; ++cc) {
    int c = tid * 2 + cc;
    int g = c >> 4;
    float m = mu3[b * 32 + g], rv = rs3[b * 32 + g];
    float ga = postg[c], be = postb[c];
    const float* rp = res + ((size_t)b * 512 + c) * 1024 + st * 16;
    float* op = out + ((size_t)b * 512 + c) * 1024 + st * 16;
#pragma unroll
    for (int q = 0; q < 4; ++q) {
      f4v rr = *(const f4v*)(rp + q * 4);
      f4v o;
#pragma unroll
      for (int j = 0; j < 4; ++j) {
        float v = lds[(q * 4 + j) * 513 + c];
        o[j] = (v - m) * rv * ga + be + rr[j];
      }
      *(f4v*)(op + q * 4) = o;
    }
  }
}

// ---------------------------------------------------------------------------
extern "C" void kernel_launch(void* const* d_in, const int* in_sizes, int n_in,
                              void* d_out, int out_size, void* d_ws, size_t ws_size,
                              hipStream_t stream) {
  (void)in_sizes; (void)n_in; (void)out_size; (void)ws_size;
  const float* hs     = (const float*)d_in[0];
  const float* pre_g  = (const float*)d_in[1];
  const float* pre_b  = (const float*)d_in[2];
  const float* norm_g = (const float*)d_in[3];
  const float* norm_b = (const float*)d_in[4];
  const float* post_g = (const float*)d_in[5];
  const float* post_b = (const float*)d_in[6];
  const float* pos    = (const float*)d_in[7];
  const float* sa_b1  = (const float*)d_in[18];
  const float* sa_b2  = (const float*)d_in[20];
  const float* sa_w3  = (const float*)d_in[21];
  const float* sa_b3  = (const float*)d_in[22];
  const float* ff_b1  = (const float*)d_in[24];
  const float* ff_b2  = (const float*)d_in[26];
  const float* out_b  = (const float*)d_in[28];
  const float* wout_f = (const float*)d_in[27];

  char* ws = (char*)d_ws;
  size_t off = 0;
  auto alloc = [&](size_t bytes) -> void* {
    void* pp = ws + off;
    off += (bytes + 255) & ~(size_t)255;
    return pp;
  };
  float* x    = (float*)alloc((size_t)16777216);       // [8][512][1024] f32 region
  u16* sh     = (u16*)alloc((size_t)8388608);          // [8192][512] bf16
  u16* xt     = (u16*)alloc((size_t)8388608);          // [8192][512] bf16
  float* mu2  = (float*)alloc(1024);
  float* rs2  = (float*)alloc(1024);
  float* mu3  = (float*)alloc(1024);
  float* rs3  = (float*)alloc(1024);
  float* pl   = (float*)alloc(262144);                 // [32][16][64]
  u16* wcat   = (u16*)alloc((size_t)2691072 * 2);      // all bf16 weights
  u16* proj   = (u16*)alloc((size_t)8192 * 2560 * 2);  // q|k|v|k0|k1|v0|v1
  u16* qmb    = (u16*)alloc((size_t)8388608);          // [8192][512]
  u16* s1t    = (u16*)alloc((size_t)1048576);          // [8192][64]
  u16* colb   = (u16*)alloc((size_t)8192 * 576 * 2);   // im2col; reused as vts
  u16* s2t    = (u16*)alloc((size_t)1048576);          // [8192][64]
  float* gate = (float*)alloc((size_t)32768);          // [8192]
  u16* vtm    = (u16*)alloc((size_t)8388608);          // [512 d][1024 keys] x 16
  u16* comb   = (u16*)alloc((size_t)16777216);         // [8192][1024]
  u16* f1     = (u16*)alloc((size_t)8388608);
  u16* wff2t  = (u16*)alloc((size_t)524288);           // Wff2^T bf16
  u16* wcomb  = (u16*)alloc((size_t)524288);           // Wout@Wff2 bf16
  float* bcomb = (float*)alloc(2048);                  // fused bias
  float* fin  = x;                                     // reuse
  u16* xb     = (u16*)x;                               // bf16 NCHW x (8MB over x)
  u16* pacc   = (u16*)x;                               // 16MB over x (after xb dead)
  u16* vts    = colb;                                  // 8MB over colb

  u16* Wbig = wcat;                 // [2560][512]
  u16* Wq01 = wcat + 1310720;       // [512][512]
  u16* W1   = wcat + 1572864;       // [64][512]
  u16* W2   = wcat + 1605632;       // [64][576]
  u16* Wff1 = wcat + 1642496;       // [512][1024]
  u16* Wff2 = wcat + 2166784;       // [512][512]
  u16* Wout = wcat + 2428928;       // [512][512]

  Segs sg;
  const int srcidx[14] = {8, 9, 10, 13, 14, 15, 16, 11, 12, 17, 19, 23, 25, 27};
  const int segsz[14] = {262144, 262144, 262144, 131072, 131072, 131072, 131072,
                         131072, 131072, 32768, 36864, 524288, 262144, 262144};
  int cum = 0;
  for (int i = 0; i < 14; ++i) {
    sg.src[i] = (const float*)d_in[srcidx[i]];
    sg.cum[i] = cum;
    sg.scl[i] = 1.f;
    cum += segsz[i];
  }
  sg.cum[14] = cum;   // 2691072
  sg.scl[0] = 0.125f * LOG2E;    // wq  : 1/sqrt(64) * log2(e)
  sg.scl[7] = 0.0625f * LOG2E;   // wq0 : 1/sqrt(256) * log2(e)
  sg.scl[8] = 0.0625f * LOG2E;   // wq1

  dim3 blk(256);
  castk<<<2628, blk, 0, stream>>>(sg, wcat);
  // weight-prep for fused ff2+out: Wcomb = Wout @ Wff2, bcomb = Wout@b2 + bo
  tr512<<<64, blk, 0, stream>>>(Wff2, wff2t);
  gemm_k<128, 64, false, false, false, false><<<32, blk, 0, stream>>>(
      Wout, 512, wff2t, 512, wcomb, 512, nullptr, 512, 8, nullptr);
  bcomb_k<<<2, blk, 0, stream>>>(wout_f, ff_b2, out_b, bcomb);

  gn1_k<<<256, blk, 0, stream>>>(hs, pre_g, pre_b, pos, xb, mu2, rs2);
  trans_gn2<<<dim3(64, 8), blk, 0, stream>>>(xb, mu2, rs2, norm_g, norm_b, xt, sh);
  // fused qkv + multiscale k/v projection: [8192][512] x [2560][512]^T
  gemm_k<128, 128, false, false, false, false><<<1280, blk, 0, stream>>>(
      sh, 512, Wbig, 512, proj, 2560, nullptr, 512, 20, nullptr);
  // spatial gate path
  gemm_k<64, 64, true, false, true, false><<<128, blk, 0, stream>>>(
      xt, 512, W1, 512, s1t, 64, sa_b1, 512, 1, nullptr);
  im2col_k<<<2048, blk, 0, stream>>>(s1t, colb);
  gemm_k<64, 64, true, false, true, false><<<128, blk, 0, stream>>>(
      colb, 576, W2, 576, s2t, 64, sa_b2, 576, 1, nullptr);
  conv3_k<<<32, blk, 0, stream>>>(s2t, sa_w3, sa_b3, gate);
  // qm = diag(gate) @ (xt @ Wq01^T)  — gate folded into GEMM epilogue
  gemm_k<128, 64, false, false, false, true><<<512, blk, 0, stream>>>(
      xt, 512, Wq01, 512, qmb, 512, nullptr, 512, 8, gate);
  // V transposes (pi-permuted); colb dead by now
  tv_k<64><<<dim3(16, 64), blk, 0, stream>>>(proj, 1024, vts);
  tv_k<256><<<dim3(16, 16), blk, 0, stream>>>(proj, 2048, vtm);
  // attention
  attn_std<<<1024, blk, 0, stream>>>(proj, vts, comb);
  attn_ms<<<512, blk, 0, stream>>>(proj, qmb, vtm, pacc, pl);
  ms_comb<<<dim3(16, 16), blk, 0, stream>>>(pacc, pl, comb);
  // feed-forward: f1 = silu(comb@Wff1^T+b1); fin = f1 @ Wcomb^T + bcomb
  gemm_k<128, 64, true, false, true, false><<<512, blk, 0, stream>>>(
      comb, 1024, Wff1, 1024, f1, 512, ff_b1, 1024, 8, nullptr);
  gemm_k<128, 64, false, true, true, false><<<512, blk, 0, stream>>>(
      f1, 512, wcomb, 512, fin, 512, bcomb, 512, 8, nullptr);
  // final group norm + residual
  gn3_stats<<<256, blk, 0, stream>>>(fin, mu3, rs3);
  final_k<<<dim3(64, 8), blk, 0, stream>>>(fin, mu3, rs3, post_g, post_b, hs, (float*)d_out);
}

// Round 11
// 251.489 us; speedup vs baseline: 1.0692x; 1.0692x over previous
//
#include <hip/hip_runtime.h>

typedef unsigned short u16;
typedef unsigned long long u64;
typedef __attribute__((ext_vector_type(8))) short s8v;   // 8 x bf16 bits (4 VGPR)
typedef __attribute__((ext_vector_type(4))) short s4v;
typedef __attribute__((ext_vector_type(4))) float f4v;

#define LOG2E 1.4426950408889634f

__device__ __forceinline__ float b2f(u16 u) {
  union { unsigned u; float f; } x; x.u = ((unsigned)u) << 16; return x.f;
}
__device__ __forceinline__ u16 f2b(float f) {
  union { float f; unsigned u; } x; x.f = f;
  unsigned r = x.u + 0x7fffu + ((x.u >> 16) & 1u);
  return (u16)(r >> 16);
}
// packed f32x2 -> bf16x2 (single VALU op; RTE)
__device__ __forceinline__ unsigned cvtpk(float lo, float hi) {
  unsigned r;
  asm("v_cvt_pk_bf16_f32 %0, %1, %2" : "=v"(r) : "v"(lo), "v"(hi));
  return r;
}

#define MFMA16(a, b, c) __builtin_amdgcn_mfma_f32_16x16x32_bf16((a), (b), (c), 0, 0, 0)

__device__ __forceinline__ void gload16(const void* g, void* l) {
  __builtin_amdgcn_global_load_lds(
      (const __attribute__((address_space(1))) unsigned*)g,
      (__attribute__((address_space(3))) unsigned*)l, 16, 0, 0);
}

// ---------------------------------------------------------------------------
// weight cast: 14 f32 segments -> one contiguous bf16 region (with per-seg scale)
// ---------------------------------------------------------------------------
struct Segs {
  const float* src[14];
  int cum[15];
  float scl[14];
};

__global__ __launch_bounds__(256) void castk(Segs sg, u16* __restrict__ dst) {
  int gid = (blockIdx.x * 256 + threadIdx.x) * 4;
  if (gid >= sg.cum[14]) return;
  int s = 0;
  while (gid >= sg.cum[s + 1]) ++s;
  const float* sp = sg.src[s] + (gid - sg.cum[s]);
  float sc = sg.scl[s];
  f4v v = *(const f4v*)sp;
  s4v o;
  o[0] = (short)f2b(v[0] * sc); o[1] = (short)f2b(v[1] * sc);
  o[2] = (short)f2b(v[2] * sc); o[3] = (short)f2b(v[3] * sc);
  *(s4v*)(dst + gid) = o;
}

// ---------------------------------------------------------------------------
// GN1: group_norm(hidden, pre) + pos_emb -> xb (NCHW bf16); stats of x for GN2.
// ---------------------------------------------------------------------------
__global__ __launch_bounds__(256) void gn1_k(
    const float* __restrict__ hs, const float* __restrict__ pg, const float* __restrict__ pb,
    const float* __restrict__ pos, u16* __restrict__ xb,
    float* __restrict__ mu2, float* __restrict__ rs2)
{
  int bid = blockIdx.x;
  int b = bid >> 5, g = bid & 31;
  int tid = threadIdx.x, l = tid & 63, w = tid >> 6;
  const float* src = hs + ((size_t)b * 512 + g * 16) * 1024;
  const float* pp = pos + (size_t)(g * 16) * 1024;
  u16* dst = xb + ((size_t)b * 512 + g * 16) * 1024;
  f4v vals[16];
  float sum = 0.f, sq = 0.f;
#pragma unroll
  for (int i = 0; i < 16; ++i) {
    int idx = tid + i * 256;
    vals[i] = *(const f4v*)(src + (size_t)idx * 4);
    f4v v = vals[i];
    sum += v[0] + v[1] + v[2] + v[3];
    sq += v[0] * v[0] + v[1] * v[1] + v[2] * v[2] + v[3] * v[3];
  }
  __shared__ float red[8];
#pragma unroll
  for (int off = 1; off < 64; off <<= 1) { sum += __shfl_xor(sum, off); sq += __shfl_xor(sq, off); }
  if (l == 0) { red[w * 2] = sum; red[w * 2 + 1] = sq; }
  __syncthreads();
  float S = red[0] + red[2] + red[4] + red[6];
  float Q = red[1] + red[3] + red[5] + red[7];
  float mean = S * (1.f / 16384.f);
  float var = Q * (1.f / 16384.f) - mean * mean;
  float rstd = rsqrtf(var + 1e-6f);
  __syncthreads();
  float sum2 = 0.f, sq2 = 0.f;
#pragma unroll
  for (int i = 0; i < 16; ++i) {
    int idx = tid + i * 256;
    int c = idx >> 8;
    float gam = pg[g * 16 + c], bet = pb[g * 16 + c];
    f4v v = vals[i];
    f4v pe = *(const f4v*)(pp + (size_t)idx * 4);
    f4v o;
    s4v ob;
#pragma unroll
    for (int j = 0; j < 4; ++j) {
      o[j] = (v[j] - mean) * rstd * gam + bet + pe[j];
      ob[j] = (short)f2b(o[j]);
    }
    *(s4v*)(dst + (size_t)idx * 4) = ob;
    sum2 += o[0] + o[1] + o[2] + o[3];
    sq2 += o[0] * o[0] + o[1] * o[1] + o[2] * o[2] + o[3] * o[3];
  }
#pragma unroll
  for (int off = 1; off < 64; off <<= 1) { sum2 += __shfl_xor(sum2, off); sq2 += __shfl_xor(sq2, off); }
  if (l == 0) { red[w * 2] = sum2; red[w * 2 + 1] = sq2; }
  __syncthreads();
  if (tid == 0) {
    float S2 = red[0] + red[2] + red[4] + red[6];
    float Q2 = red[1] + red[3] + red[5] + red[7];
    float m2 = S2 * (1.f / 16384.f);
    float v2 = Q2 * (1.f / 16384.f) - m2 * m2;
    mu2[b * 32 + g] = m2;
    rs2[b * 32 + g] = rsqrtf(v2 + 1e-6f);
  }
}

// ---------------------------------------------------------------------------
// transpose xb (NCHW bf16) -> xt (token-major bf16) and sh = GN2(x) (token-major)
// ---------------------------------------------------------------------------
__global__ __launch_bounds__(256) void trans_gn2(
    const u16* __restrict__ xb, const float* __restrict__ mu2, const float* __restrict__ rs2,
    const float* __restrict__ ng, const float* __restrict__ nb,
    u16* __restrict__ xt, u16* __restrict__ sh)
{
  __shared__ float lds[512 * 17];
  int st = blockIdx.x, b = blockIdx.y;
  int tid = threadIdx.x;
  const u16* xp = xb + (size_t)b * 512 * 1024 + st * 16;
#pragma unroll
  for (int i = 0; i < 4; ++i) {
    int idx = tid + i * 256;       // 1024 chunks of 8 u16 = 512c x 2
    int c = idx >> 1, sq = (idx & 1) * 8;
    s8v v = *(const s8v*)(xp + (size_t)c * 1024 + sq);
#pragma unroll
    for (int j = 0; j < 8; ++j) lds[c * 17 + sq + j] = b2f((u16)v[j]);
  }
  __syncthreads();
  int s = tid & 15, cb0 = (tid >> 4) * 32;
  size_t token = (size_t)b * 1024 + st * 16 + s;
  float m0 = mu2[b * 32 + (cb0 >> 4)], m1 = mu2[b * 32 + (cb0 >> 4) + 1];
  float r0 = rs2[b * 32 + (cb0 >> 4)], r1 = rs2[b * 32 + (cb0 >> 4) + 1];
#pragma unroll
  for (int q = 0; q < 4; ++q) {
    s8v ox, os;
#pragma unroll
    for (int j = 0; j < 8; ++j) {
      int cj = q * 8 + j;
      int c = cb0 + cj;
      float v = lds[c * 17 + s];
      ox[j] = (short)f2b(v);
      float mm = (cj < 16) ? m0 : m1;
      float rr = (cj < 16) ? r0 : r1;
      os[j] = (short)f2b((v - mm) * rr * ng[c] + nb[c]);
    }
    *(s8v*)(xt + token * 512 + cb0 + q * 8) = ox;
    *(s8v*)(sh + token * 512 + cb0 + q * 8) = os;
  }
}

// ---------------------------------------------------------------------------
// generic bf16 MFMA GEMM: C[M][ldc] = A[M][lda] * Bw[N][ldb]^T  (+bias, +silu,
// +per-row scale). 1-D grid, XCD-swizzled, mt-group-4 L2 panel ordering.
// Single-buffered LDS; implicit wave-level overlap at ~5 blocks/CU.
// ---------------------------------------------------------------------------
template <int BM, int BN, bool SILU, bool OUT32, bool BIAS, bool RSCALE>
__global__ __launch_bounds__(256, 2) void gemm_k(
    const u16* __restrict__ A, int lda,
    const u16* __restrict__ Bw, int ldb,
    void* __restrict__ Cp, int ldc,
    const float* __restrict__ bias, int K, int ntx,
    const float* __restrict__ rscale)
{
  constexpr int WMT = BM / 2, WNT = BN / 2, MF = WMT / 16, NF = WNT / 16;
  __shared__ u16 Al[BM * 64];
  __shared__ u16 Bl[BN * 64];
  const int tid = threadIdx.x, l = tid & 63, w = tid >> 6;
  const int lg = l >> 4, lr = l & 15;
  const int wm = w >> 1, wn = w & 1;
  const int flat = blockIdx.x;
  const int cpx = gridDim.x >> 3;
  const int id = (flat & 7) * cpx + (flat >> 3);
  const int grp = id / (ntx * 4), rem = id % (ntx * 4);
  const int nt = rem >> 2, mt = grp * 4 + (rem & 3);
  const u16* Ag = A + (size_t)mt * BM * lda;
  const u16* Bg = Bw + (size_t)nt * BN * ldb;
  const f4v z = {0.f, 0.f, 0.f, 0.f};
  f4v acc[MF][NF];
#pragma unroll
  for (int i = 0; i < MF; ++i)
#pragma unroll
    for (int j = 0; j < NF; ++j) acc[i][j] = z;

  for (int kt = 0; kt < K; kt += 64) {
    __syncthreads();
    for (int f = tid; f < BM * 8; f += 256) {
      int row = f >> 3, g = (f & 7) ^ (row & 7);
      gload16(Ag + (size_t)row * lda + kt + g * 8, (char*)Al + f * 16);
    }
    for (int f = tid; f < BN * 8; f += 256) {
      int row = f >> 3, g = (f & 7) ^ (row & 7);
      gload16(Bg + (size_t)row * ldb + kt + g * 8, (char*)Bl + f * 16);
    }
    __syncthreads();
#pragma unroll
    for (int ks = 0; ks < 2; ++ks) {
      s8v af[MF], bf[NF];
#pragma unroll
      for (int mf = 0; mf < MF; ++mf) {
        int row = wm * WMT + mf * 16 + lr;
        af[mf] = *(const s8v*)((const char*)Al + row * 128 + (((ks * 4 + lg) ^ (row & 7)) << 4));
      }
#pragma unroll
      for (int nf = 0; nf < NF; ++nf) {
        int row = wn * WNT + nf * 16 + lr;
        bf[nf] = *(const s8v*)((const char*)Bl + row * 128 + (((ks * 4 + lg) ^ (row & 7)) << 4));
      }
#pragma unroll
      for (int mf = 0; mf < MF; ++mf)
#pragma unroll
        for (int nf = 0; nf < NF; ++nf)
          acc[mf][nf] = MFMA16(af[mf], bf[nf], acc[mf][nf]);
    }
  }
#pragma unroll
  for (int mf = 0; mf < MF; ++mf) {
    int row0 = mt * BM + wm * WMT + mf * 16 + lg * 4;
#pragma unroll
    for (int nf = 0; nf < NF; ++nf) {
      int col = nt * BN + wn * WNT + nf * 16 + lr;
      float bv = BIAS ? bias[col] : 0.f;
#pragma unroll
      for (int r = 0; r < 4; ++r) {
        float v = acc[mf][nf][r] + bv;
        if (RSCALE) v *= rscale[row0 + r];
        if (SILU) v = v / (1.f + exp2f(-v * LOG2E));
        size_t off = (size_t)(row0 + r) * ldc + col;
        if (OUT32) ((float*)Cp)[off] = v;
        else ((u16*)Cp)[off] = f2b(v);
      }
    }
  }
}

// ---------------------------------------------------------------------------
// im2col for 3x3 conv
// ---------------------------------------------------------------------------
__global__ __launch_bounds__(256) void im2col_k(const u16* __restrict__ s1t, u16* __restrict__ col) {
  int gid = blockIdx.x * 256 + threadIdx.x;
  if (gid >= 8192 * 64) return;
  int token = gid >> 6, c = gid & 63;
  int s = token & 1023, y = s >> 5, xx = s & 31;
  u16* dst = col + (size_t)token * 576 + c * 9;
#pragma unroll
  for (int dy = 0; dy < 3; ++dy)
#pragma unroll
    for (int dx = 0; dx < 3; ++dx) {
      int yy = y + dy - 1, x2 = xx + dx - 1;
      u16 v = 0;
      if (yy >= 0 && yy < 32 && x2 >= 0 && x2 < 32)
        v = s1t[(size_t)(token + (dy - 1) * 32 + (dx - 1)) * 64 + c];
      dst[dy * 3 + dx] = v;
    }
}

// ---------------------------------------------------------------------------
// conv3 (1x1, 64->1) + sigmoid -> gate [8192] f32
// ---------------------------------------------------------------------------
__global__ __launch_bounds__(256) void conv3_k(
    const u16* __restrict__ s2t, const float* __restrict__ w3,
    const float* __restrict__ b3, float* __restrict__ gate)
{
  int token = blockIdx.x * 256 + threadIdx.x;
  if (token >= 8192) return;
  float acc = b3[0];
#pragma unroll
  for (int q = 0; q < 8; ++q) {
    s8v v = *(const s8v*)(s2t + (size_t)token * 64 + q * 8);
#pragma unroll
    for (int e = 0; e < 8; ++e) acc += b2f((u16)v[e]) * w3[q * 8 + e];
  }
  gate[token] = 1.f / (1.f + exp2f(-acc * LOG2E));
}

// ---------------------------------------------------------------------------
// V transpose: proj[token][col0 + hh*HD + d] -> out[(y)*HD + d][1024 keys]
// with per-64-key-block pi-permutation: position a*4+bb holds key bb*16+a.
// ---------------------------------------------------------------------------
template <int HD>
__global__ __launch_bounds__(256) void tv_k(const u16* __restrict__ proj, int col0,
                                            u16* __restrict__ out)
{
  __shared__ u16 tile[64][HD + 2];
  const int tid = threadIdx.x;
  const int kb = blockIdx.x, y = blockIdx.y;
  const int nh = 512 / HD;
  const int b = y / nh, hh = y % nh;
  const u16* src = proj + ((size_t)b * 1024 + kb * 64) * 2560 + col0 + hh * HD;
  for (int f = tid; f < 64 * HD / 8; f += 256) {
    int key = f / (HD / 8), c = f % (HD / 8);
    *(s8v*)&tile[key][c * 8] = *(const s8v*)(src + (size_t)key * 2560 + c * 8);
  }
  __syncthreads();
  u16* dst = out + (size_t)y * HD * 1024 + kb * 64;
  for (int idx = tid; idx < HD * 16; idx += 256) {
    int d = idx >> 4, a = idx & 15;
    u16 e0 = tile[a][d], e1 = tile[16 + a][d], e2 = tile[32 + a][d], e3 = tile[48 + a][d];
    u64 v = (u64)e0 | ((u64)e1 << 16) | ((u64)e2 << 32) | ((u64)e3 << 48);
    *(u64*)(dst + (size_t)d * 1024 + a * 4) = v;
  }
}

// ---------------------------------------------------------------------------
// standard MHA flash attention: hd=64, unnormalized flash.
// K/V dbuf LDS; staging pointers hoisted out of the K-loop (constant strides).
// ---------------------------------------------------------------------------
__global__ __launch_bounds__(256, 4) void attn_std(
    const u16* __restrict__ proj, const u16* __restrict__ vts, u16* __restrict__ comb)
{
  const int tid = threadIdx.x, l = tid & 63, w = tid >> 6;
  const int lg = l >> 4, lr = l & 15;
  const int flat = blockIdx.x;
  const int xcd = flat & 7, idx = flat >> 3;      // idx 0..127
  const int bh = xcd + 8 * (idx >> 4);            // 8 heads per XCD
  const int qt = idx & 15;
  const int b = bh >> 3, h = bh & 7;
  const size_t tokb = (size_t)b * 1024;
  __shared__ u16 Kl[2][64 * 64];
  __shared__ u16 Vl[2][64 * 64];
  __shared__ u16 Pl[4][16 * 64];
  const int qr0 = qt * 64 + w * 16;
  s8v qf[2];
#pragma unroll
  for (int ks = 0; ks < 2; ++ks)
    qf[ks] = *(const s8v*)(proj + (tokb + qr0 + lr) * 2560 + h * 64 + ks * 32 + lg * 8);
  const f4v z = {0.f, 0.f, 0.f, 0.f};
  f4v acc[4];
  float lsl[4] = {0.f, 0.f, 0.f, 0.f};
#pragma unroll
  for (int r = 0; r < 4; ++r) acc[r] = z;

  const u16* gk[2];
  const u16* gv[2];
  char* lk[2];
  char* lv[2];
#pragma unroll
  for (int j = 0; j < 2; ++j) {
    int f = tid + j * 256;
    int key = f >> 3, g = (f & 7) ^ (key & 7);
    gk[j] = proj + (tokb + key) * 2560 + 512 + h * 64 + g * 8;
    int c = (f & 7) ^ (key & 7);
    gv[j] = vts + (size_t)bh * 64 * 1024 + (size_t)key * 1024 + c * 8;
    lk[j] = (char*)&Kl[0][0] + f * 16;
    lv[j] = (char*)&Vl[0][0] + f * 16;
  }

  auto stage = [&](int buf) {
#pragma unroll
    for (int j = 0; j < 2; ++j) {
      gload16(gk[j], lk[j] + buf * 8192);
      gload16(gv[j], lv[j] + buf * 8192);
    }
#pragma unroll
    for (int j = 0; j < 2; ++j) { gk[j] += 64 * 2560; gv[j] += 64; }
  };

  stage(0);
  __syncthreads();
  int cur = 0;
  for (int kt = 0; kt < 16; ++kt) {
    if (kt < 15) stage(cur ^ 1);
    f4v sf[4];
#pragma unroll
    for (int nf = 0; nf < 4; ++nf) sf[nf] = z;
#pragma unroll
    for (int ks = 0; ks < 2; ++ks) {
      s8v kfr[4];
#pragma unroll
      for (int nf = 0; nf < 4; ++nf) {
        int row = nf * 16 + lr;
        kfr[nf] = *(const s8v*)((const char*)&Kl[cur][0] + row * 128 + (((ks * 4 + lg) ^ (row & 7)) << 4));
      }
#pragma unroll
      for (int nf = 0; nf < 4; ++nf) sf[nf] = MFMA16(qf[ks], kfr[nf], sf[nf]);
    }
#pragma unroll
    for (int r = 0; r < 4; ++r) {
      float pv[4];
#pragma unroll
      for (int nf = 0; nf < 4; ++nf) pv[nf] = exp2f(sf[nf][r]);
      lsl[r] += (pv[0] + pv[1]) + (pv[2] + pv[3]);
      int q = lg * 4 + r;
      u64 pk = (u64)cvtpk(pv[0], pv[1]) | ((u64)cvtpk(pv[2], pv[3]) << 32);
      *(u64*)((char*)&Pl[w][0] + q * 128 + ((((lr >> 1) ^ (q & 7)) << 4)) + (lr & 1) * 8) = pk;
    }
#pragma unroll
    for (int ks2 = 0; ks2 < 2; ++ks2) {
      int g = ks2 * 4 + lg;
      s8v pfr = *(const s8v*)((const char*)&Pl[w][0] + lr * 128 + ((g ^ (lr & 7)) << 4));
#pragma unroll
      for (int nf = 0; nf < 4; ++nf) {
        int d = nf * 16 + lr;
        s8v vfr = *(const s8v*)((const char*)&Vl[cur][0] + d * 128 + ((g ^ (d & 7)) << 4));
        acc[nf] = MFMA16(pfr, vfr, acc[nf]);
      }
    }
    __syncthreads();
    cur ^= 1;
  }
#pragma unroll
  for (int r = 0; r < 4; ++r) {
    float t = lsl[r];
#pragma unroll
    for (int off = 1; off < 16; off <<= 1) t += __shfl_xor(t, off);
    float inv = 1.f / t;
    size_t row = tokb + qr0 + lg * 4 + r;
#pragma unroll
    for (int nf = 0; nf < 4; ++nf)
      comb[row * 1024 + h * 64 + nf * 16 + lr] = f2b(acc[nf][r] * inv);
  }
}

// ---------------------------------------------------------------------------
// multi-scale attention: hd=256, K-split=2, unnormalized flash.
// K/V single-buffered LDS; staging pointers hoisted with constant strides.
// ---------------------------------------------------------------------------
__global__ __launch_bounds__(256, 2) void attn_ms(
    const u16* __restrict__ proj, const u16* __restrict__ qm, const u16* __restrict__ vtm,
    u16* __restrict__ pacc, float* __restrict__ pl)
{
  const int tid = threadIdx.x, l = tid & 63, w = tid >> 6;
  const int lg = l >> 4, lr = l & 15;
  const int flat = blockIdx.x;
  const int xcd = flat & 7, idx = flat >> 3;      // idx 0..63
  const int bp = xcd + 8 * (idx >> 5);            // 2 (b,p) pairs per XCD
  const int rest = idx & 31;
  const int qt = rest >> 1, ks = rest & 1;
  const int b = bp >> 1, p = bp & 1;
  const size_t tokb = (size_t)b * 1024;
  __shared__ u16 Kl[64 * 256];
  __shared__ u16 Vl[256 * 64];
  __shared__ u16 Pl[4][16 * 64];
  const int qr0 = qt * 64 + w * 16;
  s8v qf[8];
#pragma unroll
  for (int kf = 0; kf < 8; ++kf)
    qf[kf] = *(const s8v*)(qm + (tokb + qr0 + lr) * 512 + p * 256 + kf * 32 + lg * 8);
  const f4v z = {0.f, 0.f, 0.f, 0.f};
  f4v acc[16];
#pragma unroll
  for (int i = 0; i < 16; ++i) acc[i] = z;
  float lsl[4] = {0.f, 0.f, 0.f, 0.f};
  const u16* vbase = vtm + (size_t)bp * 256 * 1024;

  const u16* gk[8];
  const u16* gv[8];
#pragma unroll
  for (int j = 0; j < 8; ++j) {
    int f = tid + j * 256;
    int key = f >> 5, pgc = f & 31;
    int g = (pgc & 24) | ((pgc & 7) ^ (key & 7));
    gk[j] = proj + (tokb + ks * 512 + key) * 2560 + 1536 + p * 256 + g * 8;
    int d = f >> 3, c = (f & 7) ^ (d & 7);
    gv[j] = vbase + (size_t)d * 1024 + ks * 512 + c * 8;
  }

  for (int kk = 0; kk < 8; ++kk) {
    __syncthreads();
#pragma unroll
    for (int j = 0; j < 8; ++j) gload16(gk[j], (char*)Kl + (tid + j * 256) * 16);
#pragma unroll
    for (int j = 0; j < 8; ++j) gload16(gv[j], (char*)Vl + (tid + j * 256) * 16);
#pragma unroll
    for (int j = 0; j < 8; ++j) { gk[j] += 64 * 2560; gv[j] += 64; }
    __syncthreads();
    f4v sf[4];
#pragma unroll
    for (int nf = 0; nf < 4; ++nf) sf[nf] = z;
#pragma unroll
    for (int ksi = 0; ksi < 8; ++ksi) {
      s8v kfr[4];
#pragma unroll
      for (int nf = 0; nf < 4; ++nf) {
        int row = nf * 16 + lr;
        int g = ksi * 4 + lg;
        int pg2 = (g & 24) | ((g & 7) ^ (row & 7));
        kfr[nf] = *(const s8v*)((const char*)Kl + row * 512 + (pg2 << 4));
      }
#pragma unroll
      for (int nf = 0; nf < 4; ++nf) sf[nf] = MFMA16(qf[ksi], kfr[nf], sf[nf]);
    }
#pragma unroll
    for (int r = 0; r < 4; ++r) {
      float pv[4];
#pragma unroll
      for (int nf = 0; nf < 4; ++nf) pv[nf] = exp2f(sf[nf][r]);
      lsl[r] += (pv[0] + pv[1]) + (pv[2] + pv[3]);
      int q = lg * 4 + r;
      u64 pk = (u64)cvtpk(pv[0], pv[1]) | ((u64)cvtpk(pv[2], pv[3]) << 32);
      *(u64*)((char*)&Pl[w][0] + q * 128 + ((((lr >> 1) ^ (q & 7)) << 4)) + (lr & 1) * 8) = pk;
    }
#pragma unroll
    for (int ks2 = 0; ks2 < 2; ++ks2) {
      int g = ks2 * 4 + lg;
      s8v pfr = *(const s8v*)((const char*)&Pl[w][0] + lr * 128 + ((g ^ (lr & 7)) << 4));
#pragma unroll
      for (int nfd = 0; nfd < 16; ++nfd) {
        int d = nfd * 16 + lr;
        s8v vfr = *(const s8v*)((const char*)Vl + d * 128 + ((g ^ (d & 7)) << 4));
        acc[nfd] = MFMA16(pfr, vfr, acc[nfd]);
      }
    }
  }
#pragma unroll
  for (int r = 0; r < 4; ++r) {
    float t = lsl[r];
#pragma unroll
    for (int off = 1; off < 16; off <<= 1) t += __shfl_xor(t, off);
    size_t prow = ((size_t)(bp * 2 + ks) * 16 + qt) * 64 + w * 16 + lg * 4 + r;
#pragma unroll
    for (int nfd = 0; nfd < 16; ++nfd)
      pacc[prow * 256 + nfd * 16 + lr] = f2b(acc[nfd][r]);
    if (lr == 0) pl[prow] = t;
  }
}

// ---------------------------------------------------------------------------
// combine the 2 K-slices of attn_ms -> comb[:, 512:1024]  (shared exponent frame)
// ---------------------------------------------------------------------------
__global__ __launch_bounds__(256) void ms_comb(
    const u16* __restrict__ pacc, const float* __restrict__ pl,
    u16* __restrict__ comb)
{
  const int qt = blockIdx.x, bp = blockIdx.y;
  const int tid = threadIdx.x;
  const int row = tid >> 2, seg = tid & 3;
  size_t prow0 = ((size_t)(bp * 2 + 0) * 16 + qt) * 64 + row;
  size_t prow1 = ((size_t)(bp * 2 + 1) * 16 + qt) * 64 + row;
  float inv = 1.f / (pl[prow0] + pl[prow1]);
  const int b = bp >> 1, p = bp & 1;
  size_t orow = ((size_t)b * 1024 + qt * 64 + row) * 1024 + 512 + p * 256 + seg * 64;
#pragma unroll
  for (int j = 0; j < 8; ++j) {
    s8v v0 = *(const s8v*)(pacc + prow0 * 256 + seg * 64 + j * 8);
    s8v v1 = *(const s8v*)(pacc + prow1 * 256 + seg * 64 + j * 8);
    s8v ov;
#pragma unroll
    for (int e = 0; e < 8; ++e)
      ov[e] = (short)f2b((b2f((u16)v0[e]) + b2f((u16)v1[e])) * inv);
    *(s8v*)(comb + orow + j * 8) = ov;
  }
}

// ---------------------------------------------------------------------------
// GN3 stats over fin [8192][512] (bf16) per (b, group)
// ---------------------------------------------------------------------------
__global__ __launch_bounds__(256) void gn3_stats(
    const u16* __restrict__ fin, float* __restrict__ mu3, float* __restrict__ rs3)
{
  int bid = blockIdx.x;
  int b = bid >> 5, g = bid & 31;
  int tid = threadIdx.x, l = tid & 63, w = tid >> 6;
  const u16* fp = fin + (size_t)b * 1024 * 512 + g * 16;
  float sum = 0.f, sq = 0.f;
#pragma unroll
  for (int i = 0; i < 8; ++i) {
    int idx = tid + i * 256;       // 2048 chunks of 8 = 1024 tokens x 2
    int s = idx >> 1, half = (idx & 1) * 8;
    s8v v = *(const s8v*)(fp + (size_t)s * 512 + half);
#pragma unroll
    for (int e = 0; e < 8; ++e) { float f = b2f((u16)v[e]); sum += f; sq += f * f; }
  }
  __shared__ float red[8];
#pragma unroll
  for (int off = 1; off < 64; off <<= 1) { sum += __shfl_xor(sum, off); sq += __shfl_xor(sq, off); }
  if (l == 0) { red[w * 2] = sum; red[w * 2 + 1] = sq; }
  __syncthreads();
  if (tid == 0) {
    float S = red[0] + red[2] + red[4] + red[6];
    float Q = red[1] + red[3] + red[5] + red[7];
    float mean = S * (1.f / 16384.f);
    float var = Q * (1.f / 16384.f) - mean * mean;
    mu3[b * 32 + g] = mean;
    rs3[b * 32 + g] = rsqrtf(var + 1e-6f);
  }
}

// ---------------------------------------------------------------------------
// final: transpose fin (bf16) back to NCHW, apply GN3 + residual -> out (f32)
// ---------------------------------------------------------------------------
__global__ __launch_bounds__(256) void final_k(
    const u16* __restrict__ fin, const float* __restrict__ mu3, const float* __restrict__ rs3,
    const float* __restrict__ postg, const float* __restrict__ postb,
    const float* __restrict__ res, float* __restrict__ out)
{
  __shared__ float lds[16 * 513];
  int st = blockIdx.x, b = blockIdx.y;
  int tid = threadIdx.x;
  const u16* fp = fin + ((size_t)b * 1024 + st * 16) * 512;
#pragma unroll
  for (int i = 0; i < 4; ++i) {
    int idx = tid + i * 256;   // 1024 chunks of 8 = 16 s x 64
    int s = idx >> 6, c8 = (idx & 63) * 8;
    s8v v = *(const s8v*)(fp + (size_t)s * 512 + c8);
#pragma unroll
    for (int j = 0; j < 8; ++j) lds[s * 513 + c8 + j] = b2f((u16)v[j]);
  }
  __syncthreads();
#pragma unroll
  for (int cc = 0; cc < 2; ++cc) {
    int c = tid * 2 + cc;
    int g = c >> 4;
    float m = mu3[b * 32 + g], rv = rs3[b * 32 + g];
    float ga = postg[c], be = postb[c];
    const float* rp = res + ((size_t)b * 512 + c) * 1024 + st * 16;
    float* op = out + ((size_t)b * 512 + c) * 1024 + st * 16;
#pragma unroll
    for (int q = 0; q < 4; ++q) {
      f4v rr = *(const f4v*)(rp + q * 4);
      f4v o;
#pragma unroll
      for (int j = 0; j < 4; ++j) {
        float v = lds[(q * 4 + j) * 513 + c];
        o[j] = (v - m) * rv * ga + be + rr[j];
      }
      *(f4v*)(op + q * 4) = o;
    }
  }
}

// ---------------------------------------------------------------------------
extern "C" void kernel_launch(void* const* d_in, const int* in_sizes, int n_in,
                              void* d_out, int out_size, void* d_ws, size_t ws_size,
                              hipStream_t stream) {
  (void)in_sizes; (void)n_in; (void)out_size; (void)ws_size;
  const float* hs     = (const float*)d_in[0];
  const float* pre_g  = (const float*)d_in[1];
  const float* pre_b  = (const float*)d_in[2];
  const float* norm_g = (const float*)d_in[3];
  const float* norm_b = (const float*)d_in[4];
  const float* post_g = (const float*)d_in[5];
  const float* post_b = (const float*)d_in[6];
  const float* pos    = (const float*)d_in[7];
  const float* sa_b1  = (const float*)d_in[18];
  const float* sa_b2  = (const float*)d_in[20];
  const float* sa_w3  = (const float*)d_in[21];
  const float* sa_b3  = (const float*)d_in[22];
  const float* ff_b1  = (const float*)d_in[24];
  const float* ff_b2  = (const float*)d_in[26];
  const float* out_b  = (const float*)d_in[28];

  char* ws = (char*)d_ws;
  size_t off = 0;
  auto alloc = [&](size_t bytes) -> void* {
    void* pp = ws + off;
    off += (bytes + 255) & ~(size_t)255;
    return pp;
  };
  float* x    = (float*)alloc((size_t)16777216);       // region: xb -> pacc -> fin
  u16* sh     = (u16*)alloc((size_t)8388608);          // [8192][512] bf16
  u16* xt     = (u16*)alloc((size_t)8388608);          // [8192][512] bf16
  float* mu2  = (float*)alloc(1024);
  float* rs2  = (float*)alloc(1024);
  float* mu3  = (float*)alloc(1024);
  float* rs3  = (float*)alloc(1024);
  float* pl   = (float*)alloc(262144);                 // [32][16][64]
  u16* wcat   = (u16*)alloc((size_t)2691072 * 2);      // all bf16 weights
  u16* proj   = (u16*)alloc((size_t)8192 * 2560 * 2);  // q|k|v|k0|k1|v0|v1
  u16* qmb    = (u16*)alloc((size_t)8388608);          // [8192][512]
  u16* s1t    = (u16*)alloc((size_t)1048576);          // [8192][64]
  u16* colb   = (u16*)alloc((size_t)8192 * 576 * 2);   // im2col; reused as vts
  u16* s2t    = (u16*)alloc((size_t)1048576);          // [8192][64]
  float* gate = (float*)alloc((size_t)32768);          // [8192]
  u16* vtm    = (u16*)alloc((size_t)8388608);          // [512 d][1024 keys] x 16
  u16* comb   = (u16*)alloc((size_t)16777216);         // [8192][1024]
  u16* f1     = (u16*)alloc((size_t)8388608);
  u16* f2     = (u16*)alloc((size_t)8388608);
  u16* xb     = (u16*)x;                               // bf16 NCHW x (8MB over x)
  u16* pacc   = (u16*)x;                               // 16MB over x (after xb dead)
  u16* fin    = (u16*)x;                               // bf16 [8192][512] (after pacc dead)
  u16* vts    = colb;                                  // 8MB over colb

  u16* Wbig = wcat;                 // [2560][512]
  u16* Wq01 = wcat + 1310720;       // [512][512]
  u16* W1   = wcat + 1572864;       // [64][512]
  u16* W2   = wcat + 1605632;       // [64][576]
  u16* Wff1 = wcat + 1642496;       // [512][1024]
  u16* Wff2 = wcat + 2166784;       // [512][512]
  u16* Wout = wcat + 2428928;       // [512][512]

  Segs sg;
  const int srcidx[14] = {8, 9, 10, 13, 14, 15, 16, 11, 12, 17, 19, 23, 25, 27};
  const int segsz[14] = {262144, 262144, 262144, 131072, 131072, 131072, 131072,
                         131072, 131072, 32768, 36864, 524288, 262144, 262144};
  int cum = 0;
  for (int i = 0; i < 14; ++i) {
    sg.src[i] = (const float*)d_in[srcidx[i]];
    sg.cum[i] = cum;
    sg.scl[i] = 1.f;
    cum += segsz[i];
  }
  sg.cum[14] = cum;   // 2691072
  sg.scl[0] = 0.125f * LOG2E;    // wq  : 1/sqrt(64) * log2(e)
  sg.scl[7] = 0.0625f * LOG2E;   // wq0 : 1/sqrt(256) * log2(e)
  sg.scl[8] = 0.0625f * LOG2E;   // wq1

  dim3 blk(256);
  castk<<<2628, blk, 0, stream>>>(sg, wcat);
  gn1_k<<<256, blk, 0, stream>>>(hs, pre_g, pre_b, pos, xb, mu2, rs2);
  trans_gn2<<<dim3(64, 8), blk, 0, stream>>>(xb, mu2, rs2, norm_g, norm_b, xt, sh);
  // fused qkv + multiscale k/v projection: [8192][512] x [2560][512]^T
  gemm_k<128, 128, false, false, false, false><<<1280, blk, 0, stream>>>(
      sh, 512, Wbig, 512, proj, 2560, nullptr, 512, 20, nullptr);
  // spatial gate path
  gemm_k<64, 64, true, false, true, false><<<128, blk, 0, stream>>>(
      xt, 512, W1, 512, s1t, 64, sa_b1, 512, 1, nullptr);
  im2col_k<<<2048, blk, 0, stream>>>(s1t, colb);
  gemm_k<64, 64, true, false, true, false><<<128, blk, 0, stream>>>(
      colb, 576, W2, 576, s2t, 64, sa_b2, 576, 1, nullptr);
  conv3_k<<<32, blk, 0, stream>>>(s2t, sa_w3, sa_b3, gate);
  // qm = diag(gate) @ (xt @ Wq01^T)  — gate folded into GEMM epilogue
  gemm_k<128, 64, false, false, false, true><<<512, blk, 0, stream>>>(
      xt, 512, Wq01, 512, qmb, 512, nullptr, 512, 8, gate);
  // V transposes (pi-permuted); colb dead by now
  tv_k<64><<<dim3(16, 64), blk, 0, stream>>>(proj, 1024, vts);
  tv_k<256><<<dim3(16, 16), blk, 0, stream>>>(proj, 2048, vtm);
  // attention
  attn_std<<<1024, blk, 0, stream>>>(proj, vts, comb);
  attn_ms<<<512, blk, 0, stream>>>(proj, qmb, vtm, pacc, pl);
  ms_comb<<<dim3(16, 16), blk, 0, stream>>>(pacc, pl, comb);
  // feed-forward + out projection (fin in bf16)
  gemm_k<128, 64, true, false, true, false><<<512, blk, 0, stream>>>(
      comb, 1024, Wff1, 1024, f1, 512, ff_b1, 1024, 8, nullptr);
  gemm_k<128, 64, false, false, true, false><<<512, blk, 0, stream>>>(
      f1, 512, Wff2, 512, f2, 512, ff_b2, 512, 8, nullptr);
  gemm_k<128, 64, false, false, true, false><<<512, blk, 0, stream>>>(
      f2, 512, Wout, 512, fin, 512, out_b, 512, 8, nullptr);
  // final group norm + residual
  gn3_stats<<<256, blk, 0, stream>>>(fin, mu3, rs3);
  final_k<<<dim3(64, 8), blk, 0, stream>>>(fin, mu3, rs3, post_g, post_b, hs, (float*)d_out);
}

// Round 12
// 245.198 us; speedup vs baseline: 1.0966x; 1.0257x over previous
//
#include <hip/hip_runtime.h>

typedef unsigned short u16;
typedef unsigned long long u64;
typedef __attribute__((ext_vector_type(8))) short s8v;   // 8 x bf16 bits (4 VGPR)
typedef __attribute__((ext_vector_type(4))) short s4v;
typedef __attribute__((ext_vector_type(4))) float f4v;

#define LOG2E 1.4426950408889634f

__device__ __forceinline__ float b2f(u16 u) {
  union { unsigned u; float f; } x; x.u = ((unsigned)u) << 16; return x.f;
}
__device__ __forceinline__ u16 f2b(float f) {
  union { float f; unsigned u; } x; x.f = f;
  unsigned r = x.u + 0x7fffu + ((x.u >> 16) & 1u);
  return (u16)(r >> 16);
}
// packed f32x2 -> bf16x2 (single VALU op; RTE)
__device__ __forceinline__ unsigned cvtpk(float lo, float hi) {
  unsigned r;
  asm("v_cvt_pk_bf16_f32 %0, %1, %2" : "=v"(r) : "v"(lo), "v"(hi));
  return r;
}

#define MFMA16(a, b, c) __builtin_amdgcn_mfma_f32_16x16x32_bf16((a), (b), (c), 0, 0, 0)

__device__ __forceinline__ void gload16(const void* g, void* l) {
  __builtin_amdgcn_global_load_lds(
      (const __attribute__((address_space(1))) unsigned*)g,
      (__attribute__((address_space(3))) unsigned*)l, 16, 0, 0);
}

// ---------------------------------------------------------------------------
// weight cast: 14 f32 segments -> one contiguous bf16 region (with per-seg scale)
// ---------------------------------------------------------------------------
struct Segs {
  const float* src[14];
  int cum[15];
  float scl[14];
};

__global__ __launch_bounds__(256) void castk(Segs sg, u16* __restrict__ dst) {
  int gid = (blockIdx.x * 256 + threadIdx.x) * 4;
  if (gid >= sg.cum[14]) return;
  int s = 0;
  while (gid >= sg.cum[s + 1]) ++s;
  const float* sp = sg.src[s] + (gid - sg.cum[s]);
  float sc = sg.scl[s];
  f4v v = *(const f4v*)sp;
  s4v o;
  o[0] = (short)f2b(v[0] * sc); o[1] = (short)f2b(v[1] * sc);
  o[2] = (short)f2b(v[2] * sc); o[3] = (short)f2b(v[3] * sc);
  *(s4v*)(dst + gid) = o;
}

// ---------------------------------------------------------------------------
// GN1: group_norm(hidden, pre) + pos_emb -> xb (NCHW bf16); stats of x for GN2.
// ---------------------------------------------------------------------------
__global__ __launch_bounds__(256) void gn1_k(
    const float* __restrict__ hs, const float* __restrict__ pg, const float* __restrict__ pb,
    const float* __restrict__ pos, u16* __restrict__ xb,
    float* __restrict__ mu2, float* __restrict__ rs2)
{
  int bid = blockIdx.x;
  int b = bid >> 5, g = bid & 31;
  int tid = threadIdx.x, l = tid & 63, w = tid >> 6;
  const float* src = hs + ((size_t)b * 512 + g * 16) * 1024;
  const float* pp = pos + (size_t)(g * 16) * 1024;
  u16* dst = xb + ((size_t)b * 512 + g * 16) * 1024;
  f4v vals[16];
  float sum = 0.f, sq = 0.f;
#pragma unroll
  for (int i = 0; i < 16; ++i) {
    int idx = tid + i * 256;
    vals[i] = *(const f4v*)(src + (size_t)idx * 4);
    f4v v = vals[i];
    sum += v[0] + v[1] + v[2] + v[3];
    sq += v[0] * v[0] + v[1] * v[1] + v[2] * v[2] + v[3] * v[3];
  }
  __shared__ float red[8];
#pragma unroll
  for (int off = 1; off < 64; off <<= 1) { sum += __shfl_xor(sum, off); sq += __shfl_xor(sq, off); }
  if (l == 0) { red[w * 2] = sum; red[w * 2 + 1] = sq; }
  __syncthreads();
  float S = red[0] + red[2] + red[4] + red[6];
  float Q = red[1] + red[3] + red[5] + red[7];
  float mean = S * (1.f / 16384.f);
  float var = Q * (1.f / 16384.f) - mean * mean;
  float rstd = rsqrtf(var + 1e-6f);
  __syncthreads();
  float sum2 = 0.f, sq2 = 0.f;
#pragma unroll
  for (int i = 0; i < 16; ++i) {
    int idx = tid + i * 256;
    int c = idx >> 8;
    float gam = pg[g * 16 + c], bet = pb[g * 16 + c];
    f4v v = vals[i];
    f4v pe = *(const f4v*)(pp + (size_t)idx * 4);
    f4v o;
    s4v ob;
#pragma unroll
    for (int j = 0; j < 4; ++j) {
      o[j] = (v[j] - mean) * rstd * gam + bet + pe[j];
      ob[j] = (short)f2b(o[j]);
    }
    *(s4v*)(dst + (size_t)idx * 4) = ob;
    sum2 += o[0] + o[1] + o[2] + o[3];
    sq2 += o[0] * o[0] + o[1] * o[1] + o[2] * o[2] + o[3] * o[3];
  }
#pragma unroll
  for (int off = 1; off < 64; off <<= 1) { sum2 += __shfl_xor(sum2, off); sq2 += __shfl_xor(sq2, off); }
  if (l == 0) { red[w * 2] = sum2; red[w * 2 + 1] = sq2; }
  __syncthreads();
  if (tid == 0) {
    float S2 = red[0] + red[2] + red[4] + red[6];
    float Q2 = red[1] + red[3] + red[5] + red[7];
    float m2 = S2 * (1.f / 16384.f);
    float v2 = Q2 * (1.f / 16384.f) - m2 * m2;
    mu2[b * 32 + g] = m2;
    rs2[b * 32 + g] = rsqrtf(v2 + 1e-6f);
  }
}

// ---------------------------------------------------------------------------
// transpose xb (NCHW bf16) -> xt (token-major bf16) and sh = GN2(x) (token-major)
// ---------------------------------------------------------------------------
__global__ __launch_bounds__(256) void trans_gn2(
    const u16* __restrict__ xb, const float* __restrict__ mu2, const float* __restrict__ rs2,
    const float* __restrict__ ng, const float* __restrict__ nb,
    u16* __restrict__ xt, u16* __restrict__ sh)
{
  __shared__ float lds[512 * 17];
  int st = blockIdx.x, b = blockIdx.y;
  int tid = threadIdx.x;
  const u16* xp = xb + (size_t)b * 512 * 1024 + st * 16;
#pragma unroll
  for (int i = 0; i < 4; ++i) {
    int idx = tid + i * 256;       // 1024 chunks of 8 u16 = 512c x 2
    int c = idx >> 1, sq = (idx & 1) * 8;
    s8v v = *(const s8v*)(xp + (size_t)c * 1024 + sq);
#pragma unroll
    for (int j = 0; j < 8; ++j) lds[c * 17 + sq + j] = b2f((u16)v[j]);
  }
  __syncthreads();
  int s = tid & 15, cb0 = (tid >> 4) * 32;
  size_t token = (size_t)b * 1024 + st * 16 + s;
  float m0 = mu2[b * 32 + (cb0 >> 4)], m1 = mu2[b * 32 + (cb0 >> 4) + 1];
  float r0 = rs2[b * 32 + (cb0 >> 4)], r1 = rs2[b * 32 + (cb0 >> 4) + 1];
#pragma unroll
  for (int q = 0; q < 4; ++q) {
    s8v ox, os;
#pragma unroll
    for (int j = 0; j < 8; ++j) {
      int cj = q * 8 + j;
      int c = cb0 + cj;
      float v = lds[c * 17 + s];
      ox[j] = (short)f2b(v);
      float mm = (cj < 16) ? m0 : m1;
      float rr = (cj < 16) ? r0 : r1;
      os[j] = (short)f2b((v - mm) * rr * ng[c] + nb[c]);
    }
    *(s8v*)(xt + token * 512 + cb0 + q * 8) = ox;
    *(s8v*)(sh + token * 512 + cb0 + q * 8) = os;
  }
}

// ---------------------------------------------------------------------------
// generic bf16 MFMA GEMM: C[M][ldc] = A[M][lda] * Bw[N][ldb]^T  (+bias, +silu,
// +per-row scale). 1-D grid, XCD-swizzled, mt-group-4 L2 panel ordering.
// Single-buffered LDS; implicit wave-level overlap at ~5 blocks/CU.
// ---------------------------------------------------------------------------
template <int BM, int BN, bool SILU, bool OUT32, bool BIAS, bool RSCALE>
__global__ __launch_bounds__(256, 2) void gemm_k(
    const u16* __restrict__ A, int lda,
    const u16* __restrict__ Bw, int ldb,
    void* __restrict__ Cp, int ldc,
    const float* __restrict__ bias, int K, int ntx,
    const float* __restrict__ rscale)
{
  constexpr int WMT = BM / 2, WNT = BN / 2, MF = WMT / 16, NF = WNT / 16;
  __shared__ u16 Al[BM * 64];
  __shared__ u16 Bl[BN * 64];
  const int tid = threadIdx.x, l = tid & 63, w = tid >> 6;
  const int lg = l >> 4, lr = l & 15;
  const int wm = w >> 1, wn = w & 1;
  const int flat = blockIdx.x;
  const int cpx = gridDim.x >> 3;
  const int id = (flat & 7) * cpx + (flat >> 3);
  const int grp = id / (ntx * 4), rem = id % (ntx * 4);
  const int nt = rem >> 2, mt = grp * 4 + (rem & 3);
  const u16* Ag = A + (size_t)mt * BM * lda;
  const u16* Bg = Bw + (size_t)nt * BN * ldb;
  const f4v z = {0.f, 0.f, 0.f, 0.f};
  f4v acc[MF][NF];
#pragma unroll
  for (int i = 0; i < MF; ++i)
#pragma unroll
    for (int j = 0; j < NF; ++j) acc[i][j] = z;

  for (int kt = 0; kt < K; kt += 64) {
    __syncthreads();
    for (int f = tid; f < BM * 8; f += 256) {
      int row = f >> 3, g = (f & 7) ^ (row & 7);
      gload16(Ag + (size_t)row * lda + kt + g * 8, (char*)Al + f * 16);
    }
    for (int f = tid; f < BN * 8; f += 256) {
      int row = f >> 3, g = (f & 7) ^ (row & 7);
      gload16(Bg + (size_t)row * ldb + kt + g * 8, (char*)Bl + f * 16);
    }
    __syncthreads();
#pragma unroll
    for (int ks = 0; ks < 2; ++ks) {
      s8v af[MF], bf[NF];
#pragma unroll
      for (int mf = 0; mf < MF; ++mf) {
        int row = wm * WMT + mf * 16 + lr;
        af[mf] = *(const s8v*)((const char*)Al + row * 128 + (((ks * 4 + lg) ^ (row & 7)) << 4));
      }
#pragma unroll
      for (int nf = 0; nf < NF; ++nf) {
        int row = wn * WNT + nf * 16 + lr;
        bf[nf] = *(const s8v*)((const char*)Bl + row * 128 + (((ks * 4 + lg) ^ (row & 7)) << 4));
      }
#pragma unroll
      for (int mf = 0; mf < MF; ++mf)
#pragma unroll
        for (int nf = 0; nf < NF; ++nf)
          acc[mf][nf] = MFMA16(af[mf], bf[nf], acc[mf][nf]);
    }
  }
#pragma unroll
  for (int mf = 0; mf < MF; ++mf) {
    int row0 = mt * BM + wm * WMT + mf * 16 + lg * 4;
#pragma unroll
    for (int nf = 0; nf < NF; ++nf) {
      int col = nt * BN + wn * WNT + nf * 16 + lr;
      float bv = BIAS ? bias[col] : 0.f;
#pragma unroll
      for (int r = 0; r < 4; ++r) {
        float v = acc[mf][nf][r] + bv;
        if (RSCALE) v *= rscale[row0 + r];
        if (SILU) v = v / (1.f + exp2f(-v * LOG2E));
        size_t off = (size_t)(row0 + r) * ldc + col;
        if (OUT32) ((float*)Cp)[off] = v;
        else ((u16*)Cp)[off] = f2b(v);
      }
    }
  }
}

// ---------------------------------------------------------------------------
// gate GEMM: s2 = silu(col @ W2^T + b2) (64x64 per block, all channels), then
// gate[token] = sigmoid(s2[token,:] . w3 + b3) fused in-epilogue (conv3 fold).
// grid = 128 blocks (tokens/64), ntx = 1.
// ---------------------------------------------------------------------------
__global__ __launch_bounds__(256, 2) void gemm_gate_k(
    const u16* __restrict__ A, int lda,
    const u16* __restrict__ Bw, int ldb,
    const float* __restrict__ bias, int K,
    const float* __restrict__ w3, const float* __restrict__ b3,
    float* __restrict__ gate)
{
  constexpr int BM = 64, BN = 64, WMT = 32, WNT = 32, MF = 2, NF = 2;
  __shared__ u16 Al[BM * 64];
  __shared__ u16 Bl[BN * 64];
  __shared__ float gt[64][68];
  const int tid = threadIdx.x, l = tid & 63, w = tid >> 6;
  const int lg = l >> 4, lr = l & 15;
  const int wm = w >> 1, wn = w & 1;
  const int flat = blockIdx.x;
  const int cpx = gridDim.x >> 3;
  const int mt = (flat & 7) * cpx + (flat >> 3);
  const u16* Ag = A + (size_t)mt * BM * lda;
  const u16* Bg = Bw;
  const f4v z = {0.f, 0.f, 0.f, 0.f};
  f4v acc[MF][NF];
#pragma unroll
  for (int i = 0; i < MF; ++i)
#pragma unroll
    for (int j = 0; j < NF; ++j) acc[i][j] = z;

  for (int kt = 0; kt < K; kt += 64) {
    __syncthreads();
    for (int f = tid; f < BM * 8; f += 256) {
      int row = f >> 3, g = (f & 7) ^ (row & 7);
      gload16(Ag + (size_t)row * lda + kt + g * 8, (char*)Al + f * 16);
    }
    for (int f = tid; f < BN * 8; f += 256) {
      int row = f >> 3, g = (f & 7) ^ (row & 7);
      gload16(Bg + (size_t)row * ldb + kt + g * 8, (char*)Bl + f * 16);
    }
    __syncthreads();
#pragma unroll
    for (int ks = 0; ks < 2; ++ks) {
      s8v af[MF], bf[NF];
#pragma unroll
      for (int mf = 0; mf < MF; ++mf) {
        int row = wm * WMT + mf * 16 + lr;
        af[mf] = *(const s8v*)((const char*)Al + row * 128 + (((ks * 4 + lg) ^ (row & 7)) << 4));
      }
#pragma unroll
      for (int nf = 0; nf < NF; ++nf) {
        int row = wn * WNT + nf * 16 + lr;
        bf[nf] = *(const s8v*)((const char*)Bl + row * 128 + (((ks * 4 + lg) ^ (row & 7)) << 4));
      }
#pragma unroll
      for (int mf = 0; mf < MF; ++mf)
#pragma unroll
        for (int nf = 0; nf < NF; ++nf)
          acc[mf][nf] = MFMA16(af[mf], bf[nf], acc[mf][nf]);
    }
  }
  __syncthreads();
#pragma unroll
  for (int mf = 0; mf < MF; ++mf) {
    int lrow0 = wm * WMT + mf * 16 + lg * 4;
#pragma unroll
    for (int nf = 0; nf < NF; ++nf) {
      int col = wn * WNT + nf * 16 + lr;
      float bv = bias[col];
#pragma unroll
      for (int r = 0; r < 4; ++r) {
        float v = acc[mf][nf][r] + bv;
        v = v / (1.f + exp2f(-v * LOG2E));
        gt[lrow0 + r][col] = v;
      }
    }
  }
  __syncthreads();
  if (tid < 64) {
    float a = b3[0];
    for (int c = 0; c < 64; ++c) a += gt[tid][c] * w3[c];
    gate[mt * 64 + tid] = 1.f / (1.f + exp2f(-a * LOG2E));
  }
}

// ---------------------------------------------------------------------------
// im2col for 3x3 conv
// ---------------------------------------------------------------------------
__global__ __launch_bounds__(256) void im2col_k(const u16* __restrict__ s1t, u16* __restrict__ col) {
  int gid = blockIdx.x * 256 + threadIdx.x;
  if (gid >= 8192 * 64) return;
  int token = gid >> 6, c = gid & 63;
  int s = token & 1023, y = s >> 5, xx = s & 31;
  u16* dst = col + (size_t)token * 576 + c * 9;
#pragma unroll
  for (int dy = 0; dy < 3; ++dy)
#pragma unroll
    for (int dx = 0; dx < 3; ++dx) {
      int yy = y + dy - 1, x2 = xx + dx - 1;
      u16 v = 0;
      if (yy >= 0 && yy < 32 && x2 >= 0 && x2 < 32)
        v = s1t[(size_t)(token + (dy - 1) * 32 + (dx - 1)) * 64 + c];
      dst[dy * 3 + dx] = v;
    }
}

// ---------------------------------------------------------------------------
// merged V transpose: y < 64 -> std heads (HD=64, col0=1024, vts);
// y >= 64 -> ms paths (HD=256, col0=2048, vtm). pi-permuted per 64-key block.
// ---------------------------------------------------------------------------
__global__ __launch_bounds__(256) void tvm_k(const u16* __restrict__ proj,
                                             u16* __restrict__ vts, u16* __restrict__ vtm)
{
  __shared__ u16 tile[64][258];
  const int tid = threadIdx.x;
  const int kb = blockIdx.x, y = blockIdx.y;
  int hd, col0, b, hh;
  u16* outp;
  if (y < 64) { hd = 64; col0 = 1024; b = y >> 3; hh = y & 7; outp = vts + (size_t)y * 64 * 1024; }
  else { int y2 = y - 64; hd = 256; col0 = 2048; b = y2 >> 1; hh = y2 & 1; outp = vtm + (size_t)y2 * 256 * 1024; }
  const int hd8 = hd >> 3;
  const u16* src = proj + ((size_t)b * 1024 + kb * 64) * 2560 + col0 + hh * hd;
  for (int f = tid; f < 64 * hd8; f += 256) {
    int key = f / hd8, c = f % hd8;
    *(s8v*)&tile[key][c * 8] = *(const s8v*)(src + (size_t)key * 2560 + c * 8);
  }
  __syncthreads();
  u16* dst = outp + kb * 64;
  for (int idx = tid; idx < hd * 16; idx += 256) {
    int d = idx >> 4, a = idx & 15;
    u16 e0 = tile[a][d], e1 = tile[16 + a][d], e2 = tile[32 + a][d], e3 = tile[48 + a][d];
    u64 v = (u64)e0 | ((u64)e1 << 16) | ((u64)e2 << 32) | ((u64)e3 << 48);
    *(u64*)(dst + (size_t)d * 1024 + a * 4) = v;
  }
}

// ---------------------------------------------------------------------------
// standard MHA flash attention: hd=64, unnormalized flash.
// K/V dbuf LDS; staging pointers hoisted out of the K-loop (constant strides).
// ---------------------------------------------------------------------------
__global__ __launch_bounds__(256, 4) void attn_std(
    const u16* __restrict__ proj, const u16* __restrict__ vts, u16* __restrict__ comb)
{
  const int tid = threadIdx.x, l = tid & 63, w = tid >> 6;
  const int lg = l >> 4, lr = l & 15;
  const int flat = blockIdx.x;
  const int xcd = flat & 7, idx = flat >> 3;      // idx 0..127
  const int bh = xcd + 8 * (idx >> 4);            // 8 heads per XCD
  const int qt = idx & 15;
  const int b = bh >> 3, h = bh & 7;
  const size_t tokb = (size_t)b * 1024;
  __shared__ u16 Kl[2][64 * 64];
  __shared__ u16 Vl[2][64 * 64];
  __shared__ u16 Pl[4][16 * 64];
  const int qr0 = qt * 64 + w * 16;
  s8v qf[2];
#pragma unroll
  for (int ks = 0; ks < 2; ++ks)
    qf[ks] = *(const s8v*)(proj + (tokb + qr0 + lr) * 2560 + h * 64 + ks * 32 + lg * 8);
  const f4v z = {0.f, 0.f, 0.f, 0.f};
  f4v acc[4];
  float lsl[4] = {0.f, 0.f, 0.f, 0.f};
#pragma unroll
  for (int r = 0; r < 4; ++r) acc[r] = z;

  const u16* gk[2];
  const u16* gv[2];
  char* lk[2];
  char* lv[2];
#pragma unroll
  for (int j = 0; j < 2; ++j) {
    int f = tid + j * 256;
    int key = f >> 3, g = (f & 7) ^ (key & 7);
    gk[j] = proj + (tokb + key) * 2560 + 512 + h * 64 + g * 8;
    int c = (f & 7) ^ (key & 7);
    gv[j] = vts + (size_t)bh * 64 * 1024 + (size_t)key * 1024 + c * 8;
    lk[j] = (char*)&Kl[0][0] + f * 16;
    lv[j] = (char*)&Vl[0][0] + f * 16;
  }

  auto stage = [&](int buf) {
#pragma unroll
    for (int j = 0; j < 2; ++j) {
      gload16(gk[j], lk[j] + buf * 8192);
      gload16(gv[j], lv[j] + buf * 8192);
    }
#pragma unroll
    for (int j = 0; j < 2; ++j) { gk[j] += 64 * 2560; gv[j] += 64; }
  };

  stage(0);
  __syncthreads();
  int cur = 0;
  for (int kt = 0; kt < 16; ++kt) {
    if (kt < 15) stage(cur ^ 1);
    f4v sf[4];
#pragma unroll
    for (int nf = 0; nf < 4; ++nf) sf[nf] = z;
#pragma unroll
    for (int ks = 0; ks < 2; ++ks) {
      s8v kfr[4];
#pragma unroll
      for (int nf = 0; nf < 4; ++nf) {
        int row = nf * 16 + lr;
        kfr[nf] = *(const s8v*)((const char*)&Kl[cur][0] + row * 128 + (((ks * 4 + lg) ^ (row & 7)) << 4));
      }
#pragma unroll
      for (int nf = 0; nf < 4; ++nf) sf[nf] = MFMA16(qf[ks], kfr[nf], sf[nf]);
    }
#pragma unroll
    for (int r = 0; r < 4; ++r) {
      float pv[4];
#pragma unroll
      for (int nf = 0; nf < 4; ++nf) pv[nf] = exp2f(sf[nf][r]);
      lsl[r] += (pv[0] + pv[1]) + (pv[2] + pv[3]);
      int q = lg * 4 + r;
      u64 pk = (u64)cvtpk(pv[0], pv[1]) | ((u64)cvtpk(pv[2], pv[3]) << 32);
      *(u64*)((char*)&Pl[w][0] + q * 128 + ((((lr >> 1) ^ (q & 7)) << 4)) + (lr & 1) * 8) = pk;
    }
#pragma unroll
    for (int ks2 = 0; ks2 < 2; ++ks2) {
      int g = ks2 * 4 + lg;
      s8v pfr = *(const s8v*)((const char*)&Pl[w][0] + lr * 128 + ((g ^ (lr & 7)) << 4));
#pragma unroll
      for (int nf = 0; nf < 4; ++nf) {
        int d = nf * 16 + lr;
        s8v vfr = *(const s8v*)((const char*)&Vl[cur][0] + d * 128 + ((g ^ (d & 7)) << 4));
        acc[nf] = MFMA16(pfr, vfr, acc[nf]);
      }
    }
    __syncthreads();
    cur ^= 1;
  }
#pragma unroll
  for (int r = 0; r < 4; ++r) {
    float t = lsl[r];
#pragma unroll
    for (int off = 1; off < 16; off <<= 1) t += __shfl_xor(t, off);
    float inv = 1.f / t;
    size_t row = tokb + qr0 + lg * 4 + r;
#pragma unroll
    for (int nf = 0; nf < 4; ++nf)
      comb[row * 1024 + h * 64 + nf * 16 + lr] = f2b(acc[nf][r] * inv);
  }
}

// ---------------------------------------------------------------------------
// multi-scale attention: hd=256, K-split=2, unnormalized flash.
// K/V single-buffered LDS; staging pointers hoisted with constant strides.
// ---------------------------------------------------------------------------
__global__ __launch_bounds__(256, 2) void attn_ms(
    const u16* __restrict__ proj, const u16* __restrict__ qm, const u16* __restrict__ vtm,
    u16* __restrict__ pacc, float* __restrict__ pl)
{
  const int tid = threadIdx.x, l = tid & 63, w = tid >> 6;
  const int lg = l >> 4, lr = l & 15;
  const int flat = blockIdx.x;
  const int xcd = flat & 7, idx = flat >> 3;      // idx 0..63
  const int bp = xcd + 8 * (idx >> 5);            // 2 (b,p) pairs per XCD
  const int rest = idx & 31;
  const int qt = rest >> 1, ks = rest & 1;
  const int b = bp >> 1, p = bp & 1;
  const size_t tokb = (size_t)b * 1024;
  __shared__ u16 Kl[64 * 256];
  __shared__ u16 Vl[256 * 64];
  __shared__ u16 Pl[4][16 * 64];
  const int qr0 = qt * 64 + w * 16;
  s8v qf[8];
#pragma unroll
  for (int kf = 0; kf < 8; ++kf)
    qf[kf] = *(const s8v*)(qm + (tokb + qr0 + lr) * 512 + p * 256 + kf * 32 + lg * 8);
  const f4v z = {0.f, 0.f, 0.f, 0.f};
  f4v acc[16];
#pragma unroll
  for (int i = 0; i < 16; ++i) acc[i] = z;
  float lsl[4] = {0.f, 0.f, 0.f, 0.f};
  const u16* vbase = vtm + (size_t)bp * 256 * 1024;

  const u16* gk[8];
  const u16* gv[8];
#pragma unroll
  for (int j = 0; j < 8; ++j) {
    int f = tid + j * 256;
    int key = f >> 5, pgc = f & 31;
    int g = (pgc & 24) | ((pgc & 7) ^ (key & 7));
    gk[j] = proj + (tokb + ks * 512 + key) * 2560 + 1536 + p * 256 + g * 8;
    int d = f >> 3, c = (f & 7) ^ (d & 7);
    gv[j] = vbase + (size_t)d * 1024 + ks * 512 + c * 8;
  }

  for (int kk = 0; kk < 8; ++kk) {
    __syncthreads();
#pragma unroll
    for (int j = 0; j < 8; ++j) gload16(gk[j], (char*)Kl + (tid + j * 256) * 16);
#pragma unroll
    for (int j = 0; j < 8; ++j) gload16(gv[j], (char*)Vl + (tid + j * 256) * 16);
#pragma unroll
    for (int j = 0; j < 8; ++j) { gk[j] += 64 * 2560; gv[j] += 64; }
    __syncthreads();
    f4v sf[4];
#pragma unroll
    for (int nf = 0; nf < 4; ++nf) sf[nf] = z;
#pragma unroll
    for (int ksi = 0; ksi < 8; ++ksi) {
      s8v kfr[4];
#pragma unroll
      for (int nf = 0; nf < 4; ++nf) {
        int row = nf * 16 + lr;
        int g = ksi * 4 + lg;
        int pg2 = (g & 24) | ((g & 7) ^ (row & 7));
        kfr[nf] = *(const s8v*)((const char*)Kl + row * 512 + (pg2 << 4));
      }
#pragma unroll
      for (int nf = 0; nf < 4; ++nf) sf[nf] = MFMA16(qf[ksi], kfr[nf], sf[nf]);
    }
#pragma unroll
    for (int r = 0; r < 4; ++r) {
      float pv[4];
#pragma unroll
      for (int nf = 0; nf < 4; ++nf) pv[nf] = exp2f(sf[nf][r]);
      lsl[r] += (pv[0] + pv[1]) + (pv[2] + pv[3]);
      int q = lg * 4 + r;
      u64 pk = (u64)cvtpk(pv[0], pv[1]) | ((u64)cvtpk(pv[2], pv[3]) << 32);
      *(u64*)((char*)&Pl[w][0] + q * 128 + ((((lr >> 1) ^ (q & 7)) << 4)) + (lr & 1) * 8) = pk;
    }
#pragma unroll
    for (int ks2 = 0; ks2 < 2; ++ks2) {
      int g = ks2 * 4 + lg;
      s8v pfr = *(const s8v*)((const char*)&Pl[w][0] + lr * 128 + ((g ^ (lr & 7)) << 4));
#pragma unroll
      for (int nfd = 0; nfd < 16; ++nfd) {
        int d = nfd * 16 + lr;
        s8v vfr = *(const s8v*)((const char*)Vl + d * 128 + ((g ^ (d & 7)) << 4));
        acc[nfd] = MFMA16(pfr, vfr, acc[nfd]);
      }
    }
  }
#pragma unroll
  for (int r = 0; r < 4; ++r) {
    float t = lsl[r];
#pragma unroll
    for (int off = 1; off < 16; off <<= 1) t += __shfl_xor(t, off);
    size_t prow = ((size_t)(bp * 2 + ks) * 16 + qt) * 64 + w * 16 + lg * 4 + r;
#pragma unroll
    for (int nfd = 0; nfd < 16; ++nfd)
      pacc[prow * 256 + nfd * 16 + lr] = f2b(acc[nfd][r]);
    if (lr == 0) pl[prow] = t;
  }
}

// ---------------------------------------------------------------------------
// combine the 2 K-slices of attn_ms -> comb[:, 512:1024]  (shared exponent frame)
// ---------------------------------------------------------------------------
__global__ __launch_bounds__(256) void ms_comb(
    const u16* __restrict__ pacc, const float* __restrict__ pl,
    u16* __restrict__ comb)
{
  const int qt = blockIdx.x, bp = blockIdx.y;
  const int tid = threadIdx.x;
  const int row = tid >> 2, seg = tid & 3;
  size_t prow0 = ((size_t)(bp * 2 + 0) * 16 + qt) * 64 + row;
  size_t prow1 = ((size_t)(bp * 2 + 1) * 16 + qt) * 64 + row;
  float inv = 1.f / (pl[prow0] + pl[prow1]);
  const int b = bp >> 1, p = bp & 1;
  size_t orow = ((size_t)b * 1024 + qt * 64 + row) * 1024 + 512 + p * 256 + seg * 64;
#pragma unroll
  for (int j = 0; j < 8; ++j) {
    s8v v0 = *(const s8v*)(pacc + prow0 * 256 + seg * 64 + j * 8);
    s8v v1 = *(const s8v*)(pacc + prow1 * 256 + seg * 64 + j * 8);
    s8v ov;
#pragma unroll
    for (int e = 0; e < 8; ++e)
      ov[e] = (short)f2b((b2f((u16)v0[e]) + b2f((u16)v1[e])) * inv);
    *(s8v*)(comb + orow + j * 8) = ov;
  }
}

// ---------------------------------------------------------------------------
// GN3 stats over fin [8192][512] (bf16) per (b, group)
// ---------------------------------------------------------------------------
__global__ __launch_bounds__(256) void gn3_stats(
    const u16* __restrict__ fin, float* __restrict__ mu3, float* __restrict__ rs3)
{
  int bid = blockIdx.x;
  int b = bid >> 5, g = bid & 31;
  int tid = threadIdx.x, l = tid & 63, w = tid >> 6;
  const u16* fp = fin + (size_t)b * 1024 * 512 + g * 16;
  float sum = 0.f, sq = 0.f;
#pragma unroll
  for (int i = 0; i < 8; ++i) {
    int idx = tid + i * 256;       // 2048 chunks of 8 = 1024 tokens x 2
    int s = idx >> 1, half = (idx & 1) * 8;
    s8v v = *(const s8v*)(fp + (size_t)s * 512 + half);
#pragma unroll
    for (int e = 0; e < 8; ++e) { float f = b2f((u16)v[e]); sum += f; sq += f * f; }
  }
  __shared__ float red[8];
#pragma unroll
  for (int off = 1; off < 64; off <<= 1) { sum += __shfl_xor(sum, off); sq += __shfl_xor(sq, off); }
  if (l == 0) { red[w * 2] = sum; red[w * 2 + 1] = sq; }
  __syncthreads();
  if (tid == 0) {
    float S = red[0] + red[2] + red[4] + red[6];
    float Q = red[1] + red[3] + red[5] + red[7];
    float mean = S * (1.f / 16384.f);
    float var = Q * (1.f / 16384.f) - mean * mean;
    mu3[b * 32 + g] = mean;
    rs3[b * 32 + g] = rsqrtf(var + 1e-6f);
  }
}

// ---------------------------------------------------------------------------
// final: transpose fin (bf16) back to NCHW, apply GN3 + residual -> out (f32)
// ---------------------------------------------------------------------------
__global__ __launch_bounds__(256) void final_k(
    const u16* __restrict__ fin, const float* __restrict__ mu3, const float* __restrict__ rs3,
    const float* __restrict__ postg, const float* __restrict__ postb,
    const float* __restrict__ res, float* __restrict__ out)
{
  __shared__ float lds[16 * 513];
  int st = blockIdx.x, b = blockIdx.y;
  int tid = threadIdx.x;
  const u16* fp = fin + ((size_t)b * 1024 + st * 16) * 512;
#pragma unroll
  for (int i = 0; i < 4; ++i) {
    int idx = tid + i * 256;   // 1024 chunks of 8 = 16 s x 64
    int s = idx >> 6, c8 = (idx & 63) * 8;
    s8v v = *(const s8v*)(fp + (size_t)s * 512 + c8);
#pragma unroll
    for (int j = 0; j < 8; ++j) lds[s * 513 + c8 + j] = b2f((u16)v[j]);
  }
  __syncthreads();
#pragma unroll
  for (int cc = 0; cc < 2; ++cc) {
    int c = tid * 2 + cc;
    int g = c >> 4;
    float m = mu3[b * 32 + g], rv = rs3[b * 32 + g];
    float ga = postg[c], be = postb[c];
    const float* rp = res + ((size_t)b * 512 + c) * 1024 + st * 16;
    float* op = out + ((size_t)b * 512 + c) * 1024 + st * 16;
#pragma unroll
    for (int q = 0; q < 4; ++q) {
      f4v rr = *(const f4v*)(rp + q * 4);
      f4v o;
#pragma unroll
      for (int j = 0; j < 4; ++j) {
        float v = lds[(q * 4 + j) * 513 + c];
        o[j] = (v - m) * rv * ga + be + rr[j];
      }
      *(f4v*)(op + q * 4) = o;
    }
  }
}

// ---------------------------------------------------------------------------
extern "C" void kernel_launch(void* const* d_in, const int* in_sizes, int n_in,
                              void* d_out, int out_size, void* d_ws, size_t ws_size,
                              hipStream_t stream) {
  (void)in_sizes; (void)n_in; (void)out_size; (void)ws_size;
  const float* hs     = (const float*)d_in[0];
  const float* pre_g  = (const float*)d_in[1];
  const float* pre_b  = (const float*)d_in[2];
  const float* norm_g = (const float*)d_in[3];
  const float* norm_b = (const float*)d_in[4];
  const float* post_g = (const float*)d_in[5];
  const float* post_b = (const float*)d_in[6];
  const float* pos    = (const float*)d_in[7];
  const float* sa_b1  = (const float*)d_in[18];
  const float* sa_b2  = (const float*)d_in[20];
  const float* sa_w3  = (const float*)d_in[21];
  const float* sa_b3  = (const float*)d_in[22];
  const float* ff_b1  = (const float*)d_in[24];
  const float* ff_b2  = (const float*)d_in[26];
  const float* out_b  = (const float*)d_in[28];

  char* ws = (char*)d_ws;
  size_t off = 0;
  auto alloc = [&](size_t bytes) -> void* {
    void* pp = ws + off;
    off += (bytes + 255) & ~(size_t)255;
    return pp;
  };
  float* x    = (float*)alloc((size_t)16777216);       // region: xb -> pacc -> fin
  u16* sh     = (u16*)alloc((size_t)8388608);          // [8192][512] bf16
  u16* xt     = (u16*)alloc((size_t)8388608);          // [8192][512] bf16
  float* mu2  = (float*)alloc(1024);
  float* rs2  = (float*)alloc(1024);
  float* mu3  = (float*)alloc(1024);
  float* rs3  = (float*)alloc(1024);
  float* pl   = (float*)alloc(262144);                 // [32][16][64]
  u16* wcat   = (u16*)alloc((size_t)2691072 * 2);      // all bf16 weights
  u16* proj   = (u16*)alloc((size_t)8192 * 2560 * 2);  // q|k|v|k0|k1|v0|v1
  u16* qmb    = (u16*)alloc((size_t)8388608);          // [8192][512]
  u16* s1t    = (u16*)alloc((size_t)1048576);          // [8192][64]
  u16* colb   = (u16*)alloc((size_t)8192 * 576 * 2);   // im2col; reused as vts
  float* gate = (float*)alloc((size_t)32768);          // [8192]
  u16* vtm    = (u16*)alloc((size_t)8388608);          // [512 d][1024 keys] x 16
  u16* comb   = (u16*)alloc((size_t)16777216);         // [8192][1024]
  u16* f1     = (u16*)alloc((size_t)8388608);
  u16* f2     = (u16*)alloc((size_t)8388608);
  u16* xb     = (u16*)x;                               // bf16 NCHW x (8MB over x)
  u16* pacc   = (u16*)x;                               // 16MB over x (after xb dead)
  u16* fin    = (u16*)x;                               // bf16 [8192][512] (after pacc dead)
  u16* vts    = colb;                                  // 8MB over colb

  u16* Wbig = wcat;                 // [2560][512]
  u16* Wq01 = wcat + 1310720;       // [512][512]
  u16* W1   = wcat + 1572864;       // [64][512]
  u16* W2   = wcat + 1605632;       // [64][576]
  u16* Wff1 = wcat + 1642496;       // [512][1024]
  u16* Wff2 = wcat + 2166784;       // [512][512]
  u16* Wout = wcat + 2428928;       // [512][512]

  Segs sg;
  const int srcidx[14] = {8, 9, 10, 13, 14, 15, 16, 11, 12, 17, 19, 23, 25, 27};
  const int segsz[14] = {262144, 262144, 262144, 131072, 131072, 131072, 131072,
                         131072, 131072, 32768, 36864, 524288, 262144, 262144};
  int cum = 0;
  for (int i = 0; i < 14; ++i) {
    sg.src[i] = (const float*)d_in[srcidx[i]];
    sg.cum[i] = cum;
    sg.scl[i] = 1.f;
    cum += segsz[i];
  }
  sg.cum[14] = cum;   // 2691072
  sg.scl[0] = 0.125f * LOG2E;    // wq  : 1/sqrt(64) * log2(e)
  sg.scl[7] = 0.0625f * LOG2E;   // wq0 : 1/sqrt(256) * log2(e)
  sg.scl[8] = 0.0625f * LOG2E;   // wq1

  dim3 blk(256);
  castk<<<2628, blk, 0, stream>>>(sg, wcat);
  gn1_k<<<256, blk, 0, stream>>>(hs, pre_g, pre_b, pos, xb, mu2, rs2);
  trans_gn2<<<dim3(64, 8), blk, 0, stream>>>(xb, mu2, rs2, norm_g, norm_b, xt, sh);
  // fused qkv + multiscale k/v projection: [8192][512] x [2560][512]^T
  gemm_k<128, 128, false, false, false, false><<<1280, blk, 0, stream>>>(
      sh, 512, Wbig, 512, proj, 2560, nullptr, 512, 20, nullptr);
  // spatial gate path
  gemm_k<64, 64, true, false, true, false><<<128, blk, 0, stream>>>(
      xt, 512, W1, 512, s1t, 64, sa_b1, 512, 1, nullptr);
  im2col_k<<<2048, blk, 0, stream>>>(s1t, colb);
  // s2 GEMM with conv3+sigmoid fused in the epilogue -> gate
  gemm_gate_k<<<128, blk, 0, stream>>>(colb, 576, W2, 576, sa_b2, 576, sa_w3, sa_b3, gate);
  // qm = diag(gate) @ (xt @ Wq01^T)  — gate folded into GEMM epilogue
  gemm_k<128, 64, false, false, false, true><<<512, blk, 0, stream>>>(
      xt, 512, Wq01, 512, qmb, 512, nullptr, 512, 8, gate);
  // merged V transposes (pi-permuted); colb dead by now
  tvm_k<<<dim3(16, 80), blk, 0, stream>>>(proj, vts, vtm);
  // attention
  attn_std<<<1024, blk, 0, stream>>>(proj, vts, comb);
  attn_ms<<<512, blk, 0, stream>>>(proj, qmb, vtm, pacc, pl);
  ms_comb<<<dim3(16, 16), blk, 0, stream>>>(pacc, pl, comb);
  // feed-forward + out projection (fin in bf16)
  gemm_k<128, 64, true, false, true, false><<<512, blk, 0, stream>>>(
      comb, 1024, Wff1, 1024, f1, 512, ff_b1, 1024, 8, nullptr);
  gemm_k<128, 64, false, false, true, false><<<512, blk, 0, stream>>>(
      f1, 512, Wff2, 512, f2, 512, ff_b2, 512, 8, nullptr);
  gemm_k<128, 64, false, false, true, false><<<512, blk, 0, stream>>>(
      f2, 512, Wout, 512, fin, 512, out_b, 512, 8, nullptr);
  // final group norm + residual
  gn3_stats<<<256, blk, 0, stream>>>(fin, mu3, rs3);
  final_k<<<dim3(64, 8), blk, 0, stream>>>(fin, mu3, rs3, post_g, post_b, hs, (float*)d_out);
}

// Round 13
// 244.666 us; speedup vs baseline: 1.0990x; 1.0022x over previous
//
#include <hip/hip_runtime.h>

typedef unsigned short u16;
typedef unsigned long long u64;
typedef __attribute__((ext_vector_type(8))) short s8v;   // 8 x bf16 bits (4 VGPR)
typedef __attribute__((ext_vector_type(4))) short s4v;
typedef __attribute__((ext_vector_type(4))) float f4v;

#define LOG2E 1.4426950408889634f

__device__ __forceinline__ float b2f(u16 u) {
  union { unsigned u; float f; } x; x.u = ((unsigned)u) << 16; return x.f;
}
__device__ __forceinline__ u16 f2b(float f) {
  union { float f; unsigned u; } x; x.f = f;
  unsigned r = x.u + 0x7fffu + ((x.u >> 16) & 1u);
  return (u16)(r >> 16);
}
// packed f32x2 -> bf16x2 (single VALU op; RTE)
__device__ __forceinline__ unsigned cvtpk(float lo, float hi) {
  unsigned r;
  asm("v_cvt_pk_bf16_f32 %0, %1, %2" : "=v"(r) : "v"(lo), "v"(hi));
  return r;
}

#define MFMA16(a, b, c) __builtin_amdgcn_mfma_f32_16x16x32_bf16((a), (b), (c), 0, 0, 0)

__device__ __forceinline__ void gload16(const void* g, void* l) {
  __builtin_amdgcn_global_load_lds(
      (const __attribute__((address_space(1))) unsigned*)g,
      (__attribute__((address_space(3))) unsigned*)l, 16, 0, 0);
}

// ---------------------------------------------------------------------------
// weight cast: 14 f32 segments -> one contiguous bf16 region (with per-seg scale)
// ---------------------------------------------------------------------------
struct Segs {
  const float* src[14];
  int cum[15];
  float scl[14];
};

__global__ __launch_bounds__(256) void castk(Segs sg, u16* __restrict__ dst) {
  int gid = (blockIdx.x * 256 + threadIdx.x) * 4;
  if (gid >= sg.cum[14]) return;
  int s = 0;
  while (gid >= sg.cum[s + 1]) ++s;
  const float* sp = sg.src[s] + (gid - sg.cum[s]);
  float sc = sg.scl[s];
  f4v v = *(const f4v*)sp;
  s4v o;
  o[0] = (short)f2b(v[0] * sc); o[1] = (short)f2b(v[1] * sc);
  o[2] = (short)f2b(v[2] * sc); o[3] = (short)f2b(v[3] * sc);
  *(s4v*)(dst + gid) = o;
}

// ---------------------------------------------------------------------------
// GN1: group_norm(hidden, pre) + pos_emb -> xb (NCHW bf16); stats of x for GN2.
// ---------------------------------------------------------------------------
__global__ __launch_bounds__(256) void gn1_k(
    const float* __restrict__ hs, const float* __restrict__ pg, const float* __restrict__ pb,
    const float* __restrict__ pos, u16* __restrict__ xb,
    float* __restrict__ mu2, float* __restrict__ rs2)
{
  int bid = blockIdx.x;
  int b = bid >> 5, g = bid & 31;
  int tid = threadIdx.x, l = tid & 63, w = tid >> 6;
  const float* src = hs + ((size_t)b * 512 + g * 16) * 1024;
  const float* pp = pos + (size_t)(g * 16) * 1024;
  u16* dst = xb + ((size_t)b * 512 + g * 16) * 1024;
  f4v vals[16];
  float sum = 0.f, sq = 0.f;
#pragma unroll
  for (int i = 0; i < 16; ++i) {
    int idx = tid + i * 256;
    vals[i] = *(const f4v*)(src + (size_t)idx * 4);
    f4v v = vals[i];
    sum += v[0] + v[1] + v[2] + v[3];
    sq += v[0] * v[0] + v[1] * v[1] + v[2] * v[2] + v[3] * v[3];
  }
  __shared__ float red[8];
#pragma unroll
  for (int off = 1; off < 64; off <<= 1) { sum += __shfl_xor(sum, off); sq += __shfl_xor(sq, off); }
  if (l == 0) { red[w * 2] = sum; red[w * 2 + 1] = sq; }
  __syncthreads();
  float S = red[0] + red[2] + red[4] + red[6];
  float Q = red[1] + red[3] + red[5] + red[7];
  float mean = S * (1.f / 16384.f);
  float var = Q * (1.f / 16384.f) - mean * mean;
  float rstd = rsqrtf(var + 1e-6f);
  __syncthreads();
  float sum2 = 0.f, sq2 = 0.f;
#pragma unroll
  for (int i = 0; i < 16; ++i) {
    int idx = tid + i * 256;
    int c = idx >> 8;
    float gam = pg[g * 16 + c], bet = pb[g * 16 + c];
    f4v v = vals[i];
    f4v pe = *(const f4v*)(pp + (size_t)idx * 4);
    f4v o;
    s4v ob;
#pragma unroll
    for (int j = 0; j < 4; ++j) {
      o[j] = (v[j] - mean) * rstd * gam + bet + pe[j];
      ob[j] = (short)f2b(o[j]);
    }
    *(s4v*)(dst + (size_t)idx * 4) = ob;
    sum2 += o[0] + o[1] + o[2] + o[3];
    sq2 += o[0] * o[0] + o[1] * o[1] + o[2] * o[2] + o[3] * o[3];
  }
#pragma unroll
  for (int off = 1; off < 64; off <<= 1) { sum2 += __shfl_xor(sum2, off); sq2 += __shfl_xor(sq2, off); }
  if (l == 0) { red[w * 2] = sum2; red[w * 2 + 1] = sq2; }
  __syncthreads();
  if (tid == 0) {
    float S2 = red[0] + red[2] + red[4] + red[6];
    float Q2 = red[1] + red[3] + red[5] + red[7];
    float m2 = S2 * (1.f / 16384.f);
    float v2 = Q2 * (1.f / 16384.f) - m2 * m2;
    mu2[b * 32 + g] = m2;
    rs2[b * 32 + g] = rsqrtf(v2 + 1e-6f);
  }
}

// ---------------------------------------------------------------------------
// transpose xb (NCHW bf16) -> xt (token-major bf16) and sh = GN2(x) (token-major)
// ---------------------------------------------------------------------------
__global__ __launch_bounds__(256) void trans_gn2(
    const u16* __restrict__ xb, const float* __restrict__ mu2, const float* __restrict__ rs2,
    const float* __restrict__ ng, const float* __restrict__ nb,
    u16* __restrict__ xt, u16* __restrict__ sh)
{
  __shared__ float lds[512 * 17];
  int st = blockIdx.x, b = blockIdx.y;
  int tid = threadIdx.x;
  const u16* xp = xb + (size_t)b * 512 * 1024 + st * 16;
#pragma unroll
  for (int i = 0; i < 4; ++i) {
    int idx = tid + i * 256;       // 1024 chunks of 8 u16 = 512c x 2
    int c = idx >> 1, sq = (idx & 1) * 8;
    s8v v = *(const s8v*)(xp + (size_t)c * 1024 + sq);
#pragma unroll
    for (int j = 0; j < 8; ++j) lds[c * 17 + sq + j] = b2f((u16)v[j]);
  }
  __syncthreads();
  int s = tid & 15, cb0 = (tid >> 4) * 32;
  size_t token = (size_t)b * 1024 + st * 16 + s;
  float m0 = mu2[b * 32 + (cb0 >> 4)], m1 = mu2[b * 32 + (cb0 >> 4) + 1];
  float r0 = rs2[b * 32 + (cb0 >> 4)], r1 = rs2[b * 32 + (cb0 >> 4) + 1];
#pragma unroll
  for (int q = 0; q < 4; ++q) {
    s8v ox, os;
#pragma unroll
    for (int j = 0; j < 8; ++j) {
      int cj = q * 8 + j;
      int c = cb0 + cj;
      float v = lds[c * 17 + s];
      ox[j] = (short)f2b(v);
      float mm = (cj < 16) ? m0 : m1;
      float rr = (cj < 16) ? r0 : r1;
      os[j] = (short)f2b((v - mm) * rr * ng[c] + nb[c]);
    }
    *(s8v*)(xt + token * 512 + cb0 + q * 8) = ox;
    *(s8v*)(sh + token * 512 + cb0 + q * 8) = os;
  }
}

// ---------------------------------------------------------------------------
// generic bf16 MFMA GEMM: C[M][ldc] = A[M][lda] * Bw[N][ldb]^T  (+bias, +silu,
// +per-row scale). 1-D grid, XCD-swizzled, mt-group-4 L2 panel ordering.
// Single-buffered LDS; implicit wave-level overlap at ~5 blocks/CU.
// ---------------------------------------------------------------------------
template <int BM, int BN, bool SILU, bool OUT32, bool BIAS, bool RSCALE>
__global__ __launch_bounds__(256, 2) void gemm_k(
    const u16* __restrict__ A, int lda,
    const u16* __restrict__ Bw, int ldb,
    void* __restrict__ Cp, int ldc,
    const float* __restrict__ bias, int K, int ntx,
    const float* __restrict__ rscale)
{
  constexpr int WMT = BM / 2, WNT = BN / 2, MF = WMT / 16, NF = WNT / 16;
  __shared__ u16 Al[BM * 64];
  __shared__ u16 Bl[BN * 64];
  const int tid = threadIdx.x, l = tid & 63, w = tid >> 6;
  const int lg = l >> 4, lr = l & 15;
  const int wm = w >> 1, wn = w & 1;
  const int flat = blockIdx.x;
  const int cpx = gridDim.x >> 3;
  const int id = (flat & 7) * cpx + (flat >> 3);
  const int grp = id / (ntx * 4), rem = id % (ntx * 4);
  const int nt = rem >> 2, mt = grp * 4 + (rem & 3);
  const u16* Ag = A + (size_t)mt * BM * lda;
  const u16* Bg = Bw + (size_t)nt * BN * ldb;
  const f4v z = {0.f, 0.f, 0.f, 0.f};
  f4v acc[MF][NF];
#pragma unroll
  for (int i = 0; i < MF; ++i)
#pragma unroll
    for (int j = 0; j < NF; ++j) acc[i][j] = z;

  for (int kt = 0; kt < K; kt += 64) {
    __syncthreads();
    for (int f = tid; f < BM * 8; f += 256) {
      int row = f >> 3, g = (f & 7) ^ (row & 7);
      gload16(Ag + (size_t)row * lda + kt + g * 8, (char*)Al + f * 16);
    }
    for (int f = tid; f < BN * 8; f += 256) {
      int row = f >> 3, g = (f & 7) ^ (row & 7);
      gload16(Bg + (size_t)row * ldb + kt + g * 8, (char*)Bl + f * 16);
    }
    __syncthreads();
#pragma unroll
    for (int ks = 0; ks < 2; ++ks) {
      s8v af[MF], bf[NF];
#pragma unroll
      for (int mf = 0; mf < MF; ++mf) {
        int row = wm * WMT + mf * 16 + lr;
        af[mf] = *(const s8v*)((const char*)Al + row * 128 + (((ks * 4 + lg) ^ (row & 7)) << 4));
      }
#pragma unroll
      for (int nf = 0; nf < NF; ++nf) {
        int row = wn * WNT + nf * 16 + lr;
        bf[nf] = *(const s8v*)((const char*)Bl + row * 128 + (((ks * 4 + lg) ^ (row & 7)) << 4));
      }
#pragma unroll
      for (int mf = 0; mf < MF; ++mf)
#pragma unroll
        for (int nf = 0; nf < NF; ++nf)
          acc[mf][nf] = MFMA16(af[mf], bf[nf], acc[mf][nf]);
    }
  }
#pragma unroll
  for (int mf = 0; mf < MF; ++mf) {
    int row0 = mt * BM + wm * WMT + mf * 16 + lg * 4;
#pragma unroll
    for (int nf = 0; nf < NF; ++nf) {
      int col = nt * BN + wn * WNT + nf * 16 + lr;
      float bv = BIAS ? bias[col] : 0.f;
#pragma unroll
      for (int r = 0; r < 4; ++r) {
        float v = acc[mf][nf][r] + bv;
        if (RSCALE) v *= rscale[row0 + r];
        if (SILU) v = v / (1.f + exp2f(-v * LOG2E));
        size_t off = (size_t)(row0 + r) * ldc + col;
        if (OUT32) ((float*)Cp)[off] = v;
        else ((u16*)Cp)[off] = f2b(v);
      }
    }
  }
}

// ---------------------------------------------------------------------------
// gate GEMM: s2 = silu(col @ W2^T + b2) (64x64 per block, all channels), then
// gate[token] = sigmoid(s2[token,:] . w3 + b3) fused in-epilogue (conv3 fold).
// ---------------------------------------------------------------------------
__global__ __launch_bounds__(256, 2) void gemm_gate_k(
    const u16* __restrict__ A, int lda,
    const u16* __restrict__ Bw, int ldb,
    const float* __restrict__ bias, int K,
    const float* __restrict__ w3, const float* __restrict__ b3,
    float* __restrict__ gate)
{
  constexpr int BM = 64, BN = 64, WMT = 32, WNT = 32, MF = 2, NF = 2;
  __shared__ u16 Al[BM * 64];
  __shared__ u16 Bl[BN * 64];
  __shared__ float gt[64][68];
  const int tid = threadIdx.x, l = tid & 63, w = tid >> 6;
  const int lg = l >> 4, lr = l & 15;
  const int wm = w >> 1, wn = w & 1;
  const int flat = blockIdx.x;
  const int cpx = gridDim.x >> 3;
  const int mt = (flat & 7) * cpx + (flat >> 3);
  const u16* Ag = A + (size_t)mt * BM * lda;
  const u16* Bg = Bw;
  const f4v z = {0.f, 0.f, 0.f, 0.f};
  f4v acc[MF][NF];
#pragma unroll
  for (int i = 0; i < MF; ++i)
#pragma unroll
    for (int j = 0; j < NF; ++j) acc[i][j] = z;

  for (int kt = 0; kt < K; kt += 64) {
    __syncthreads();
    for (int f = tid; f < BM * 8; f += 256) {
      int row = f >> 3, g = (f & 7) ^ (row & 7);
      gload16(Ag + (size_t)row * lda + kt + g * 8, (char*)Al + f * 16);
    }
    for (int f = tid; f < BN * 8; f += 256) {
      int row = f >> 3, g = (f & 7) ^ (row & 7);
      gload16(Bg + (size_t)row * ldb + kt + g * 8, (char*)Bl + f * 16);
    }
    __syncthreads();
#pragma unroll
    for (int ks = 0; ks < 2; ++ks) {
      s8v af[MF], bf[NF];
#pragma unroll
      for (int mf = 0; mf < MF; ++mf) {
        int row = wm * WMT + mf * 16 + lr;
        af[mf] = *(const s8v*)((const char*)Al + row * 128 + (((ks * 4 + lg) ^ (row & 7)) << 4));
      }
#pragma unroll
      for (int nf = 0; nf < NF; ++nf) {
        int row = wn * WNT + nf * 16 + lr;
        bf[nf] = *(const s8v*)((const char*)Bl + row * 128 + (((ks * 4 + lg) ^ (row & 7)) << 4));
      }
#pragma unroll
      for (int mf = 0; mf < MF; ++mf)
#pragma unroll
        for (int nf = 0; nf < NF; ++nf)
          acc[mf][nf] = MFMA16(af[mf], bf[nf], acc[mf][nf]);
    }
  }
  __syncthreads();
#pragma unroll
  for (int mf = 0; mf < MF; ++mf) {
    int lrow0 = wm * WMT + mf * 16 + lg * 4;
#pragma unroll
    for (int nf = 0; nf < NF; ++nf) {
      int col = wn * WNT + nf * 16 + lr;
      float bv = bias[col];
#pragma unroll
      for (int r = 0; r < 4; ++r) {
        float v = acc[mf][nf][r] + bv;
        v = v / (1.f + exp2f(-v * LOG2E));
        gt[lrow0 + r][col] = v;
      }
    }
  }
  __syncthreads();
  if (tid < 64) {
    float a = b3[0];
    for (int c = 0; c < 64; ++c) a += gt[tid][c] * w3[c];
    gate[mt * 64 + tid] = 1.f / (1.f + exp2f(-a * LOG2E));
  }
}

// ---------------------------------------------------------------------------
// im2col for 3x3 conv
// ---------------------------------------------------------------------------
__global__ __launch_bounds__(256) void im2col_k(const u16* __restrict__ s1t, u16* __restrict__ col) {
  int gid = blockIdx.x * 256 + threadIdx.x;
  if (gid >= 8192 * 64) return;
  int token = gid >> 6, c = gid & 63;
  int s = token & 1023, y = s >> 5, xx = s & 31;
  u16* dst = col + (size_t)token * 576 + c * 9;
#pragma unroll
  for (int dy = 0; dy < 3; ++dy)
#pragma unroll
    for (int dx = 0; dx < 3; ++dx) {
      int yy = y + dy - 1, x2 = xx + dx - 1;
      u16 v = 0;
      if (yy >= 0 && yy < 32 && x2 >= 0 && x2 < 32)
        v = s1t[(size_t)(token + (dy - 1) * 32 + (dx - 1)) * 64 + c];
      dst[dy * 3 + dx] = v;
    }
}

// ---------------------------------------------------------------------------
// merged V transpose: y < 64 -> std heads (HD=64, col0=1024, vts);
// y >= 64 -> ms paths (HD=256, col0=2048, vtm). pi-permuted per 64-key block.
// ---------------------------------------------------------------------------
__global__ __launch_bounds__(256) void tvm_k(const u16* __restrict__ proj,
                                             u16* __restrict__ vts, u16* __restrict__ vtm)
{
  __shared__ u16 tile[64][258];
  const int tid = threadIdx.x;
  const int kb = blockIdx.x, y = blockIdx.y;
  int hd, col0, b, hh;
  u16* outp;
  if (y < 64) { hd = 64; col0 = 1024; b = y >> 3; hh = y & 7; outp = vts + (size_t)y * 64 * 1024; }
  else { int y2 = y - 64; hd = 256; col0 = 2048; b = y2 >> 1; hh = y2 & 1; outp = vtm + (size_t)y2 * 256 * 1024; }
  const int hd8 = hd >> 3;
  const u16* src = proj + ((size_t)b * 1024 + kb * 64) * 2560 + col0 + hh * hd;
  for (int f = tid; f < 64 * hd8; f += 256) {
    int key = f / hd8, c = f % hd8;
    *(s8v*)&tile[key][c * 8] = *(const s8v*)(src + (size_t)key * 2560 + c * 8);
  }
  __syncthreads();
  u16* dst = outp + kb * 64;
  for (int idx = tid; idx < hd * 16; idx += 256) {
    int d = idx >> 4, a = idx & 15;
    u16 e0 = tile[a][d], e1 = tile[16 + a][d], e2 = tile[32 + a][d], e3 = tile[48 + a][d];
    u64 v = (u64)e0 | ((u64)e1 << 16) | ((u64)e2 << 32) | ((u64)e3 << 48);
    *(u64*)(dst + (size_t)d * 1024 + a * 4) = v;
  }
}

// ---------------------------------------------------------------------------
// standard MHA flash attention: hd=64, unnormalized flash.
// K/V dbuf LDS; hoisted staging pointers; s_setprio(1) around MFMA clusters
// (T5: pays when resident blocks are phase-diverse).
// ---------------------------------------------------------------------------
__global__ __launch_bounds__(256, 4) void attn_std(
    const u16* __restrict__ proj, const u16* __restrict__ vts, u16* __restrict__ comb)
{
  const int tid = threadIdx.x, l = tid & 63, w = tid >> 6;
  const int lg = l >> 4, lr = l & 15;
  const int flat = blockIdx.x;
  const int xcd = flat & 7, idx = flat >> 3;      // idx 0..127
  const int bh = xcd + 8 * (idx >> 4);            // 8 heads per XCD
  const int qt = idx & 15;
  const int b = bh >> 3, h = bh & 7;
  const size_t tokb = (size_t)b * 1024;
  __shared__ u16 Kl[2][64 * 64];
  __shared__ u16 Vl[2][64 * 64];
  __shared__ u16 Pl[4][16 * 64];
  const int qr0 = qt * 64 + w * 16;
  s8v qf[2];
#pragma unroll
  for (int ks = 0; ks < 2; ++ks)
    qf[ks] = *(const s8v*)(proj + (tokb + qr0 + lr) * 2560 + h * 64 + ks * 32 + lg * 8);
  const f4v z = {0.f, 0.f, 0.f, 0.f};
  f4v acc[4];
  float lsl[4] = {0.f, 0.f, 0.f, 0.f};
#pragma unroll
  for (int r = 0; r < 4; ++r) acc[r] = z;

  const u16* gk[2];
  const u16* gv[2];
  char* lk[2];
  char* lv[2];
#pragma unroll
  for (int j = 0; j < 2; ++j) {
    int f = tid + j * 256;
    int key = f >> 3, g = (f & 7) ^ (key & 7);
    gk[j] = proj + (tokb + key) * 2560 + 512 + h * 64 + g * 8;
    int c = (f & 7) ^ (key & 7);
    gv[j] = vts + (size_t)bh * 64 * 1024 + (size_t)key * 1024 + c * 8;
    lk[j] = (char*)&Kl[0][0] + f * 16;
    lv[j] = (char*)&Vl[0][0] + f * 16;
  }

  auto stage = [&](int buf) {
#pragma unroll
    for (int j = 0; j < 2; ++j) {
      gload16(gk[j], lk[j] + buf * 8192);
      gload16(gv[j], lv[j] + buf * 8192);
    }
#pragma unroll
    for (int j = 0; j < 2; ++j) { gk[j] += 64 * 2560; gv[j] += 64; }
  };

  stage(0);
  __syncthreads();
  int cur = 0;
  for (int kt = 0; kt < 16; ++kt) {
    if (kt < 15) stage(cur ^ 1);
    f4v sf[4];
#pragma unroll
    for (int nf = 0; nf < 4; ++nf) sf[nf] = z;
    __builtin_amdgcn_s_setprio(1);
#pragma unroll
    for (int ks = 0; ks < 2; ++ks) {
      s8v kfr[4];
#pragma unroll
      for (int nf = 0; nf < 4; ++nf) {
        int row = nf * 16 + lr;
        kfr[nf] = *(const s8v*)((const char*)&Kl[cur][0] + row * 128 + (((ks * 4 + lg) ^ (row & 7)) << 4));
      }
#pragma unroll
      for (int nf = 0; nf < 4; ++nf) sf[nf] = MFMA16(qf[ks], kfr[nf], sf[nf]);
    }
    __builtin_amdgcn_s_setprio(0);
#pragma unroll
    for (int r = 0; r < 4; ++r) {
      float pv[4];
#pragma unroll
      for (int nf = 0; nf < 4; ++nf) pv[nf] = exp2f(sf[nf][r]);
      lsl[r] += (pv[0] + pv[1]) + (pv[2] + pv[3]);
      int q = lg * 4 + r;
      u64 pk = (u64)cvtpk(pv[0], pv[1]) | ((u64)cvtpk(pv[2], pv[3]) << 32);
      *(u64*)((char*)&Pl[w][0] + q * 128 + ((((lr >> 1) ^ (q & 7)) << 4)) + (lr & 1) * 8) = pk;
    }
    __builtin_amdgcn_s_setprio(1);
#pragma unroll
    for (int ks2 = 0; ks2 < 2; ++ks2) {
      int g = ks2 * 4 + lg;
      s8v pfr = *(const s8v*)((const char*)&Pl[w][0] + lr * 128 + ((g ^ (lr & 7)) << 4));
#pragma unroll
      for (int nf = 0; nf < 4; ++nf) {
        int d = nf * 16 + lr;
        s8v vfr = *(const s8v*)((const char*)&Vl[cur][0] + d * 128 + ((g ^ (d & 7)) << 4));
        acc[nf] = MFMA16(pfr, vfr, acc[nf]);
      }
    }
    __builtin_amdgcn_s_setprio(0);
    __syncthreads();
    cur ^= 1;
  }
#pragma unroll
  for (int r = 0; r < 4; ++r) {
    float t = lsl[r];
#pragma unroll
    for (int off = 1; off < 16; off <<= 1) t += __shfl_xor(t, off);
    float inv = 1.f / t;
    size_t row = tokb + qr0 + lg * 4 + r;
#pragma unroll
    for (int nf = 0; nf < 4; ++nf)
      comb[row * 1024 + h * 64 + nf * 16 + lr] = f2b(acc[nf][r] * inv);
  }
}

// ---------------------------------------------------------------------------
// multi-scale attention: hd=256, K-split=2, unnormalized flash.
// K/V single-buffered LDS; hoisted staging pointers; setprio around MFMA.
// ---------------------------------------------------------------------------
__global__ __launch_bounds__(256, 2) void attn_ms(
    const u16* __restrict__ proj, const u16* __restrict__ qm, const u16* __restrict__ vtm,
    u16* __restrict__ pacc, float* __restrict__ pl)
{
  const int tid = threadIdx.x, l = tid & 63, w = tid >> 6;
  const int lg = l >> 4, lr = l & 15;
  const int flat = blockIdx.x;
  const int xcd = flat & 7, idx = flat >> 3;      // idx 0..63
  const int bp = xcd + 8 * (idx >> 5);            // 2 (b,p) pairs per XCD
  const int rest = idx & 31;
  const int qt = rest >> 1, ks = rest & 1;
  const int b = bp >> 1, p = bp & 1;
  const size_t tokb = (size_t)b * 1024;
  __shared__ u16 Kl[64 * 256];
  __shared__ u16 Vl[256 * 64];
  __shared__ u16 Pl[4][16 * 64];
  const int qr0 = qt * 64 + w * 16;
  s8v qf[8];
#pragma unroll
  for (int kf = 0; kf < 8; ++kf)
    qf[kf] = *(const s8v*)(qm + (tokb + qr0 + lr) * 512 + p * 256 + kf * 32 + lg * 8);
  const f4v z = {0.f, 0.f, 0.f, 0.f};
  f4v acc[16];
#pragma unroll
  for (int i = 0; i < 16; ++i) acc[i] = z;
  float lsl[4] = {0.f, 0.f, 0.f, 0.f};
  const u16* vbase = vtm + (size_t)bp * 256 * 1024;

  const u16* gk[8];
  const u16* gv[8];
#pragma unroll
  for (int j = 0; j < 8; ++j) {
    int f = tid + j * 256;
    int key = f >> 5, pgc = f & 31;
    int g = (pgc & 24) | ((pgc & 7) ^ (key & 7));
    gk[j] = proj + (tokb + ks * 512 + key) * 2560 + 1536 + p * 256 + g * 8;
    int d = f >> 3, c = (f & 7) ^ (d & 7);
    gv[j] = vbase + (size_t)d * 1024 + ks * 512 + c * 8;
  }

  for (int kk = 0; kk < 8; ++kk) {
    __syncthreads();
#pragma unroll
    for (int j = 0; j < 8; ++j) gload16(gk[j], (char*)Kl + (tid + j * 256) * 16);
#pragma unroll
    for (int j = 0; j < 8; ++j) gload16(gv[j], (char*)Vl + (tid + j * 256) * 16);
#pragma unroll
    for (int j = 0; j < 8; ++j) { gk[j] += 64 * 2560; gv[j] += 64; }
    __syncthreads();
    f4v sf[4];
#pragma unroll
    for (int nf = 0; nf < 4; ++nf) sf[nf] = z;
    __builtin_amdgcn_s_setprio(1);
#pragma unroll
    for (int ksi = 0; ksi < 8; ++ksi) {
      s8v kfr[4];
#pragma unroll
      for (int nf = 0; nf < 4; ++nf) {
        int row = nf * 16 + lr;
        int g = ksi * 4 + lg;
        int pg2 = (g & 24) | ((g & 7) ^ (row & 7));
        kfr[nf] = *(const s8v*)((const char*)Kl + row * 512 + (pg2 << 4));
      }
#pragma unroll
      for (int nf = 0; nf < 4; ++nf) sf[nf] = MFMA16(qf[ksi], kfr[nf], sf[nf]);
    }
    __builtin_amdgcn_s_setprio(0);
#pragma unroll
    for (int r = 0; r < 4; ++r) {
      float pv[4];
#pragma unroll
      for (int nf = 0; nf < 4; ++nf) pv[nf] = exp2f(sf[nf][r]);
      lsl[r] += (pv[0] + pv[1]) + (pv[2] + pv[3]);
      int q = lg * 4 + r;
      u64 pk = (u64)cvtpk(pv[0], pv[1]) | ((u64)cvtpk(pv[2], pv[3]) << 32);
      *(u64*)((char*)&Pl[w][0] + q * 128 + ((((lr >> 1) ^ (q & 7)) << 4)) + (lr & 1) * 8) = pk;
    }
    __builtin_amdgcn_s_setprio(1);
#pragma unroll
    for (int ks2 = 0; ks2 < 2; ++ks2) {
      int g = ks2 * 4 + lg;
      s8v pfr = *(const s8v*)((const char*)&Pl[w][0] + lr * 128 + ((g ^ (lr & 7)) << 4));
#pragma unroll
      for (int nfd = 0; nfd < 16; ++nfd) {
        int d = nfd * 16 + lr;
        s8v vfr = *(const s8v*)((const char*)Vl + d * 128 + ((g ^ (d & 7)) << 4));
        acc[nfd] = MFMA16(pfr, vfr, acc[nfd]);
      }
    }
    __builtin_amdgcn_s_setprio(0);
  }
#pragma unroll
  for (int r = 0; r < 4; ++r) {
    float t = lsl[r];
#pragma unroll
    for (int off = 1; off < 16; off <<= 1) t += __shfl_xor(t, off);
    size_t prow = ((size_t)(bp * 2 + ks) * 16 + qt) * 64 + w * 16 + lg * 4 + r;
#pragma unroll
    for (int nfd = 0; nfd < 16; ++nfd)
      pacc[prow * 256 + nfd * 16 + lr] = f2b(acc[nfd][r]);
    if (lr == 0) pl[prow] = t;
  }
}

// ---------------------------------------------------------------------------
// combine the 2 K-slices of attn_ms -> comb[:, 512:1024]  (shared exponent frame)
// ---------------------------------------------------------------------------
__global__ __launch_bounds__(256) void ms_comb(
    const u16* __restrict__ pacc, const float* __restrict__ pl,
    u16* __restrict__ comb)
{
  const int qt = blockIdx.x, bp = blockIdx.y;
  const int tid = threadIdx.x;
  const int row = tid >> 2, seg = tid & 3;
  size_t prow0 = ((size_t)(bp * 2 + 0) * 16 + qt) * 64 + row;
  size_t prow1 = ((size_t)(bp * 2 + 1) * 16 + qt) * 64 + row;
  float inv = 1.f / (pl[prow0] + pl[prow1]);
  const int b = bp >> 1, p = bp & 1;
  size_t orow = ((size_t)b * 1024 + qt * 64 + row) * 1024 + 512 + p * 256 + seg * 64;
#pragma unroll
  for (int j = 0; j < 8; ++j) {
    s8v v0 = *(const s8v*)(pacc + prow0 * 256 + seg * 64 + j * 8);
    s8v v1 = *(const s8v*)(pacc + prow1 * 256 + seg * 64 + j * 8);
    s8v ov;
#pragma unroll
    for (int e = 0; e < 8; ++e)
      ov[e] = (short)f2b((b2f((u16)v0[e]) + b2f((u16)v1[e])) * inv);
    *(s8v*)(comb + orow + j * 8) = ov;
  }
}

// ---------------------------------------------------------------------------
// GN3 stats over fin [8192][512] (bf16) per (b, group)
// ---------------------------------------------------------------------------
__global__ __launch_bounds__(256) void gn3_stats(
    const u16* __restrict__ fin, float* __restrict__ mu3, float* __restrict__ rs3)
{
  int bid = blockIdx.x;
  int b = bid >> 5, g = bid & 31;
  int tid = threadIdx.x, l = tid & 63, w = tid >> 6;
  const u16* fp = fin + (size_t)b * 1024 * 512 + g * 16;
  float sum = 0.f, sq = 0.f;
#pragma unroll
  for (int i = 0; i < 8; ++i) {
    int idx = tid + i * 256;       // 2048 chunks of 8 = 1024 tokens x 2
    int s = idx >> 1, half = (idx & 1) * 8;
    s8v v = *(const s8v*)(fp + (size_t)s * 512 + half);
#pragma unroll
    for (int e = 0; e < 8; ++e) { float f = b2f((u16)v[e]); sum += f; sq += f * f; }
  }
  __shared__ float red[8];
#pragma unroll
  for (int off = 1; off < 64; off <<= 1) { sum += __shfl_xor(sum, off); sq += __shfl_xor(sq, off); }
  if (l == 0) { red[w * 2] = sum; red[w * 2 + 1] = sq; }
  __syncthreads();
  if (tid == 0) {
    float S = red[0] + red[2] + red[4] + red[6];
    float Q = red[1] + red[3] + red[5] + red[7];
    float mean = S * (1.f / 16384.f);
    float var = Q * (1.f / 16384.f) - mean * mean;
    mu3[b * 32 + g] = mean;
    rs3[b * 32 + g] = rsqrtf(var + 1e-6f);
  }
}

// ---------------------------------------------------------------------------
// final: transpose fin (bf16) back to NCHW, apply GN3 + residual -> out (f32)
// ---------------------------------------------------------------------------
__global__ __launch_bounds__(256) void final_k(
    const u16* __restrict__ fin, const float* __restrict__ mu3, const float* __restrict__ rs3,
    const float* __restrict__ postg, const float* __restrict__ postb,
    const float* __restrict__ res, float* __restrict__ out)
{
  __shared__ float lds[16 * 513];
  int st = blockIdx.x, b = blockIdx.y;
  int tid = threadIdx.x;
  const u16* fp = fin + ((size_t)b * 1024 + st * 16) * 512;
#pragma unroll
  for (int i = 0; i < 4; ++i) {
    int idx = tid + i * 256;   // 1024 chunks of 8 = 16 s x 64
    int s = idx >> 6, c8 = (idx & 63) * 8;
    s8v v = *(const s8v*)(fp + (size_t)s * 512 + c8);
#pragma unroll
    for (int j = 0; j < 8; ++j) lds[s * 513 + c8 + j] = b2f((u16)v[j]);
  }
  __syncthreads();
#pragma unroll
  for (int cc = 0; cc < 2; ++cc) {
    int c = tid * 2 + cc;
    int g = c >> 4;
    float m = mu3[b * 32 + g], rv = rs3[b * 32 + g];
    float ga = postg[c], be = postb[c];
    const float* rp = res + ((size_t)b * 512 + c) * 1024 + st * 16;
    float* op = out + ((size_t)b * 512 + c) * 1024 + st * 16;
#pragma unroll
    for (int q = 0; q < 4; ++q) {
      f4v rr = *(const f4v*)(rp + q * 4);
      f4v o;
#pragma unroll
      for (int j = 0; j < 4; ++j) {
        float v = lds[(q * 4 + j) * 513 + c];
        o[j] = (v - m) * rv * ga + be + rr[j];
      }
      *(f4v*)(op + q * 4) = o;
    }
  }
}

// ---------------------------------------------------------------------------
extern "C" void kernel_launch(void* const* d_in, const int* in_sizes, int n_in,
                              void* d_out, int out_size, void* d_ws, size_t ws_size,
                              hipStream_t stream) {
  (void)in_sizes; (void)n_in; (void)out_size; (void)ws_size;
  const float* hs     = (const float*)d_in[0];
  const float* pre_g  = (const float*)d_in[1];
  const float* pre_b  = (const float*)d_in[2];
  const float* norm_g = (const float*)d_in[3];
  const float* norm_b = (const float*)d_in[4];
  const float* post_g = (const float*)d_in[5];
  const float* post_b = (const float*)d_in[6];
  const float* pos    = (const float*)d_in[7];
  const float* sa_b1  = (const float*)d_in[18];
  const float* sa_b2  = (const float*)d_in[20];
  const float* sa_w3  = (const float*)d_in[21];
  const float* sa_b3  = (const float*)d_in[22];
  const float* ff_b1  = (const float*)d_in[24];
  const float* ff_b2  = (const float*)d_in[26];
  const float* out_b  = (const float*)d_in[28];

  char* ws = (char*)d_ws;
  size_t off = 0;
  auto alloc = [&](size_t bytes) -> void* {
    void* pp = ws + off;
    off += (bytes + 255) & ~(size_t)255;
    return pp;
  };
  float* x    = (float*)alloc((size_t)16777216);       // region: xb -> pacc -> fin
  u16* sh     = (u16*)alloc((size_t)8388608);          // [8192][512] bf16
  u16* xt     = (u16*)alloc((size_t)8388608);          // [8192][512] bf16
  float* mu2  = (float*)alloc(1024);
  float* rs2  = (float*)alloc(1024);
  float* mu3  = (float*)alloc(1024);
  float* rs3  = (float*)alloc(1024);
  float* pl   = (float*)alloc(262144);                 // [32][16][64]
  u16* wcat   = (u16*)alloc((size_t)2691072 * 2);      // all bf16 weights
  u16* proj   = (u16*)alloc((size_t)8192 * 2560 * 2);  // q|k|v|k0|k1|v0|v1
  u16* qmb    = (u16*)alloc((size_t)8388608);          // [8192][512]
  u16* s1t    = (u16*)alloc((size_t)1048576);          // [8192][64]
  u16* colb   = (u16*)alloc((size_t)8192 * 576 * 2);   // im2col; reused as vts
  float* gate = (float*)alloc((size_t)32768);          // [8192]
  u16* vtm    = (u16*)alloc((size_t)8388608);          // [512 d][1024 keys] x 16
  u16* comb   = (u16*)alloc((size_t)16777216);         // [8192][1024]
  u16* f1     = (u16*)alloc((size_t)8388608);
  u16* f2     = (u16*)alloc((size_t)8388608);
  u16* xb     = (u16*)x;                               // bf16 NCHW x (8MB over x)
  u16* pacc   = (u16*)x;                               // 16MB over x (after xb dead)
  u16* fin    = (u16*)x;                               // bf16 [8192][512] (after pacc dead)
  u16* vts    = colb;                                  // 8MB over colb

  u16* Wbig = wcat;                 // [2560][512]
  u16* Wq01 = wcat + 1310720;       // [512][512]
  u16* W1   = wcat + 1572864;       // [64][512]
  u16* W2   = wcat + 1605632;       // [64][576]
  u16* Wff1 = wcat + 1642496;       // [512][1024]
  u16* Wff2 = wcat + 2166784;       // [512][512]
  u16* Wout = wcat + 2428928;       // [512][512]

  Segs sg;
  const int srcidx[14] = {8, 9, 10, 13, 14, 15, 16, 11, 12, 17, 19, 23, 25, 27};
  const int segsz[14] = {262144, 262144, 262144, 131072, 131072, 131072, 131072,
                         131072, 131072, 32768, 36864, 524288, 262144, 262144};
  int cum = 0;
  for (int i = 0; i < 14; ++i) {
    sg.src[i] = (const float*)d_in[srcidx[i]];
    sg.cum[i] = cum;
    sg.scl[i] = 1.f;
    cum += segsz[i];
  }
  sg.cum[14] = cum;   // 2691072
  sg.scl[0] = 0.125f * LOG2E;    // wq  : 1/sqrt(64) * log2(e)
  sg.scl[7] = 0.0625f * LOG2E;   // wq0 : 1/sqrt(256) * log2(e)
  sg.scl[8] = 0.0625f * LOG2E;   // wq1

  dim3 blk(256);
  castk<<<2628, blk, 0, stream>>>(sg, wcat);
  gn1_k<<<256, blk, 0, stream>>>(hs, pre_g, pre_b, pos, xb, mu2, rs2);
  trans_gn2<<<dim3(64, 8), blk, 0, stream>>>(xb, mu2, rs2, norm_g, norm_b, xt, sh);
  // fused qkv + multiscale k/v projection: [8192][512] x [2560][512]^T
  gemm_k<128, 128, false, false, false, false><<<1280, blk, 0, stream>>>(
      sh, 512, Wbig, 512, proj, 2560, nullptr, 512, 20, nullptr);
  // spatial gate path
  gemm_k<64, 64, true, false, true, false><<<128, blk, 0, stream>>>(
      xt, 512, W1, 512, s1t, 64, sa_b1, 512, 1, nullptr);
  im2col_k<<<2048, blk, 0, stream>>>(s1t, colb);
  // s2 GEMM with conv3+sigmoid fused in the epilogue -> gate
  gemm_gate_k<<<128, blk, 0, stream>>>(colb, 576, W2, 576, sa_b2, 576, sa_w3, sa_b3, gate);
  // qm = diag(gate) @ (xt @ Wq01^T)  — gate folded into GEMM epilogue
  gemm_k<128, 64, false, false, false, true><<<512, blk, 0, stream>>>(
      xt, 512, Wq01, 512, qmb, 512, nullptr, 512, 8, gate);
  // merged V transposes (pi-permuted); colb dead by now
  tvm_k<<<dim3(16, 80), blk, 0, stream>>>(proj, vts, vtm);
  // attention
  attn_std<<<1024, blk, 0, stream>>>(proj, vts, comb);
  attn_ms<<<512, blk, 0, stream>>>(proj, qmb, vtm, pacc, pl);
  ms_comb<<<dim3(16, 16), blk, 0, stream>>>(pacc, pl, comb);
  // feed-forward + out projection (fin in bf16)
  gemm_k<128, 64, true, false, true, false><<<512, blk, 0, stream>>>(
      comb, 1024, Wff1, 1024, f1, 512, ff_b1, 1024, 8, nullptr);
  gemm_k<128, 64, false, false, true, false><<<512, blk, 0, stream>>>(
      f1, 512, Wff2, 512, f2, 512, ff_b2, 512, 8, nullptr);
  gemm_k<128, 64, false, false, true, false><<<512, blk, 0, stream>>>(
      f2, 512, Wout, 512, fin, 512, out_b, 512, 8, nullptr);
  // final group norm + residual
  gn3_stats<<<256, blk, 0, stream>>>(fin, mu3, rs3);
  final_k<<<dim3(64, 8), blk, 0, stream>>>(fin, mu3, rs3, post_g, post_b, hs, (float*)d_out);
}

// Round 14
// 244.022 us; speedup vs baseline: 1.1019x; 1.0026x over previous
//
#include <hip/hip_runtime.h>

typedef unsigned short u16;
typedef unsigned long long u64;
typedef __attribute__((ext_vector_type(8))) short s8v;   // 8 x bf16 bits (4 VGPR)
typedef __attribute__((ext_vector_type(4))) short s4v;
typedef __attribute__((ext_vector_type(4))) float f4v;

#define LOG2E 1.4426950408889634f

__device__ __forceinline__ float b2f(u16 u) {
  union { unsigned u; float f; } x; x.u = ((unsigned)u) << 16; return x.f;
}
__device__ __forceinline__ u16 f2b(float f) {
  union { float f; unsigned u; } x; x.f = f;
  unsigned r = x.u + 0x7fffu + ((x.u >> 16) & 1u);
  return (u16)(r >> 16);
}
// packed f32x2 -> bf16x2 (single VALU op; RTE)
__device__ __forceinline__ unsigned cvtpk(float lo, float hi) {
  unsigned r;
  asm("v_cvt_pk_bf16_f32 %0, %1, %2" : "=v"(r) : "v"(lo), "v"(hi));
  return r;
}

#define MFMA16(a, b, c) __builtin_amdgcn_mfma_f32_16x16x32_bf16((a), (b), (c), 0, 0, 0)

__device__ __forceinline__ void gload16(const void* g, void* l) {
  __builtin_amdgcn_global_load_lds(
      (const __attribute__((address_space(1))) unsigned*)g,
      (__attribute__((address_space(3))) unsigned*)l, 16, 0, 0);
}

// ---------------------------------------------------------------------------
// weight cast: 14 f32 segments -> one contiguous bf16 region (with per-seg scale)
// ---------------------------------------------------------------------------
struct Segs {
  const float* src[14];
  int cum[15];
  float scl[14];
};

__global__ __launch_bounds__(256) void castk(Segs sg, u16* __restrict__ dst) {
  int gid = (blockIdx.x * 256 + threadIdx.x) * 4;
  if (gid >= sg.cum[14]) return;
  int s = 0;
  while (gid >= sg.cum[s + 1]) ++s;
  const float* sp = sg.src[s] + (gid - sg.cum[s]);
  float sc = sg.scl[s];
  f4v v = *(const f4v*)sp;
  s4v o;
  o[0] = (short)f2b(v[0] * sc); o[1] = (short)f2b(v[1] * sc);
  o[2] = (short)f2b(v[2] * sc); o[3] = (short)f2b(v[3] * sc);
  *(s4v*)(dst + gid) = o;
}

// ---------------------------------------------------------------------------
// GN1: group_norm(hidden, pre) + pos_emb -> xb (NCHW bf16); stats of x for GN2.
// ---------------------------------------------------------------------------
__global__ __launch_bounds__(256) void gn1_k(
    const float* __restrict__ hs, const float* __restrict__ pg, const float* __restrict__ pb,
    const float* __restrict__ pos, u16* __restrict__ xb,
    float* __restrict__ mu2, float* __restrict__ rs2)
{
  int bid = blockIdx.x;
  int b = bid >> 5, g = bid & 31;
  int tid = threadIdx.x, l = tid & 63, w = tid >> 6;
  const float* src = hs + ((size_t)b * 512 + g * 16) * 1024;
  const float* pp = pos + (size_t)(g * 16) * 1024;
  u16* dst = xb + ((size_t)b * 512 + g * 16) * 1024;
  f4v vals[16];
  float sum = 0.f, sq = 0.f;
#pragma unroll
  for (int i = 0; i < 16; ++i) {
    int idx = tid + i * 256;
    vals[i] = *(const f4v*)(src + (size_t)idx * 4);
    f4v v = vals[i];
    sum += v[0] + v[1] + v[2] + v[3];
    sq += v[0] * v[0] + v[1] * v[1] + v[2] * v[2] + v[3] * v[3];
  }
  __shared__ float red[8];
#pragma unroll
  for (int off = 1; off < 64; off <<= 1) { sum += __shfl_xor(sum, off); sq += __shfl_xor(sq, off); }
  if (l == 0) { red[w * 2] = sum; red[w * 2 + 1] = sq; }
  __syncthreads();
  float S = red[0] + red[2] + red[4] + red[6];
  float Q = red[1] + red[3] + red[5] + red[7];
  float mean = S * (1.f / 16384.f);
  float var = Q * (1.f / 16384.f) - mean * mean;
  float rstd = rsqrtf(var + 1e-6f);
  __syncthreads();
  float sum2 = 0.f, sq2 = 0.f;
#pragma unroll
  for (int i = 0; i < 16; ++i) {
    int idx = tid + i * 256;
    int c = idx >> 8;
    float gam = pg[g * 16 + c], bet = pb[g * 16 + c];
    f4v v = vals[i];
    f4v pe = *(const f4v*)(pp + (size_t)idx * 4);
    f4v o;
    s4v ob;
#pragma unroll
    for (int j = 0; j < 4; ++j) {
      o[j] = (v[j] - mean) * rstd * gam + bet + pe[j];
      ob[j] = (short)f2b(o[j]);
    }
    *(s4v*)(dst + (size_t)idx * 4) = ob;
    sum2 += o[0] + o[1] + o[2] + o[3];
    sq2 += o[0] * o[0] + o[1] * o[1] + o[2] * o[2] + o[3] * o[3];
  }
#pragma unroll
  for (int off = 1; off < 64; off <<= 1) { sum2 += __shfl_xor(sum2, off); sq2 += __shfl_xor(sq2, off); }
  if (l == 0) { red[w * 2] = sum2; red[w * 2 + 1] = sq2; }
  __syncthreads();
  if (tid == 0) {
    float S2 = red[0] + red[2] + red[4] + red[6];
    float Q2 = red[1] + red[3] + red[5] + red[7];
    float m2 = S2 * (1.f / 16384.f);
    float v2 = Q2 * (1.f / 16384.f) - m2 * m2;
    mu2[b * 32 + g] = m2;
    rs2[b * 32 + g] = rsqrtf(v2 + 1e-6f);
  }
}

// ---------------------------------------------------------------------------
// transpose xb (NCHW bf16) -> xt (token-major bf16) and sh = GN2(x) (token-major)
// ---------------------------------------------------------------------------
__global__ __launch_bounds__(256) void trans_gn2(
    const u16* __restrict__ xb, const float* __restrict__ mu2, const float* __restrict__ rs2,
    const float* __restrict__ ng, const float* __restrict__ nb,
    u16* __restrict__ xt, u16* __restrict__ sh)
{
  __shared__ float lds[512 * 17];
  int st = blockIdx.x, b = blockIdx.y;
  int tid = threadIdx.x;
  const u16* xp = xb + (size_t)b * 512 * 1024 + st * 16;
#pragma unroll
  for (int i = 0; i < 4; ++i) {
    int idx = tid + i * 256;       // 1024 chunks of 8 u16 = 512c x 2
    int c = idx >> 1, sq = (idx & 1) * 8;
    s8v v = *(const s8v*)(xp + (size_t)c * 1024 + sq);
#pragma unroll
    for (int j = 0; j < 8; ++j) lds[c * 17 + sq + j] = b2f((u16)v[j]);
  }
  __syncthreads();
  int s = tid & 15, cb0 = (tid >> 4) * 32;
  size_t token = (size_t)b * 1024 + st * 16 + s;
  float m0 = mu2[b * 32 + (cb0 >> 4)], m1 = mu2[b * 32 + (cb0 >> 4) + 1];
  float r0 = rs2[b * 32 + (cb0 >> 4)], r1 = rs2[b * 32 + (cb0 >> 4) + 1];
#pragma unroll
  for (int q = 0; q < 4; ++q) {
    s8v ox, os;
#pragma unroll
    for (int j = 0; j < 8; ++j) {
      int cj = q * 8 + j;
      int c = cb0 + cj;
      float v = lds[c * 17 + s];
      ox[j] = (short)f2b(v);
      float mm = (cj < 16) ? m0 : m1;
      float rr = (cj < 16) ? r0 : r1;
      os[j] = (short)f2b((v - mm) * rr * ng[c] + nb[c]);
    }
    *(s8v*)(xt + token * 512 + cb0 + q * 8) = ox;
    *(s8v*)(sh + token * 512 + cb0 + q * 8) = os;
  }
}

// ---------------------------------------------------------------------------
// generic bf16 MFMA GEMM: C[M][ldc] = A[M][lda] * Bw[N][ldb]^T  (+bias, +silu,
// +per-row scale). 1-D grid, XCD-swizzled, mt-group-4 L2 panel ordering.
// Single-buffered LDS; implicit wave-level overlap at ~5 blocks/CU.
// ---------------------------------------------------------------------------
template <int BM, int BN, bool SILU, bool OUT32, bool BIAS, bool RSCALE>
__global__ __launch_bounds__(256, 2) void gemm_k(
    const u16* __restrict__ A, int lda,
    const u16* __restrict__ Bw, int ldb,
    void* __restrict__ Cp, int ldc,
    const float* __restrict__ bias, int K, int ntx,
    const float* __restrict__ rscale)
{
  constexpr int WMT = BM / 2, WNT = BN / 2, MF = WMT / 16, NF = WNT / 16;
  __shared__ u16 Al[BM * 64];
  __shared__ u16 Bl[BN * 64];
  const int tid = threadIdx.x, l = tid & 63, w = tid >> 6;
  const int lg = l >> 4, lr = l & 15;
  const int wm = w >> 1, wn = w & 1;
  const int flat = blockIdx.x;
  const int cpx = gridDim.x >> 3;
  const int id = (flat & 7) * cpx + (flat >> 3);
  const int grp = id / (ntx * 4), rem = id % (ntx * 4);
  const int nt = rem >> 2, mt = grp * 4 + (rem & 3);
  const u16* Ag = A + (size_t)mt * BM * lda;
  const u16* Bg = Bw + (size_t)nt * BN * ldb;
  const f4v z = {0.f, 0.f, 0.f, 0.f};
  f4v acc[MF][NF];
#pragma unroll
  for (int i = 0; i < MF; ++i)
#pragma unroll
    for (int j = 0; j < NF; ++j) acc[i][j] = z;

  for (int kt = 0; kt < K; kt += 64) {
    __syncthreads();
    for (int f = tid; f < BM * 8; f += 256) {
      int row = f >> 3, g = (f & 7) ^ (row & 7);
      gload16(Ag + (size_t)row * lda + kt + g * 8, (char*)Al + f * 16);
    }
    for (int f = tid; f < BN * 8; f += 256) {
      int row = f >> 3, g = (f & 7) ^ (row & 7);
      gload16(Bg + (size_t)row * ldb + kt + g * 8, (char*)Bl + f * 16);
    }
    __syncthreads();
#pragma unroll
    for (int ks = 0; ks < 2; ++ks) {
      s8v af[MF], bf[NF];
#pragma unroll
      for (int mf = 0; mf < MF; ++mf) {
        int row = wm * WMT + mf * 16 + lr;
        af[mf] = *(const s8v*)((const char*)Al + row * 128 + (((ks * 4 + lg) ^ (row & 7)) << 4));
      }
#pragma unroll
      for (int nf = 0; nf < NF; ++nf) {
        int row = wn * WNT + nf * 16 + lr;
        bf[nf] = *(const s8v*)((const char*)Bl + row * 128 + (((ks * 4 + lg) ^ (row & 7)) << 4));
      }
#pragma unroll
      for (int mf = 0; mf < MF; ++mf)
#pragma unroll
        for (int nf = 0; nf < NF; ++nf)
          acc[mf][nf] = MFMA16(af[mf], bf[nf], acc[mf][nf]);
    }
  }
#pragma unroll
  for (int mf = 0; mf < MF; ++mf) {
    int row0 = mt * BM + wm * WMT + mf * 16 + lg * 4;
#pragma unroll
    for (int nf = 0; nf < NF; ++nf) {
      int col = nt * BN + wn * WNT + nf * 16 + lr;
      float bv = BIAS ? bias[col] : 0.f;
#pragma unroll
      for (int r = 0; r < 4; ++r) {
        float v = acc[mf][nf][r] + bv;
        if (RSCALE) v *= rscale[row0 + r];
        if (SILU) v = v / (1.f + exp2f(-v * LOG2E));
        size_t off = (size_t)(row0 + r) * ldc + col;
        if (OUT32) ((float*)Cp)[off] = v;
        else ((u16*)Cp)[off] = f2b(v);
      }
    }
  }
}

// ---------------------------------------------------------------------------
// gate GEMM: s2 = silu(col @ W2^T + b2) (64x64 per block, all channels), then
// gate[token] = sigmoid(s2[token,:] . w3 + b3) fused in-epilogue (conv3 fold).
// ---------------------------------------------------------------------------
__global__ __launch_bounds__(256, 2) void gemm_gate_k(
    const u16* __restrict__ A, int lda,
    const u16* __restrict__ Bw, int ldb,
    const float* __restrict__ bias, int K,
    const float* __restrict__ w3, const float* __restrict__ b3,
    float* __restrict__ gate)
{
  constexpr int BM = 64, BN = 64, WMT = 32, WNT = 32, MF = 2, NF = 2;
  __shared__ u16 Al[BM * 64];
  __shared__ u16 Bl[BN * 64];
  __shared__ float gt[64][68];
  const int tid = threadIdx.x, l = tid & 63, w = tid >> 6;
  const int lg = l >> 4, lr = l & 15;
  const int wm = w >> 1, wn = w & 1;
  const int flat = blockIdx.x;
  const int cpx = gridDim.x >> 3;
  const int mt = (flat & 7) * cpx + (flat >> 3);
  const u16* Ag = A + (size_t)mt * BM * lda;
  const u16* Bg = Bw;
  const f4v z = {0.f, 0.f, 0.f, 0.f};
  f4v acc[MF][NF];
#pragma unroll
  for (int i = 0; i < MF; ++i)
#pragma unroll
    for (int j = 0; j < NF; ++j) acc[i][j] = z;

  for (int kt = 0; kt < K; kt += 64) {
    __syncthreads();
    for (int f = tid; f < BM * 8; f += 256) {
      int row = f >> 3, g = (f & 7) ^ (row & 7);
      gload16(Ag + (size_t)row * lda + kt + g * 8, (char*)Al + f * 16);
    }
    for (int f = tid; f < BN * 8; f += 256) {
      int row = f >> 3, g = (f & 7) ^ (row & 7);
      gload16(Bg + (size_t)row * ldb + kt + g * 8, (char*)Bl + f * 16);
    }
    __syncthreads();
#pragma unroll
    for (int ks = 0; ks < 2; ++ks) {
      s8v af[MF], bf[NF];
#pragma unroll
      for (int mf = 0; mf < MF; ++mf) {
        int row = wm * WMT + mf * 16 + lr;
        af[mf] = *(const s8v*)((const char*)Al + row * 128 + (((ks * 4 + lg) ^ (row & 7)) << 4));
      }
#pragma unroll
      for (int nf = 0; nf < NF; ++nf) {
        int row = wn * WNT + nf * 16 + lr;
        bf[nf] = *(const s8v*)((const char*)Bl + row * 128 + (((ks * 4 + lg) ^ (row & 7)) << 4));
      }
#pragma unroll
      for (int mf = 0; mf < MF; ++mf)
#pragma unroll
        for (int nf = 0; nf < NF; ++nf)
          acc[mf][nf] = MFMA16(af[mf], bf[nf], acc[mf][nf]);
    }
  }
  __syncthreads();
#pragma unroll
  for (int mf = 0; mf < MF; ++mf) {
    int lrow0 = wm * WMT + mf * 16 + lg * 4;
#pragma unroll
    for (int nf = 0; nf < NF; ++nf) {
      int col = wn * WNT + nf * 16 + lr;
      float bv = bias[col];
#pragma unroll
      for (int r = 0; r < 4; ++r) {
        float v = acc[mf][nf][r] + bv;
        v = v / (1.f + exp2f(-v * LOG2E));
        gt[lrow0 + r][col] = v;
      }
    }
  }
  __syncthreads();
  if (tid < 64) {
    float a = b3[0];
    for (int c = 0; c < 64; ++c) a += gt[tid][c] * w3[c];
    gate[mt * 64 + tid] = 1.f / (1.f + exp2f(-a * LOG2E));
  }
}

// ---------------------------------------------------------------------------
// im2col for 3x3 conv
// ---------------------------------------------------------------------------
__global__ __launch_bounds__(256) void im2col_k(const u16* __restrict__ s1t, u16* __restrict__ col) {
  int gid = blockIdx.x * 256 + threadIdx.x;
  if (gid >= 8192 * 64) return;
  int token = gid >> 6, c = gid & 63;
  int s = token & 1023, y = s >> 5, xx = s & 31;
  u16* dst = col + (size_t)token * 576 + c * 9;
#pragma unroll
  for (int dy = 0; dy < 3; ++dy)
#pragma unroll
    for (int dx = 0; dx < 3; ++dx) {
      int yy = y + dy - 1, x2 = xx + dx - 1;
      u16 v = 0;
      if (yy >= 0 && yy < 32 && x2 >= 0 && x2 < 32)
        v = s1t[(size_t)(token + (dy - 1) * 32 + (dx - 1)) * 64 + c];
      dst[dy * 3 + dx] = v;
    }
}

// ---------------------------------------------------------------------------
// merged V transpose: y < 64 -> std heads (HD=64, col0=1024, vts);
// y >= 64 -> ms paths (HD=256, col0=2048, vtm). pi-permuted per 64-key block.
// ---------------------------------------------------------------------------
__global__ __launch_bounds__(256) void tvm_k(const u16* __restrict__ proj,
                                             u16* __restrict__ vts, u16* __restrict__ vtm)
{
  __shared__ u16 tile[64][258];
  const int tid = threadIdx.x;
  const int kb = blockIdx.x, y = blockIdx.y;
  int hd, col0, b, hh;
  u16* outp;
  if (y < 64) { hd = 64; col0 = 1024; b = y >> 3; hh = y & 7; outp = vts + (size_t)y * 64 * 1024; }
  else { int y2 = y - 64; hd = 256; col0 = 2048; b = y2 >> 1; hh = y2 & 1; outp = vtm + (size_t)y2 * 256 * 1024; }
  const int hd8 = hd >> 3;
  const u16* src = proj + ((size_t)b * 1024 + kb * 64) * 2560 + col0 + hh * hd;
  for (int f = tid; f < 64 * hd8; f += 256) {
    int key = f / hd8, c = f % hd8;
    *(s8v*)&tile[key][c * 8] = *(const s8v*)(src + (size_t)key * 2560 + c * 8);
  }
  __syncthreads();
  u16* dst = outp + kb * 64;
  for (int idx = tid; idx < hd * 16; idx += 256) {
    int d = idx >> 4, a = idx & 15;
    u16 e0 = tile[a][d], e1 = tile[16 + a][d], e2 = tile[32 + a][d], e3 = tile[48 + a][d];
    u64 v = (u64)e0 | ((u64)e1 << 16) | ((u64)e2 << 32) | ((u64)e3 << 48);
    *(u64*)(dst + (size_t)d * 1024 + a * 4) = v;
  }
}

// ---------------------------------------------------------------------------
// standard MHA flash attention: hd=64, unnormalized flash.
// K/V single-buffered in LDS (24 KB -> 6 blocks/CU for TLP); hoisted staging
// pointers; setprio around MFMA clusters.
// ---------------------------------------------------------------------------
__global__ __launch_bounds__(256, 4) void attn_std(
    const u16* __restrict__ proj, const u16* __restrict__ vts, u16* __restrict__ comb)
{
  const int tid = threadIdx.x, l = tid & 63, w = tid >> 6;
  const int lg = l >> 4, lr = l & 15;
  const int flat = blockIdx.x;
  const int xcd = flat & 7, idx = flat >> 3;      // idx 0..127
  const int bh = xcd + 8 * (idx >> 4);            // 8 heads per XCD
  const int qt = idx & 15;
  const int b = bh >> 3, h = bh & 7;
  const size_t tokb = (size_t)b * 1024;
  __shared__ u16 Kl[64 * 64];
  __shared__ u16 Vl[64 * 64];
  __shared__ u16 Pl[4][16 * 64];
  const int qr0 = qt * 64 + w * 16;
  s8v qf[2];
#pragma unroll
  for (int ks = 0; ks < 2; ++ks)
    qf[ks] = *(const s8v*)(proj + (tokb + qr0 + lr) * 2560 + h * 64 + ks * 32 + lg * 8);
  const f4v z = {0.f, 0.f, 0.f, 0.f};
  f4v acc[4];
  float lsl[4] = {0.f, 0.f, 0.f, 0.f};
#pragma unroll
  for (int r = 0; r < 4; ++r) acc[r] = z;

  const u16* gk[2];
  const u16* gv[2];
  char* lk[2];
  char* lv[2];
#pragma unroll
  for (int j = 0; j < 2; ++j) {
    int f = tid + j * 256;
    int key = f >> 3, g = (f & 7) ^ (key & 7);
    gk[j] = proj + (tokb + key) * 2560 + 512 + h * 64 + g * 8;
    int c = (f & 7) ^ (key & 7);
    gv[j] = vts + (size_t)bh * 64 * 1024 + (size_t)key * 1024 + c * 8;
    lk[j] = (char*)&Kl[0] + f * 16;
    lv[j] = (char*)&Vl[0] + f * 16;
  }

  for (int kt = 0; kt < 16; ++kt) {
    __syncthreads();
#pragma unroll
    for (int j = 0; j < 2; ++j) {
      gload16(gk[j], lk[j]);
      gload16(gv[j], lv[j]);
    }
#pragma unroll
    for (int j = 0; j < 2; ++j) { gk[j] += 64 * 2560; gv[j] += 64; }
    __syncthreads();
    f4v sf[4];
#pragma unroll
    for (int nf = 0; nf < 4; ++nf) sf[nf] = z;
    __builtin_amdgcn_s_setprio(1);
#pragma unroll
    for (int ks = 0; ks < 2; ++ks) {
      s8v kfr[4];
#pragma unroll
      for (int nf = 0; nf < 4; ++nf) {
        int row = nf * 16 + lr;
        kfr[nf] = *(const s8v*)((const char*)&Kl[0] + row * 128 + (((ks * 4 + lg) ^ (row & 7)) << 4));
      }
#pragma unroll
      for (int nf = 0; nf < 4; ++nf) sf[nf] = MFMA16(qf[ks], kfr[nf], sf[nf]);
    }
    __builtin_amdgcn_s_setprio(0);
#pragma unroll
    for (int r = 0; r < 4; ++r) {
      float pv[4];
#pragma unroll
      for (int nf = 0; nf < 4; ++nf) pv[nf] = exp2f(sf[nf][r]);
      lsl[r] += (pv[0] + pv[1]) + (pv[2] + pv[3]);
      int q = lg * 4 + r;
      u64 pk = (u64)cvtpk(pv[0], pv[1]) | ((u64)cvtpk(pv[2], pv[3]) << 32);
      *(u64*)((char*)&Pl[w][0] + q * 128 + ((((lr >> 1) ^ (q & 7)) << 4)) + (lr & 1) * 8) = pk;
    }
    __builtin_amdgcn_s_setprio(1);
#pragma unroll
    for (int ks2 = 0; ks2 < 2; ++ks2) {
      int g = ks2 * 4 + lg;
      s8v pfr = *(const s8v*)((const char*)&Pl[w][0] + lr * 128 + ((g ^ (lr & 7)) << 4));
#pragma unroll
      for (int nf = 0; nf < 4; ++nf) {
        int d = nf * 16 + lr;
        s8v vfr = *(const s8v*)((const char*)&Vl[0] + d * 128 + ((g ^ (d & 7)) << 4));
        acc[nf] = MFMA16(pfr, vfr, acc[nf]);
      }
    }
    __builtin_amdgcn_s_setprio(0);
  }
#pragma unroll
  for (int r = 0; r < 4; ++r) {
    float t = lsl[r];
#pragma unroll
    for (int off = 1; off < 16; off <<= 1) t += __shfl_xor(t, off);
    float inv = 1.f / t;
    size_t row = tokb + qr0 + lg * 4 + r;
#pragma unroll
    for (int nf = 0; nf < 4; ++nf)
      comb[row * 1024 + h * 64 + nf * 16 + lr] = f2b(acc[nf][r] * inv);
  }
}

// ---------------------------------------------------------------------------
// multi-scale attention: hd=256, K-split=2, unnormalized flash.
// K/V single-buffered LDS; hoisted staging pointers; setprio around MFMA.
// ---------------------------------------------------------------------------
__global__ __launch_bounds__(256, 2) void attn_ms(
    const u16* __restrict__ proj, const u16* __restrict__ qm, const u16* __restrict__ vtm,
    u16* __restrict__ pacc, float* __restrict__ pl)
{
  const int tid = threadIdx.x, l = tid & 63, w = tid >> 6;
  const int lg = l >> 4, lr = l & 15;
  const int flat = blockIdx.x;
  const int xcd = flat & 7, idx = flat >> 3;      // idx 0..63
  const int bp = xcd + 8 * (idx >> 5);            // 2 (b,p) pairs per XCD
  const int rest = idx & 31;
  const int qt = rest >> 1, ks = rest & 1;
  const int b = bp >> 1, p = bp & 1;
  const size_t tokb = (size_t)b * 1024;
  __shared__ u16 Kl[64 * 256];
  __shared__ u16 Vl[256 * 64];
  __shared__ u16 Pl[4][16 * 64];
  const int qr0 = qt * 64 + w * 16;
  s8v qf[8];
#pragma unroll
  for (int kf = 0; kf < 8; ++kf)
    qf[kf] = *(const s8v*)(qm + (tokb + qr0 + lr) * 512 + p * 256 + kf * 32 + lg * 8);
  const f4v z = {0.f, 0.f, 0.f, 0.f};
  f4v acc[16];
#pragma unroll
  for (int i = 0; i < 16; ++i) acc[i] = z;
  float lsl[4] = {0.f, 0.f, 0.f, 0.f};
  const u16* vbase = vtm + (size_t)bp * 256 * 1024;

  const u16* gk[8];
  const u16* gv[8];
#pragma unroll
  for (int j = 0; j < 8; ++j) {
    int f = tid + j * 256;
    int key = f >> 5, pgc = f & 31;
    int g = (pgc & 24) | ((pgc & 7) ^ (key & 7));
    gk[j] = proj + (tokb + ks * 512 + key) * 2560 + 1536 + p * 256 + g * 8;
    int d = f >> 3, c = (f & 7) ^ (d & 7);
    gv[j] = vbase + (size_t)d * 1024 + ks * 512 + c * 8;
  }

  for (int kk = 0; kk < 8; ++kk) {
    __syncthreads();
#pragma unroll
    for (int j = 0; j < 8; ++j) gload16(gk[j], (char*)Kl + (tid + j * 256) * 16);
#pragma unroll
    for (int j = 0; j < 8; ++j) gload16(gv[j], (char*)Vl + (tid + j * 256) * 16);
#pragma unroll
    for (int j = 0; j < 8; ++j) { gk[j] += 64 * 2560; gv[j] += 64; }
    __syncthreads();
    f4v sf[4];
#pragma unroll
    for (int nf = 0; nf < 4; ++nf) sf[nf] = z;
    __builtin_amdgcn_s_setprio(1);
#pragma unroll
    for (int ksi = 0; ksi < 8; ++ksi) {
      s8v kfr[4];
#pragma unroll
      for (int nf = 0; nf < 4; ++nf) {
        int row = nf * 16 + lr;
        int g = ksi * 4 + lg;
        int pg2 = (g & 24) | ((g & 7) ^ (row & 7));
        kfr[nf] = *(const s8v*)((const char*)Kl + row * 512 + (pg2 << 4));
      }
#pragma unroll
      for (int nf = 0; nf < 4; ++nf) sf[nf] = MFMA16(qf[ksi], kfr[nf], sf[nf]);
    }
    __builtin_amdgcn_s_setprio(0);
#pragma unroll
    for (int r = 0; r < 4; ++r) {
      float pv[4];
#pragma unroll
      for (int nf = 0; nf < 4; ++nf) pv[nf] = exp2f(sf[nf][r]);
      lsl[r] += (pv[0] + pv[1]) + (pv[2] + pv[3]);
      int q = lg * 4 + r;
      u64 pk = (u64)cvtpk(pv[0], pv[1]) | ((u64)cvtpk(pv[2], pv[3]) << 32);
      *(u64*)((char*)&Pl[w][0] + q * 128 + ((((lr >> 1) ^ (q & 7)) << 4)) + (lr & 1) * 8) = pk;
    }
    __builtin_amdgcn_s_setprio(1);
#pragma unroll
    for (int ks2 = 0; ks2 < 2; ++ks2) {
      int g = ks2 * 4 + lg;
      s8v pfr = *(const s8v*)((const char*)&Pl[w][0] + lr * 128 + ((g ^ (lr & 7)) << 4));
#pragma unroll
      for (int nfd = 0; nfd < 16; ++nfd) {
        int d = nfd * 16 + lr;
        s8v vfr = *(const s8v*)((const char*)Vl + d * 128 + ((g ^ (d & 7)) << 4));
        acc[nfd] = MFMA16(pfr, vfr, acc[nfd]);
      }
    }
    __builtin_amdgcn_s_setprio(0);
  }
#pragma unroll
  for (int r = 0; r < 4; ++r) {
    float t = lsl[r];
#pragma unroll
    for (int off = 1; off < 16; off <<= 1) t += __shfl_xor(t, off);
    size_t prow = ((size_t)(bp * 2 + ks) * 16 + qt) * 64 + w * 16 + lg * 4 + r;
#pragma unroll
    for (int nfd = 0; nfd < 16; ++nfd)
      pacc[prow * 256 + nfd * 16 + lr] = f2b(acc[nfd][r]);
    if (lr == 0) pl[prow] = t;
  }
}

// ---------------------------------------------------------------------------
// combine the 2 K-slices of attn_ms -> comb[:, 512:1024]  (shared exponent frame)
// ---------------------------------------------------------------------------
__global__ __launch_bounds__(256) void ms_comb(
    const u16* __restrict__ pacc, const float* __restrict__ pl,
    u16* __restrict__ comb)
{
  const int qt = blockIdx.x, bp = blockIdx.y;
  const int tid = threadIdx.x;
  const int row = tid >> 2, seg = tid & 3;
  size_t prow0 = ((size_t)(bp * 2 + 0) * 16 + qt) * 64 + row;
  size_t prow1 = ((size_t)(bp * 2 + 1) * 16 + qt) * 64 + row;
  float inv = 1.f / (pl[prow0] + pl[prow1]);
  const int b = bp >> 1, p = bp & 1;
  size_t orow = ((size_t)b * 1024 + qt * 64 + row) * 1024 + 512 + p * 256 + seg * 64;
#pragma unroll
  for (int j = 0; j < 8; ++j) {
    s8v v0 = *(const s8v*)(pacc + prow0 * 256 + seg * 64 + j * 8);
    s8v v1 = *(const s8v*)(pacc + prow1 * 256 + seg * 64 + j * 8);
    s8v ov;
#pragma unroll
    for (int e = 0; e < 8; ++e)
      ov[e] = (short)f2b((b2f((u16)v0[e]) + b2f((u16)v1[e])) * inv);
    *(s8v*)(comb + orow + j * 8) = ov;
  }
}

// ---------------------------------------------------------------------------
// GN3 stats over fin [8192][512] (bf16) per (b, group)
// ---------------------------------------------------------------------------
__global__ __launch_bounds__(256) void gn3_stats(
    const u16* __restrict__ fin, float* __restrict__ mu3, float* __restrict__ rs3)
{
  int bid = blockIdx.x;
  int b = bid >> 5, g = bid & 31;
  int tid = threadIdx.x, l = tid & 63, w = tid >> 6;
  const u16* fp = fin + (size_t)b * 1024 * 512 + g * 16;
  float sum = 0.f, sq = 0.f;
#pragma unroll
  for (int i = 0; i < 8; ++i) {
    int idx = tid + i * 256;       // 2048 chunks of 8 = 1024 tokens x 2
    int s = idx >> 1, half = (idx & 1) * 8;
    s8v v = *(const s8v*)(fp + (size_t)s * 512 + half);
#pragma unroll
    for (int e = 0; e < 8; ++e) { float f = b2f((u16)v[e]); sum += f; sq += f * f; }
  }
  __shared__ float red[8];
#pragma unroll
  for (int off = 1; off < 64; off <<= 1) { sum += __shfl_xor(sum, off); sq += __shfl_xor(sq, off); }
  if (l == 0) { red[w * 2] = sum; red[w * 2 + 1] = sq; }
  __syncthreads();
  if (tid == 0) {
    float S = red[0] + red[2] + red[4] + red[6];
    float Q = red[1] + red[3] + red[5] + red[7];
    float mean = S * (1.f / 16384.f);
    float var = Q * (1.f / 16384.f) - mean * mean;
    mu3[b * 32 + g] = mean;
    rs3[b * 32 + g] = rsqrtf(var + 1e-6f);
  }
}

// ---------------------------------------------------------------------------
// final: transpose fin (bf16) back to NCHW, apply GN3 + residual -> out (f32)
// ---------------------------------------------------------------------------
__global__ __launch_bounds__(256) void final_k(
    const u16* __restrict__ fin, const float* __restrict__ mu3, const float* __restrict__ rs3,
    const float* __restrict__ postg, const float* __restrict__ postb,
    const float* __restrict__ res, float* __restrict__ out)
{
  __shared__ float lds[16 * 513];
  int st = blockIdx.x, b = blockIdx.y;
  int tid = threadIdx.x;
  const u16* fp = fin + ((size_t)b * 1024 + st * 16) * 512;
#pragma unroll
  for (int i = 0; i < 4; ++i) {
    int idx = tid + i * 256;   // 1024 chunks of 8 = 16 s x 64
    int s = idx >> 6, c8 = (idx & 63) * 8;
    s8v v = *(const s8v*)(fp + (size_t)s * 512 + c8);
#pragma unroll
    for (int j = 0; j < 8; ++j) lds[s * 513 + c8 + j] = b2f((u16)v[j]);
  }
  __syncthreads();
#pragma unroll
  for (int cc = 0; cc < 2; ++cc) {
    int c = tid * 2 + cc;
    int g = c >> 4;
    float m = mu3[b * 32 + g], rv = rs3[b * 32 + g];
    float ga = postg[c], be = postb[c];
    const float* rp = res + ((size_t)b * 512 + c) * 1024 + st * 16;
    float* op = out + ((size_t)b * 512 + c) * 1024 + st * 16;
#pragma unroll
    for (int q = 0; q < 4; ++q) {
      f4v rr = *(const f4v*)(rp + q * 4);
      f4v o;
#pragma unroll
      for (int j = 0; j < 4; ++j) {
        float v = lds[(q * 4 + j) * 513 + c];
        o[j] = (v - m) * rv * ga + be + rr[j];
      }
      *(f4v*)(op + q * 4) = o;
    }
  }
}

// ---------------------------------------------------------------------------
extern "C" void kernel_launch(void* const* d_in, const int* in_sizes, int n_in,
                              void* d_out, int out_size, void* d_ws, size_t ws_size,
                              hipStream_t stream) {
  (void)in_sizes; (void)n_in; (void)out_size; (void)ws_size;
  const float* hs     = (const float*)d_in[0];
  const float* pre_g  = (const float*)d_in[1];
  const float* pre_b  = (const float*)d_in[2];
  const float* norm_g = (const float*)d_in[3];
  const float* norm_b = (const float*)d_in[4];
  const float* post_g = (const float*)d_in[5];
  const float* post_b = (const float*)d_in[6];
  const float* pos    = (const float*)d_in[7];
  const float* sa_b1  = (const float*)d_in[18];
  const float* sa_b2  = (const float*)d_in[20];
  const float* sa_w3  = (const float*)d_in[21];
  const float* sa_b3  = (const float*)d_in[22];
  const float* ff_b1  = (const float*)d_in[24];
  const float* ff_b2  = (const float*)d_in[26];
  const float* out_b  = (const float*)d_in[28];

  char* ws = (char*)d_ws;
  size_t off = 0;
  auto alloc = [&](size_t bytes) -> void* {
    void* pp = ws + off;
    off += (bytes + 255) & ~(size_t)255;
    return pp;
  };
  float* x    = (float*)alloc((size_t)16777216);       // region: xb -> pacc -> fin
  u16* sh     = (u16*)alloc((size_t)8388608);          // [8192][512] bf16
  u16* xt     = (u16*)alloc((size_t)8388608);          // [8192][512] bf16
  float* mu2  = (float*)alloc(1024);
  float* rs2  = (float*)alloc(1024);
  float* mu3  = (float*)alloc(1024);
  float* rs3  = (float*)alloc(1024);
  float* pl   = (float*)alloc(262144);                 // [32][16][64]
  u16* wcat   = (u16*)alloc((size_t)2691072 * 2);      // all bf16 weights
  u16* proj   = (u16*)alloc((size_t)8192 * 2560 * 2);  // q|k|v|k0|k1|v0|v1
  u16* qmb    = (u16*)alloc((size_t)8388608);          // [8192][512]
  u16* s1t    = (u16*)alloc((size_t)1048576);          // [8192][64]
  u16* colb   = (u16*)alloc((size_t)8192 * 576 * 2);   // im2col; reused as vts
  float* gate = (float*)alloc((size_t)32768);          // [8192]
  u16* vtm    = (u16*)alloc((size_t)8388608);          // [512 d][1024 keys] x 16
  u16* comb   = (u16*)alloc((size_t)16777216);         // [8192][1024]
  u16* f1     = (u16*)alloc((size_t)8388608);
  u16* f2     = (u16*)alloc((size_t)8388608);
  u16* xb     = (u16*)x;                               // bf16 NCHW x (8MB over x)
  u16* pacc   = (u16*)x;                               // 16MB over x (after xb dead)
  u16* fin    = (u16*)x;                               // bf16 [8192][512] (after pacc dead)
  u16* vts    = colb;                                  // 8MB over colb

  u16* Wbig = wcat;                 // [2560][512]
  u16* Wq01 = wcat + 1310720;       // [512][512]
  u16* W1   = wcat + 1572864;       // [64][512]
  u16* W2   = wcat + 1605632;       // [64][576]
  u16* Wff1 = wcat + 1642496;       // [512][1024]
  u16* Wff2 = wcat + 2166784;       // [512][512]
  u16* Wout = wcat + 2428928;       // [512][512]

  Segs sg;
  const int srcidx[14] = {8, 9, 10, 13, 14, 15, 16, 11, 12, 17, 19, 23, 25, 27};
  const int segsz[14] = {262144, 262144, 262144, 131072, 131072, 131072, 131072,
                         131072, 131072, 32768, 36864, 524288, 262144, 262144};
  int cum = 0;
  for (int i = 0; i < 14; ++i) {
    sg.src[i] = (const float*)d_in[srcidx[i]];
    sg.cum[i] = cum;
    sg.scl[i] = 1.f;
    cum += segsz[i];
  }
  sg.cum[14] = cum;   // 2691072
  sg.scl[0] = 0.125f * LOG2E;    // wq  : 1/sqrt(64) * log2(e)
  sg.scl[7] = 0.0625f * LOG2E;   // wq0 : 1/sqrt(256) * log2(e)
  sg.scl[8] = 0.0625f * LOG2E;   // wq1

  dim3 blk(256);
  castk<<<2628, blk, 0, stream>>>(sg, wcat);
  gn1_k<<<256, blk, 0, stream>>>(hs, pre_g, pre_b, pos, xb, mu2, rs2);
  trans_gn2<<<dim3(64, 8), blk, 0, stream>>>(xb, mu2, rs2, norm_g, norm_b, xt, sh);
  // fused qkv + multiscale k/v projection: [8192][512] x [2560][512]^T
  gemm_k<128, 128, false, false, false, false><<<1280, blk, 0, stream>>>(
      sh, 512, Wbig, 512, proj, 2560, nullptr, 512, 20, nullptr);
  // spatial gate path
  gemm_k<64, 64, true, false, true, false><<<128, blk, 0, stream>>>(
      xt, 512, W1, 512, s1t, 64, sa_b1, 512, 1, nullptr);
  im2col_k<<<2048, blk, 0, stream>>>(s1t, colb);
  // s2 GEMM with conv3+sigmoid fused in the epilogue -> gate
  gemm_gate_k<<<128, blk, 0, stream>>>(colb, 576, W2, 576, sa_b2, 576, sa_w3, sa_b3, gate);
  // qm = diag(gate) @ (xt @ Wq01^T)  — gate folded into GEMM epilogue
  gemm_k<128, 64, false, false, false, true><<<512, blk, 0, stream>>>(
      xt, 512, Wq01, 512, qmb, 512, nullptr, 512, 8, gate);
  // merged V transposes (pi-permuted); colb dead by now
  tvm_k<<<dim3(16, 80), blk, 0, stream>>>(proj, vts, vtm);
  // attention
  attn_std<<<1024, blk, 0, stream>>>(proj, vts, comb);
  attn_ms<<<512, blk, 0, stream>>>(proj, qmb, vtm, pacc, pl);
  ms_comb<<<dim3(16, 16), blk, 0, stream>>>(pacc, pl, comb);
  // feed-forward + out projection (fin in bf16)
  gemm_k<128, 64, true, false, true, false><<<512, blk, 0, stream>>>(
      comb, 1024, Wff1, 1024, f1, 512, ff_b1, 1024, 8, nullptr);
  gemm_k<128, 64, false, false, true, false><<<512, blk, 0, stream>>>(
      f1, 512, Wff2, 512, f2, 512, ff_b2, 512, 8, nullptr);
  gemm_k<128, 64, false, false, true, false><<<512, blk, 0, stream>>>(
      f2, 512, Wout, 512, fin, 512, out_b, 512, 8, nullptr);
  // final group norm + residual
  gn3_stats<<<256, blk, 0, stream>>>(fin, mu3, rs3);
  final_k<<<dim3(64, 8), blk, 0, stream>>>(fin, mu3, rs3, post_g, post_b, hs, (float*)d_out);
}